// Round 1
// baseline (1634.700 us; speedup 1.0000x reference)
//
#include <hip/hip_runtime.h>

// MVGRL encoder, MI355X gfx950.
// Requires ws_size >= ~68 MB.
#define NN 4096
#define NE 65536
#define NBAG 16
#define BFD 8192
#define CIN 128
#define HIDC 512
#define NG 64
#define ALPHA_C 0.2f
#define BETA_C 0.8f
#define K_SOLVE 24
#define K_W 24

typedef __attribute__((ext_vector_type(8))) short short8;
typedef __attribute__((ext_vector_type(4))) float f32x4;
typedef __attribute__((ext_vector_type(2))) float f32x2;

__device__ __forceinline__ short f2bf(float f){
  unsigned u = __float_as_uint(f);
  u += 0x7fffu + ((u >> 16) & 1u);
  return (short)(u >> 16);
}

// ---------- embedding bag (mean, padding idx = BFD) ----------
__global__ void k_embed(const float* __restrict__ cb, const int* __restrict__ xidx,
                        float* __restrict__ xf){
  int n = blockIdx.x, c = threadIdx.x;
  float acc = 0.f; int cnt = 0;
  #pragma unroll
  for (int b = 0; b < NBAG; ++b){
    int id = xidx[n*NBAG + b];
    if (id != BFD){ acc += cb[(size_t)id*CIN + c]; ++cnt; }
  }
  xf[(size_t)n*CIN + c] = acc / (float)(cnt > 0 ? cnt : 1);
}

// ---------- graph prep ----------
__global__ void k_scatter(const int* __restrict__ ei, unsigned* __restrict__ Ab,
                          unsigned* __restrict__ ATb, int* __restrict__ cntD){
  int e = blockIdx.x*256 + threadIdx.x;
  if (e >= NE) return;
  int s = ei[e], d = ei[NE + e];
  atomicOr(&Ab[s*128 + (d >> 5)], 1u << (d & 31));   // A[s][d] = 1 (dedup via .set)
  atomicOr(&ATb[d*128 + (s >> 5)], 1u << (s & 31));  // A^T
  atomicAdd(&cntD[d], 1);                            // in-degree WITH multiplicity (sparse tower)
}

__global__ void k_hist_batch(const int* __restrict__ batch, int* __restrict__ bcnt){
  int n = blockIdx.x*256 + threadIdx.x;
  if (n >= NN) return;
  atomicAdd(&bcnt[batch[n]], 1);
}

__global__ void k_popc_rows(const unsigned* __restrict__ bits, int* __restrict__ out){
  int wid = (blockIdx.x*blockDim.x + threadIdx.x) >> 6;
  int lane = threadIdx.x & 63;
  if (wid >= NN) return;
  int s = __popc(bits[wid*128 + lane]) + __popc(bits[wid*128 + 64 + lane]);
  #pragma unroll
  for (int o = 32; o > 0; o >>= 1) s += __shfl_down(s, o);
  if (lane == 0) out[wid] = s;
}

__global__ void k_rsqrt1p(const int* __restrict__ cnt, float* __restrict__ out){
  int i = blockIdx.x*256 + threadIdx.x;
  if (i >= NN) return;
  out[i] = rsqrtf((float)cnt[i] + 1.0f);  // 1/sqrt(deg + self-loop)
}

// exclusive prefix over n (<=4096) ints; rp[0..n], single block of 1024
__global__ void k_prefix(const int* __restrict__ cnt, int* __restrict__ rp, int n){
  __shared__ int a[4096];
  __shared__ int ps[1024];
  int t = threadIdx.x;
  for (int i = t; i < 4096; i += 1024) a[i] = (i < n) ? cnt[i] : 0;
  __syncthreads();
  int b0 = a[t*4], b1 = a[t*4+1], b2 = a[t*4+2], b3 = a[t*4+3];
  int s0 = b0, s1 = s0+b1, s2 = s1+b2, s3 = s2+b3;
  ps[t] = s3;
  __syncthreads();
  for (int off = 1; off < 1024; off <<= 1){
    int v = ps[t];
    int u = (t >= off) ? ps[t-off] : 0;
    __syncthreads();
    ps[t] = v + u;
    __syncthreads();
  }
  int excl = (t > 0) ? ps[t-1] : 0;
  int base = t*4;
  if (base     < n) rp[base]   = excl;
  if (base + 1 < n) rp[base+1] = excl + s0;
  if (base + 2 < n) rp[base+2] = excl + s1;
  if (base + 3 < n) rp[base+3] = excl + s2;
  if (t == 1023) rp[n] = ps[1023];
}

// CSR columns from bitmap rows (deterministic wave-scan ordering)
__global__ void k_fill_bits(const unsigned* __restrict__ bits, const int* __restrict__ rp,
                            int* __restrict__ colidx){
  int wid = (blockIdx.x*blockDim.x + threadIdx.x) >> 6;
  int lane = threadIdx.x & 63;
  if (wid >= NN) return;
  unsigned w0 = bits[wid*128 + lane];
  unsigned w1 = bits[wid*128 + 64 + lane];
  int c = __popc(w0) + __popc(w1);
  int x = c;
  #pragma unroll
  for (int d = 1; d < 64; d <<= 1){
    int y = __shfl_up(x, d);
    if (lane >= d) x += y;
  }
  int pos = rp[wid] + (x - c);
  while (w0){ int b = __ffs(w0) - 1; w0 &= w0 - 1; colidx[pos++] = lane*32 + b; }
  while (w1){ int b = __ffs(w1) - 1; w1 &= w1 - 1; colidx[pos++] = (64 + lane)*32 + b; }
}

__global__ void k_fill_edges(const int* __restrict__ ei, const int* __restrict__ rp,
                             int* __restrict__ cur, int* __restrict__ srcs){
  int e = blockIdx.x*256 + threadIdx.x;
  if (e >= NE) return;
  int s = ei[e], d = ei[NE + e];
  int pos = atomicAdd(&cur[d], 1);
  srcs[rp[d] + pos] = s;
}

// ---------- sparse-tower GCN aggregation (wave per row, C=512) ----------
__global__ __launch_bounds__(256) void k_gcn_sp(const float* __restrict__ U, float* __restrict__ out,
    const int* __restrict__ rp, const int* __restrict__ srcs, const float* __restrict__ dis,
    const float* __restrict__ bias, const float* __restrict__ avec){
  int wid = (blockIdx.x*256 + threadIdx.x) >> 6;
  int lane = threadIdx.x & 63;
  if (wid >= NN) return;
  int j = wid;
  f32x4 a0 = {0,0,0,0}, a1 = {0,0,0,0};
  int b = rp[j], e = rp[j+1];
  for (int k = b; k < e; ++k){
    int s = srcs[k]; float w = dis[s];
    const f32x4* Us = (const f32x4*)(U + (size_t)s*HIDC);
    a0 += w*Us[lane]; a1 += w*Us[64+lane];
  }
  float dj = dis[j];
  const f32x4* Uj = (const f32x4*)(U + (size_t)j*HIDC);
  a0 += dj*Uj[lane]; a1 += dj*Uj[64+lane];
  float* op = out + (size_t)j*HIDC;
  #pragma unroll
  for (int v = 0; v < 4; ++v){
    int c0 = lane*4 + v, c1 = 256 + lane*4 + v;
    float x0 = dj*a0[v] + bias[c0]; float p0 = avec[c0];
    op[c0] = x0 >= 0.f ? x0 : p0*x0;
    float x1 = dj*a1[v] + bias[c1]; float p1 = avec[c1];
    op[c1] = x1 >= 0.f ? x1 : p1*x1;
  }
}

// ---------- one Neumann step: Xn = Z + 0.8 * An^T * X   (wave per row) ----------
template<int C>
__global__ __launch_bounds__(256) void k_bapply(const float* __restrict__ X, const float* __restrict__ Z,
    float* __restrict__ Xn, const int* __restrict__ rp, const int* __restrict__ cols,
    const float* __restrict__ di){
  int wid = (blockIdx.x*256 + threadIdx.x) >> 6;
  int lane = threadIdx.x & 63;
  if (wid >= NN) return;
  int j = wid;
  int b = rp[j], e = rp[j+1];
  float dj = di[j];
  if constexpr (C == 512){
    f32x4 a0 = {0,0,0,0}, a1 = {0,0,0,0};
    for (int k = b; k < e; ++k){
      int i = cols[k]; float w = di[i];
      const f32x4* Xi = (const f32x4*)(X + (size_t)i*512);
      a0 += w*Xi[lane]; a1 += w*Xi[64+lane];
    }
    const f32x4* Xj = (const f32x4*)(X + (size_t)j*512);
    a0 += dj*Xj[lane]; a1 += dj*Xj[64+lane];
    const f32x4* Zj = (const f32x4*)(Z + (size_t)j*512);
    f32x4* Oj = (f32x4*)(Xn + (size_t)j*512);
    Oj[lane]    = Zj[lane]    + (BETA_C*dj)*a0;
    Oj[64+lane] = Zj[64+lane] + (BETA_C*dj)*a1;
  } else {
    f32x2 a0 = {0,0};
    for (int k = b; k < e; ++k){
      int i = cols[k]; float w = di[i];
      const f32x2* Xi = (const f32x2*)(X + (size_t)i*128);
      a0 += w*Xi[lane];
    }
    const f32x2* Xj = (const f32x2*)(X + (size_t)j*128);
    a0 += dj*Xj[lane];
    const f32x2* Zj = (const f32x2*)(Z + (size_t)j*128);
    f32x2* Oj = (f32x2*)(Xn + (size_t)j*128);
    Oj[lane] = Zj[lane] + (BETA_C*dj)*a0;
  }
}

// ---------- w (column-sum of S) iteration ----------
__global__ void k_winit(float* __restrict__ wv){
  int i = blockIdx.x*256 + threadIdx.x;
  if (i < NN) wv[i] = ALPHA_C;
}
__global__ void k_wstep(const float* __restrict__ w, float* __restrict__ wn,
    const int* __restrict__ rp, const int* __restrict__ cols, const float* __restrict__ di){
  int j = blockIdx.x*256 + threadIdx.x;
  if (j >= NN) return;
  float acc = 0.f;
  int b = rp[j], e = rp[j+1];
  for (int k = b; k < e; ++k){ int i = cols[k]; acc += di[i]*w[i]; }
  float dj = di[j];
  acc += dj*w[j];
  wn[j] = ALPHA_C + BETA_C*dj*acc;
}
__global__ void k_dc(const float* __restrict__ wv, float* __restrict__ dc){
  int i = blockIdx.x*256 + threadIdx.x;
  if (i >= NN) return;
  dc[i] = rsqrtf(fmaxf(wv[i] + 1.0f, 1e-12f));
}

// ---------- elementwise helpers ----------
template<int CSH>
__global__ void k_prepZ(const float* __restrict__ in, const float* __restrict__ dc,
                        float* __restrict__ Z, float* __restrict__ X0){
  int idx = blockIdx.x*256 + threadIdx.x;
  if (idx >= (NN << CSH)) return;
  float v = ALPHA_C * dc[idx >> CSH] * in[idx];
  Z[idx] = v; X0[idx] = v;
}
__global__ void k_fin1(const float* __restrict__ X, const float* __restrict__ xf,
                       const float* __restrict__ dc, float* __restrict__ Px){
  int idx = blockIdx.x*256 + threadIdx.x;
  if (idx >= NN*CIN) return;
  float d = dc[idx >> 7];
  Px[idx] = d*(X[idx] + d*xf[idx]);
}
__global__ void k_fin2(const float* __restrict__ X, const float* __restrict__ U,
                       const float* __restrict__ dc, const float* __restrict__ bias,
                       const float* __restrict__ avec, float* __restrict__ out){
  int idx = blockIdx.x*256 + threadIdx.x;
  if (idx >= NN*HIDC) return;
  int i = idx >> 9, c = idx & 511;
  float d = dc[i];
  float v = d*(X[idx] + d*U[idx]) + bias[c];
  float a = avec[c];
  out[idx] = v >= 0.f ? v : a*v;
}

// ---------- segment sum -> [NG, 1024] ----------
__global__ void k_segsum(const float* __restrict__ z1, const float* __restrict__ z2,
                         const int* __restrict__ gptr, float* __restrict__ gv){
  int g = blockIdx.x, t = threadIdx.x;
  float s0 = 0, s1 = 0, s2 = 0, s3 = 0;
  int rb = gptr[g], re = gptr[g+1];
  for (int r = rb; r < re; ++r){
    s0 += z1[(size_t)r*HIDC + t];       s1 += z1[(size_t)r*HIDC + 256 + t];
    s2 += z2[(size_t)r*HIDC + t];       s3 += z2[(size_t)r*HIDC + 256 + t];
  }
  gv[g*1024 + t] = s0; gv[g*1024 + 256 + t] = s1;
  gv[g*1024 + 512 + t] = s2; gv[g*1024 + 768 + t] = s3;
}

// ---------- bf16 MFMA GEMM: C = act(A*B + bias) [+ addm]; A[M,K],B[K,N] f32 row-major ----------
template<int BM, int BN, int ACT, int ADDM, int BIAS>
__global__ __launch_bounds__(256) void k_gemm(
    const float* __restrict__ A, const float* __restrict__ B,
    float* __restrict__ C, const float* __restrict__ bias,
    const float* __restrict__ ap, const float* __restrict__ addm,
    int M, int Nn, int K)
{
  __shared__ __align__(16) short As[BM][40];
  __shared__ __align__(16) short Bs[BN][40];
  const int tid = threadIdx.x;
  const int bm0 = blockIdx.y*BM, bn0 = blockIdx.x*BN;
  const int lane = tid & 63, wv = tid >> 6;
  const int wr = wv >> 1, wc = wv & 1;
  constexpr int MR = BM/32, NR = BN/32;
  f32x4 acc[MR][NR];
  #pragma unroll
  for (int i = 0; i < MR; ++i)
    #pragma unroll
    for (int j = 0; j < NR; ++j) acc[i][j] = (f32x4){0.f,0.f,0.f,0.f};
  const int r0 = wr*(BM/2), c0 = wc*(BN/2);
  constexpr int EA = BM*32/256;
  constexpr int EB = BN*32/256;
  const int arow = (tid*EA) >> 5, acol = (tid*EA) & 31;
  const int bkr = (tid*EB) / BN, bnc = (tid*EB) % BN;
  for (int kt = 0; kt < K; kt += 32){
    __syncthreads();
    { // stage A (f32 -> bf16)
      const float* src = A + (size_t)(bm0 + arow)*K + kt + acol;
      short tmp[EA] __attribute__((aligned(16)));
      #pragma unroll
      for (int q = 0; q < EA; q += 4){
        f32x4 v = *(const f32x4*)(src + q);
        tmp[q+0] = f2bf(v[0]); tmp[q+1] = f2bf(v[1]);
        tmp[q+2] = f2bf(v[2]); tmp[q+3] = f2bf(v[3]);
      }
      #pragma unroll
      for (int q = 0; q < EA; q += 8)
        *(short8*)&As[arow][acol + q] = *(const short8*)&tmp[q];
    }
    { // stage B transposed
      const float* src = B + (size_t)(kt + bkr)*Nn + bn0 + bnc;
      #pragma unroll
      for (int q = 0; q < EB; q += 4){
        f32x4 v = *(const f32x4*)(src + q);
        Bs[bnc+q+0][bkr] = f2bf(v[0]);
        Bs[bnc+q+1][bkr] = f2bf(v[1]);
        Bs[bnc+q+2][bkr] = f2bf(v[2]);
        Bs[bnc+q+3][bkr] = f2bf(v[3]);
      }
    }
    __syncthreads();
    short8 af[MR], bfv[NR];
    #pragma unroll
    for (int mi = 0; mi < MR; ++mi)
      af[mi] = *(const short8*)&As[r0 + mi*16 + (lane & 15)][(lane >> 4)*8];
    #pragma unroll
    for (int ni = 0; ni < NR; ++ni)
      bfv[ni] = *(const short8*)&Bs[c0 + ni*16 + (lane & 15)][(lane >> 4)*8];
    #pragma unroll
    for (int mi = 0; mi < MR; ++mi)
      #pragma unroll
      for (int ni = 0; ni < NR; ++ni)
        acc[mi][ni] = __builtin_amdgcn_mfma_f32_16x16x32_bf16(af[mi], bfv[ni], acc[mi][ni], 0, 0, 0);
  }
  #pragma unroll
  for (int mi = 0; mi < MR; ++mi){
    #pragma unroll
    for (int ni = 0; ni < NR; ++ni){
      int col = bn0 + c0 + ni*16 + (lane & 15);
      #pragma unroll
      for (int q = 0; q < 4; ++q){
        int row = bm0 + r0 + mi*16 + ((lane >> 4) << 2) + q;
        float v = acc[mi][ni][q];
        if constexpr (BIAS) v += bias[col];
        if constexpr (ACT == 1){ float a = ap[col]; v = v >= 0.f ? v : a*v; }
        if constexpr (ACT == 2){ float a = ap[0];   v = v >= 0.f ? v : a*v; }
        if constexpr (ADDM) v += addm[(size_t)row*Nn + col];
        C[(size_t)row*Nn + col] = v;
      }
    }
  }
}

#define GEMM(BM,BN,ACT,ADDM,BIAS, A,B,Cp,biasp,app,addp, M,Nv,K) \
  k_gemm<BM,BN,ACT,ADDM,BIAS><<<dim3((Nv)/(BN),(M)/(BM)), 256, 0, stream>>>(A,B,Cp,biasp,app,addp,M,Nv,K)

extern "C" void kernel_launch(void* const* d_in, const int* in_sizes, int n_in,
                              void* d_out, int out_size, void* d_ws, size_t ws_size,
                              hipStream_t stream) {
  const float* cb   = (const float*)d_in[0];
  const float* g1W0 = (const float*)d_in[1];  const float* g1b0 = (const float*)d_in[2];
  const float* g1W1 = (const float*)d_in[3];  const float* g1b1 = (const float*)d_in[4];
  const float* g1a  = (const float*)d_in[5];
  const float* g2W0 = (const float*)d_in[6];  const float* g2b0 = (const float*)d_in[7];
  const float* g2W1 = (const float*)d_in[8];  const float* g2b1 = (const float*)d_in[9];
  const float* g2a  = (const float*)d_in[10];
  const float* m1W1 = (const float*)d_in[11]; const float* m1b1 = (const float*)d_in[12];
  const float* m1W2 = (const float*)d_in[13]; const float* m1b2 = (const float*)d_in[14];
  const float* m1W3 = (const float*)d_in[15]; const float* m1b3 = (const float*)d_in[16];
  const float* m1a1 = (const float*)d_in[17]; const float* m1a2 = (const float*)d_in[18];
  const float* m1a3 = (const float*)d_in[19];
  const float* m1Ws = (const float*)d_in[20]; const float* m1bs = (const float*)d_in[21];
  const float* m2W1 = (const float*)d_in[22]; const float* m2b1 = (const float*)d_in[23];
  const float* m2W2 = (const float*)d_in[24]; const float* m2b2 = (const float*)d_in[25];
  const float* m2W3 = (const float*)d_in[26]; const float* m2b3 = (const float*)d_in[27];
  const float* m2a1 = (const float*)d_in[28]; const float* m2a2 = (const float*)d_in[29];
  const float* m2a3 = (const float*)d_in[30];
  const float* m2Ws = (const float*)d_in[31]; const float* m2bs = (const float*)d_in[32];
  const int* xidx  = (const int*)d_in[33];
  const int* ei    = (const int*)d_in[34];
  const int* batch = (const int*)d_in[35];
  float* out = (float*)d_out;
  char* W = (char*)d_ws;
  constexpr size_t MB = 1024u*1024u;

  unsigned* Abits  = (unsigned*)(W);
  unsigned* ATbits = (unsigned*)(W + 2*MB);
  int* cntD  = (int*)(W + 4*MB);
  int* cur   = (int*)(W + 4*MB + 16384);
  int* bcnt  = (int*)(W + 4*MB + 32768);
  int* cntAT = (int*)(W + 4*MB + 49152);
  int* degA  = (int*)(W + 4*MB + 65536);
  int* rpAT  = (int*)(W + 4*MB + 81920);
  int* rpD   = (int*)(W + 4*MB + 102400);
  int* gptr  = (int*)(W + 4*MB + 122880);
  float* di  = (float*)(W + 4*MB + 126976);
  float* dis = (float*)(W + 4*MB + 143360);
  float* dc  = (float*)(W + 4*MB + 159744);
  float* wv0 = (float*)(W + 4*MB + 176128);
  float* wv1 = (float*)(W + 4*MB + 192512);
  int* colAT = (int*)(W + 4*MB + 208896);
  int* srcD  = (int*)(W + 4*MB + 471040);
  float* xf  = (float*)(W + 6*MB);
  float* Px  = (float*)(W + 8*MB);
  float* XA  = (float*)(W + 10*MB);
  float* XB  = (float*)(W + 18*MB);
  float* Zb  = (float*)(W + 26*MB);
  float* Ub  = (float*)(W + 34*MB);
  float* z1s = (float*)(W + 42*MB);  // z1_1 then z1_2
  float* z21 = (float*)(W + 50*MB);
  float* z22 = (float*)(W + 58*MB);
  float* gv1 = (float*)(W + 66*MB);
  float* gv2 = (float*)(W + 66*MB + 262144);
  float* gs  = (float*)(W + 66*MB + 524288);
  float* gh1 = (float*)(W + 66*MB + 655360);
  float* gh2 = (float*)(W + 66*MB + 786432);
  float* sb  = Ub;   // reuse (U dead before MLPs)
  float* h1  = XA;   // reuse (solves done before MLPs)
  float* h2  = XB;

  // zero bitmaps + counters
  hipMemsetAsync(W, 0, 4*MB, stream);
  hipMemsetAsync(W + 4*MB, 0, 49152, stream);

  k_embed<<<NN, CIN, 0, stream>>>(cb, xidx, xf);
  k_scatter<<<NE/256, 256, 0, stream>>>(ei, Abits, ATbits, cntD);
  k_hist_batch<<<NN/256, 256, 0, stream>>>(batch, bcnt);
  k_popc_rows<<<1024, 256, 0, stream>>>(Abits, degA);
  k_popc_rows<<<1024, 256, 0, stream>>>(ATbits, cntAT);
  k_rsqrt1p<<<16, 256, 0, stream>>>(degA, di);
  k_rsqrt1p<<<16, 256, 0, stream>>>(cntD, dis);
  k_prefix<<<1, 1024, 0, stream>>>(cntAT, rpAT, NN);
  k_prefix<<<1, 1024, 0, stream>>>(cntD, rpD, NN);
  k_prefix<<<1, 1024, 0, stream>>>(bcnt, gptr, NG);
  k_fill_bits<<<1024, 256, 0, stream>>>(ATbits, rpAT, colAT);
  k_fill_edges<<<NE/256, 256, 0, stream>>>(ei, rpD, cur, srcD);

  // ---- tower 1 (sparse GCN) ----
  GEMM(128,128,0,0,0, xf, g1W0, Ub, nullptr, nullptr, nullptr, NN, HIDC, CIN);
  k_gcn_sp<<<1024, 256, 0, stream>>>(Ub, z1s, rpD, srcD, dis, g1b0, g1a);
  GEMM(128,128,0,0,0, z1s, g1W1, Ub, nullptr, nullptr, nullptr, NN, HIDC, HIDC);
  k_gcn_sp<<<1024, 256, 0, stream>>>(Ub, z21, rpD, srcD, dis, g1b1, g1a);
  k_segsum<<<NG, 256, 0, stream>>>(z1s, z21, gptr, gv1);

  // ---- column sums of S -> dc ----
  k_winit<<<16, 256, 0, stream>>>(wv0);
  {
    float* wc_ = wv0; float* wn_ = wv1;
    for (int k = 0; k < K_W; ++k){
      k_wstep<<<16, 256, 0, stream>>>(wc_, wn_, rpAT, colAT, di);
      float* t = wc_; wc_ = wn_; wn_ = t;
    }
    k_dc<<<16, 256, 0, stream>>>(wc_, dc);
  }

  // ---- tower 2 layer 1: P@x (128 cols), then GEMM ----
  k_prepZ<7><<<2048, 256, 0, stream>>>(xf, dc, Zb, XA);
  {
    float* xc = XA; float* xn = XB;
    for (int k = 0; k < K_SOLVE; ++k){
      k_bapply<128><<<1024, 256, 0, stream>>>(xc, Zb, xn, rpAT, colAT, di);
      float* t = xc; xc = xn; xn = t;
    }
    k_fin1<<<2048, 256, 0, stream>>>(xc, xf, dc, Px);
  }
  GEMM(128,128,1,0,1, Px, g2W0, z1s, g2b0, g2a, nullptr, NN, HIDC, CIN);

  // ---- tower 2 layer 2: U = z1*W1, then P@U (512 cols) ----
  GEMM(128,128,0,0,0, z1s, g2W1, Ub, nullptr, nullptr, nullptr, NN, HIDC, HIDC);
  k_prepZ<9><<<8192, 256, 0, stream>>>(Ub, dc, Zb, XA);
  {
    float* xc = XA; float* xn = XB;
    for (int k = 0; k < K_SOLVE; ++k){
      k_bapply<512><<<1024, 256, 0, stream>>>(xc, Zb, xn, rpAT, colAT, di);
      float* t = xc; xc = xn; xn = t;
    }
    k_fin2<<<8192, 256, 0, stream>>>(xc, Ub, dc, g2b1, g2a, z22);
  }
  k_segsum<<<NG, 256, 0, stream>>>(z1s, z22, gptr, gv2);

  // ---- MLP1 on lv1 = z21 -> out[0 : 2097152] ----
  GEMM(128,128,0,0,1, z21, m1Ws, sb, m1bs, nullptr, nullptr, NN, HIDC, HIDC);
  GEMM(128,128,2,0,1, z21, m1W1, h1, m1b1, m1a1, nullptr, NN, HIDC, HIDC);
  GEMM(128,128,2,0,1, h1, m1W2, h2, m1b2, m1a2, nullptr, NN, HIDC, HIDC);
  GEMM(128,128,2,1,1, h2, m1W3, out, m1b3, m1a3, sb, NN, HIDC, HIDC);

  // ---- MLP1 on lv2 = z22 -> out[2129920 : +2097152] ----
  GEMM(128,128,0,0,1, z22, m1Ws, sb, m1bs, nullptr, nullptr, NN, HIDC, HIDC);
  GEMM(128,128,2,0,1, z22, m1W1, h1, m1b1, m1a1, nullptr, NN, HIDC, HIDC);
  GEMM(128,128,2,0,1, h1, m1W2, h2, m1b2, m1a2, nullptr, NN, HIDC, HIDC);
  GEMM(128,128,2,1,1, h2, m1W3, out + 2129920, m1b3, m1a3, sb, NN, HIDC, HIDC);

  // ---- MLP2 on gv1 -> out[2097152 : +32768] ----
  GEMM(64,64,0,0,1, gv1, m2Ws, gs, m2bs, nullptr, nullptr, NG, HIDC, 1024);
  GEMM(64,64,2,0,1, gv1, m2W1, gh1, m2b1, m2a1, nullptr, NG, HIDC, 1024);
  GEMM(64,64,2,0,1, gh1, m2W2, gh2, m2b2, m2a2, nullptr, NG, HIDC, HIDC);
  GEMM(64,64,2,1,1, gh2, m2W3, out + 2097152, m2b3, m2a3, gs, NG, HIDC, HIDC);

  // ---- MLP2 on gv2 -> out[4227072 : +32768] ----
  GEMM(64,64,0,0,1, gv2, m2Ws, gs, m2bs, nullptr, nullptr, NG, HIDC, 1024);
  GEMM(64,64,2,0,1, gv2, m2W1, gh1, m2b1, m2a1, nullptr, NG, HIDC, 1024);
  GEMM(64,64,2,0,1, gh1, m2W2, gh2, m2b2, m2a2, nullptr, NG, HIDC, HIDC);
  GEMM(64,64,2,1,1, gh2, m2W3, out + 4227072, m2b3, m2a3, gs, NG, HIDC, HIDC);
}

// Round 2
// 1608.235 us; speedup vs baseline: 1.0165x; 1.0165x over previous
//
#include <hip/hip_runtime.h>

// MVGRL encoder, MI355X gfx950. Round 2: split-K MLP2, stacked MLP1, fused w-solve.
#define NN 4096
#define NE 65536
#define NBAG 16
#define BFD 8192
#define CIN 128
#define HIDC 512
#define NG 64
#define ALPHA_C 0.2f
#define BETA_C 0.8f
#define K_SOLVE 24
#define K_W 24

typedef __attribute__((ext_vector_type(8))) short short8;
typedef __attribute__((ext_vector_type(4))) float f32x4;
typedef __attribute__((ext_vector_type(2))) float f32x2;

__device__ __forceinline__ short f2bf(float f){
  unsigned u = __float_as_uint(f);
  u += 0x7fffu + ((u >> 16) & 1u);
  return (short)(u >> 16);
}

// ---------- embedding bag (mean, padding idx = BFD) ----------
__global__ void k_embed(const float* __restrict__ cb, const int* __restrict__ xidx,
                        float* __restrict__ xf){
  int n = blockIdx.x, c = threadIdx.x;
  float acc = 0.f; int cnt = 0;
  #pragma unroll
  for (int b = 0; b < NBAG; ++b){
    int id = xidx[n*NBAG + b];
    if (id != BFD){ acc += cb[(size_t)id*CIN + c]; ++cnt; }
  }
  xf[(size_t)n*CIN + c] = acc / (float)(cnt > 0 ? cnt : 1);
}

// ---------- graph prep ----------
__global__ void k_scatter(const int* __restrict__ ei, unsigned* __restrict__ Ab,
                          unsigned* __restrict__ ATb, int* __restrict__ cntD){
  int e = blockIdx.x*256 + threadIdx.x;
  if (e >= NE) return;
  int s = ei[e], d = ei[NE + e];
  atomicOr(&Ab[s*128 + (d >> 5)], 1u << (d & 31));
  atomicOr(&ATb[d*128 + (s >> 5)], 1u << (s & 31));
  atomicAdd(&cntD[d], 1);
}

__global__ void k_hist_batch(const int* __restrict__ batch, int* __restrict__ bcnt){
  int n = blockIdx.x*256 + threadIdx.x;
  if (n >= NN) return;
  atomicAdd(&bcnt[batch[n]], 1);
}

// popcount rows of BOTH bitmaps (wid<NN -> A, else AT)
__global__ void k_popc2(const unsigned* __restrict__ Ab, const unsigned* __restrict__ ATb,
                        int* __restrict__ degA, int* __restrict__ cntAT){
  int wid = (blockIdx.x*blockDim.x + threadIdx.x) >> 6;
  int lane = threadIdx.x & 63;
  if (wid >= 2*NN) return;
  const unsigned* bits; int* o; int r;
  if (wid < NN){ bits = Ab; r = wid; o = degA; }
  else { bits = ATb; r = wid - NN; o = cntAT; }
  int s = __popc(bits[r*128 + lane]) + __popc(bits[r*128 + 64 + lane]);
  #pragma unroll
  for (int off = 32; off > 0; off >>= 1) s += __shfl_down(s, off);
  if (lane == 0) o[r] = s;
}

__global__ void k_rsqrt2(const int* __restrict__ degA, const int* __restrict__ cntD,
                         float* __restrict__ di, float* __restrict__ dis){
  int i = blockIdx.x*256 + threadIdx.x;
  if (i >= NN) return;
  di[i]  = rsqrtf((float)degA[i] + 1.0f);
  dis[i] = rsqrtf((float)cntD[i] + 1.0f);
}

// three exclusive prefix sums in one launch (block 0/1/2)
__global__ void k_prefix3(const int* __restrict__ c0, int* __restrict__ r0, int n0,
                          const int* __restrict__ c1, int* __restrict__ r1, int n1,
                          const int* __restrict__ c2, int* __restrict__ r2, int n2){
  const int* cnt; int* rp; int n;
  if (blockIdx.x == 0){ cnt = c0; rp = r0; n = n0; }
  else if (blockIdx.x == 1){ cnt = c1; rp = r1; n = n1; }
  else { cnt = c2; rp = r2; n = n2; }
  __shared__ int a[4096];
  __shared__ int ps[1024];
  int t = threadIdx.x;
  for (int i = t; i < 4096; i += 1024) a[i] = (i < n) ? cnt[i] : 0;
  __syncthreads();
  int b0 = a[t*4], b1 = a[t*4+1], b2 = a[t*4+2], b3 = a[t*4+3];
  int s0 = b0, s1 = s0+b1, s2 = s1+b2, s3 = s2+b3;
  ps[t] = s3;
  __syncthreads();
  for (int off = 1; off < 1024; off <<= 1){
    int v = ps[t];
    int u = (t >= off) ? ps[t-off] : 0;
    __syncthreads();
    ps[t] = v + u;
    __syncthreads();
  }
  int excl = (t > 0) ? ps[t-1] : 0;
  int base = t*4;
  if (base     < n) rp[base]   = excl;
  if (base + 1 < n) rp[base+1] = excl + s0;
  if (base + 2 < n) rp[base+2] = excl + s1;
  if (base + 3 < n) rp[base+3] = excl + s2;
  if (t == 1023) rp[n] = ps[1023];
}

__global__ void k_fill_bits(const unsigned* __restrict__ bits, const int* __restrict__ rp,
                            int* __restrict__ colidx){
  int wid = (blockIdx.x*blockDim.x + threadIdx.x) >> 6;
  int lane = threadIdx.x & 63;
  if (wid >= NN) return;
  unsigned w0 = bits[wid*128 + lane];
  unsigned w1 = bits[wid*128 + 64 + lane];
  int c = __popc(w0) + __popc(w1);
  int x = c;
  #pragma unroll
  for (int d = 1; d < 64; d <<= 1){
    int y = __shfl_up(x, d);
    if (lane >= d) x += y;
  }
  int pos = rp[wid] + (x - c);
  while (w0){ int b = __ffs(w0) - 1; w0 &= w0 - 1; colidx[pos++] = lane*32 + b; }
  while (w1){ int b = __ffs(w1) - 1; w1 &= w1 - 1; colidx[pos++] = (64 + lane)*32 + b; }
}

__global__ void k_fill_edges(const int* __restrict__ ei, const int* __restrict__ rp,
                             int* __restrict__ cur, int* __restrict__ srcs){
  int e = blockIdx.x*256 + threadIdx.x;
  if (e >= NE) return;
  int s = ei[e], d = ei[NE + e];
  int pos = atomicAdd(&cur[d], 1);
  srcs[rp[d] + pos] = s;
}

// ---------- sparse-tower GCN aggregation (wave per row) ----------
__global__ __launch_bounds__(256) void k_gcn_sp(const float* __restrict__ U, float* __restrict__ out,
    const int* __restrict__ rp, const int* __restrict__ srcs, const float* __restrict__ dis,
    const float* __restrict__ bias, const float* __restrict__ avec){
  int wid = (blockIdx.x*256 + threadIdx.x) >> 6;
  int lane = threadIdx.x & 63;
  if (wid >= NN) return;
  int j = wid;
  f32x4 a0 = {0,0,0,0}, a1 = {0,0,0,0};
  int b = rp[j], e = rp[j+1];
  for (int k = b; k < e; ++k){
    int s = srcs[k]; float w = dis[s];
    const f32x4* Us = (const f32x4*)(U + (size_t)s*HIDC);
    a0 += w*Us[lane]; a1 += w*Us[64+lane];
  }
  float dj = dis[j];
  const f32x4* Uj = (const f32x4*)(U + (size_t)j*HIDC);
  a0 += dj*Uj[lane]; a1 += dj*Uj[64+lane];
  float* op = out + (size_t)j*HIDC;
  #pragma unroll
  for (int v = 0; v < 4; ++v){
    int c0 = lane*4 + v, c1 = 256 + lane*4 + v;
    float x0 = dj*a0[v] + bias[c0]; float p0 = avec[c0];
    op[c0] = x0 >= 0.f ? x0 : p0*x0;
    float x1 = dj*a1[v] + bias[c1]; float p1 = avec[c1];
    op[c1] = x1 >= 0.f ? x1 : p1*x1;
  }
}

// ---------- one Neumann step: Xn = Z + 0.8 * An^T * X ----------
template<int C>
__global__ __launch_bounds__(256) void k_bapply(const float* __restrict__ X, const float* __restrict__ Z,
    float* __restrict__ Xn, const int* __restrict__ rp, const int* __restrict__ cols,
    const float* __restrict__ di){
  int wid = (blockIdx.x*256 + threadIdx.x) >> 6;
  int lane = threadIdx.x & 63;
  if (wid >= NN) return;
  int j = wid;
  int b = rp[j], e = rp[j+1];
  float dj = di[j];
  if constexpr (C == 512){
    f32x4 a0 = {0,0,0,0}, a1 = {0,0,0,0};
    for (int k = b; k < e; ++k){
      int i = cols[k]; float w = di[i];
      const f32x4* Xi = (const f32x4*)(X + (size_t)i*512);
      a0 += w*Xi[lane]; a1 += w*Xi[64+lane];
    }
    const f32x4* Xj = (const f32x4*)(X + (size_t)j*512);
    a0 += dj*Xj[lane]; a1 += dj*Xj[64+lane];
    const f32x4* Zj = (const f32x4*)(Z + (size_t)j*512);
    f32x4* Oj = (f32x4*)(Xn + (size_t)j*512);
    Oj[lane]    = Zj[lane]    + (BETA_C*dj)*a0;
    Oj[64+lane] = Zj[64+lane] + (BETA_C*dj)*a1;
  } else {
    f32x2 a0 = {0,0};
    for (int k = b; k < e; ++k){
      int i = cols[k]; float w = di[i];
      const f32x2* Xi = (const f32x2*)(X + (size_t)i*128);
      a0 += w*Xi[lane];
    }
    const f32x2* Xj = (const f32x2*)(X + (size_t)j*128);
    a0 += dj*Xj[lane];
    const f32x2* Zj = (const f32x2*)(Z + (size_t)j*128);
    f32x2* Oj = (f32x2*)(Xn + (size_t)j*128);
    Oj[lane] = Zj[lane] + (BETA_C*dj)*a0;
  }
}

// ---------- fused w (column-sum of S) solve: one block, LDS-resident ----------
__global__ __launch_bounds__(1024) void k_wsolve(const int* __restrict__ rp, const int* __restrict__ cols,
                                                 const float* __restrict__ di, float* __restrict__ dc){
  __shared__ float w[NN];
  __shared__ float wn[NN];
  __shared__ float ds[NN];
  __shared__ int rps[NN + 1];
  int t = threadIdx.x;
  for (int i = t; i < NN; i += 1024){ w[i] = ALPHA_C; ds[i] = di[i]; rps[i] = rp[i]; }
  if (t == 0) rps[NN] = rp[NN];
  __syncthreads();
  for (int it = 0; it < K_W; ++it){
    for (int j = t; j < NN; j += 1024){
      float acc = 0.f;
      int b = rps[j], e = rps[j+1];
      for (int k = b; k < e; ++k){ int i = cols[k]; acc += ds[i]*w[i]; }
      float dj = ds[j];
      wn[j] = ALPHA_C + BETA_C*dj*(acc + dj*w[j]);
    }
    __syncthreads();
    for (int j = t; j < NN; j += 1024) w[j] = wn[j];
    __syncthreads();
  }
  for (int i = t; i < NN; i += 1024) dc[i] = rsqrtf(fmaxf(w[i] + 1.0f, 1e-12f));
}

// ---------- elementwise helpers ----------
__global__ void k_prepZ128(const float* __restrict__ in, const float* __restrict__ dc,
                           float* __restrict__ Z, float* __restrict__ X0){
  int idx = blockIdx.x*256 + threadIdx.x;
  if (idx >= NN*CIN) return;
  float v = ALPHA_C * dc[idx >> 7] * in[idx];
  Z[idx] = v; X0[idx] = v;
}
__global__ void k_fin1(const float* __restrict__ X, const float* __restrict__ xf,
                       const float* __restrict__ dc, float* __restrict__ Px){
  int idx = blockIdx.x*256 + threadIdx.x;
  if (idx >= NN*CIN) return;
  float d = dc[idx >> 7];
  Px[idx] = d*(X[idx] + d*xf[idx]);
}
__global__ void k_fin2(const float* __restrict__ X, const float* __restrict__ U,
                       const float* __restrict__ dc, const float* __restrict__ bias,
                       const float* __restrict__ avec, float* __restrict__ out){
  int idx = blockIdx.x*256 + threadIdx.x;
  if (idx >= NN*HIDC) return;
  int i = idx >> 9, c = idx & 511;
  float d = dc[i];
  float v = d*(X[idx] + d*U[idx]) + bias[c];
  float a = avec[c];
  out[idx] = v >= 0.f ? v : a*v;
}

// ---------- segment sum -> [NG, 1024] ----------
__global__ void k_segsum(const float* __restrict__ z1, const float* __restrict__ z2,
                         const int* __restrict__ gptr, float* __restrict__ gv){
  int g = blockIdx.x, t = threadIdx.x;
  float s0 = 0, s1 = 0, s2 = 0, s3 = 0;
  int rb = gptr[g], re = gptr[g+1];
  for (int r = rb; r < re; ++r){
    s0 += z1[(size_t)r*HIDC + t];       s1 += z1[(size_t)r*HIDC + 256 + t];
    s2 += z2[(size_t)r*HIDC + t];       s3 += z2[(size_t)r*HIDC + 256 + t];
  }
  gv[g*1024 + t] = s0; gv[g*1024 + 256 + t] = s1;
  gv[g*1024 + 512 + t] = s2; gv[g*1024 + 768 + t] = s3;
}

// ---------- bf16 MFMA GEMM ----------
// KC==0: full-K, epilogue bias/act/addm, optional SPLIT (row>=4096 -> C2), optional ZOUT.
// KC>0 : split-K partial; writes raw acc to C at [blockIdx.z][M][Nn].
template<int BM, int BN, int ACT, int ADDM, int BIAS, int KC, int SPLIT, int ZOUT>
__global__ __launch_bounds__(256) void k_gemm(
    const float* __restrict__ A, const float* __restrict__ B,
    float* __restrict__ C, const float* __restrict__ bias,
    const float* __restrict__ ap, const float* __restrict__ addm,
    float* __restrict__ C2, float* __restrict__ zb, float* __restrict__ xa,
    const float* __restrict__ dcv,
    int M, int Nn, int K)
{
  __shared__ __align__(16) short As[BM][40];
  __shared__ __align__(16) short Bs[BN][40];
  const int tid = threadIdx.x;
  const int bm0 = blockIdx.y*BM, bn0 = blockIdx.x*BN;
  const int lane = tid & 63, wv = tid >> 6;
  const int wr = wv >> 1, wc = wv & 1;
  constexpr int MR = BM/32, NR = BN/32;
  f32x4 acc[MR][NR];
  #pragma unroll
  for (int i = 0; i < MR; ++i)
    #pragma unroll
    for (int j = 0; j < NR; ++j) acc[i][j] = (f32x4){0.f,0.f,0.f,0.f};
  const int r0 = wr*(BM/2), c0 = wc*(BN/2);
  constexpr int EA = BM*32/256;
  constexpr int EB = BN*32/256;
  const int arow = (tid*EA) >> 5, acol = (tid*EA) & 31;
  const int bkr = (tid*EB) / BN, bnc = (tid*EB) % BN;
  int k0 = 0, k1 = K;
  if constexpr (KC > 0){ k0 = blockIdx.z*KC; k1 = k0 + KC; }
  for (int kt = k0; kt < k1; kt += 32){
    __syncthreads();
    {
      const float* src = A + (size_t)(bm0 + arow)*K + kt + acol;
      short tmp[EA] __attribute__((aligned(16)));
      #pragma unroll
      for (int q = 0; q < EA; q += 4){
        f32x4 v = *(const f32x4*)(src + q);
        tmp[q+0] = f2bf(v[0]); tmp[q+1] = f2bf(v[1]);
        tmp[q+2] = f2bf(v[2]); tmp[q+3] = f2bf(v[3]);
      }
      #pragma unroll
      for (int q = 0; q < EA; q += 8)
        *(short8*)&As[arow][acol + q] = *(const short8*)&tmp[q];
    }
    {
      const float* src = B + (size_t)(kt + bkr)*Nn + bn0 + bnc;
      #pragma unroll
      for (int q = 0; q < EB; q += 4){
        f32x4 v = *(const f32x4*)(src + q);
        Bs[bnc+q+0][bkr] = f2bf(v[0]);
        Bs[bnc+q+1][bkr] = f2bf(v[1]);
        Bs[bnc+q+2][bkr] = f2bf(v[2]);
        Bs[bnc+q+3][bkr] = f2bf(v[3]);
      }
    }
    __syncthreads();
    short8 af[MR], bfv[NR];
    #pragma unroll
    for (int mi = 0; mi < MR; ++mi)
      af[mi] = *(const short8*)&As[r0 + mi*16 + (lane & 15)][(lane >> 4)*8];
    #pragma unroll
    for (int ni = 0; ni < NR; ++ni)
      bfv[ni] = *(const short8*)&Bs[c0 + ni*16 + (lane & 15)][(lane >> 4)*8];
    #pragma unroll
    for (int mi = 0; mi < MR; ++mi)
      #pragma unroll
      for (int ni = 0; ni < NR; ++ni)
        acc[mi][ni] = __builtin_amdgcn_mfma_f32_16x16x32_bf16(af[mi], bfv[ni], acc[mi][ni], 0, 0, 0);
  }
  #pragma unroll
  for (int mi = 0; mi < MR; ++mi){
    #pragma unroll
    for (int ni = 0; ni < NR; ++ni){
      int col = bn0 + c0 + ni*16 + (lane & 15);
      #pragma unroll
      for (int q = 0; q < 4; ++q){
        int row = bm0 + r0 + mi*16 + ((lane >> 4) << 2) + q;
        float v = acc[mi][ni][q];
        if constexpr (KC > 0){
          C[(size_t)blockIdx.z*M*Nn + (size_t)row*Nn + col] = v;
        } else {
          if constexpr (BIAS) v += bias[col];
          if constexpr (ACT == 1){ float a = ap[col]; v = v >= 0.f ? v : a*v; }
          if constexpr (ACT == 2){ float a = ap[0];   v = v >= 0.f ? v : a*v; }
          if constexpr (ADDM) v += addm[(size_t)row*Nn + col];
          if constexpr (SPLIT){
            float* dst = (row < NN) ? (C + (size_t)row*Nn) : (C2 + (size_t)(row - NN)*Nn);
            dst[col] = v;
          } else {
            C[(size_t)row*Nn + col] = v;
          }
          if constexpr (ZOUT){
            float d = ALPHA_C * dcv[row];
            size_t id = (size_t)row*Nn + col;
            float zv = d * v;
            zb[id] = zv; xa[id] = zv;
          }
        }
      }
    }
  }
}

// split-K reduce + epilogue. SPLIT: rows<64 -> C, rows>=64 -> C2.
template<int ACT, int ADDM, int SPLIT>
__global__ void k_red(const float* __restrict__ part, int KS,
                      const float* __restrict__ bias, const float* __restrict__ ap,
                      const float* __restrict__ addm,
                      float* __restrict__ C, float* __restrict__ C2,
                      int M, int Nn){
  int idx = blockIdx.x*256 + threadIdx.x;
  if (idx >= M*Nn) return;
  float v = 0.f;
  for (int z = 0; z < KS; ++z) v += part[(size_t)z*M*Nn + idx];
  int row = idx / Nn, col = idx - row*Nn;
  v += bias[col];
  if constexpr (ACT){ float a = ap[0]; v = v >= 0.f ? v : a*v; }
  if constexpr (ADDM) v += addm[idx];
  if constexpr (SPLIT){
    if (row < NG) C[(size_t)row*Nn + col] = v;
    else C2[(size_t)(row - NG)*Nn + col] = v;
  } else {
    C[idx] = v;
  }
}

extern "C" void kernel_launch(void* const* d_in, const int* in_sizes, int n_in,
                              void* d_out, int out_size, void* d_ws, size_t ws_size,
                              hipStream_t stream) {
  const float* cb   = (const float*)d_in[0];
  const float* g1W0 = (const float*)d_in[1];  const float* g1b0 = (const float*)d_in[2];
  const float* g1W1 = (const float*)d_in[3];  const float* g1b1 = (const float*)d_in[4];
  const float* g1a  = (const float*)d_in[5];
  const float* g2W0 = (const float*)d_in[6];  const float* g2b0 = (const float*)d_in[7];
  const float* g2W1 = (const float*)d_in[8];  const float* g2b1 = (const float*)d_in[9];
  const float* g2a  = (const float*)d_in[10];
  const float* m1W1 = (const float*)d_in[11]; const float* m1b1 = (const float*)d_in[12];
  const float* m1W2 = (const float*)d_in[13]; const float* m1b2 = (const float*)d_in[14];
  const float* m1W3 = (const float*)d_in[15]; const float* m1b3 = (const float*)d_in[16];
  const float* m1a1 = (const float*)d_in[17]; const float* m1a2 = (const float*)d_in[18];
  const float* m1a3 = (const float*)d_in[19];
  const float* m1Ws = (const float*)d_in[20]; const float* m1bs = (const float*)d_in[21];
  const float* m2W1 = (const float*)d_in[22]; const float* m2b1 = (const float*)d_in[23];
  const float* m2W2 = (const float*)d_in[24]; const float* m2b2 = (const float*)d_in[25];
  const float* m2W3 = (const float*)d_in[26]; const float* m2b3 = (const float*)d_in[27];
  const float* m2a1 = (const float*)d_in[28]; const float* m2a2 = (const float*)d_in[29];
  const float* m2a3 = (const float*)d_in[30];
  const float* m2Ws = (const float*)d_in[31]; const float* m2bs = (const float*)d_in[32];
  const int* xidx  = (const int*)d_in[33];
  const int* ei    = (const int*)d_in[34];
  const int* batch = (const int*)d_in[35];
  float* out = (float*)d_out;
  char* W = (char*)d_ws;
  constexpr size_t MB = 1024u*1024u;
  constexpr size_t KB = 1024u;

  // ---- workspace layout ----
  unsigned* Abits  = (unsigned*)(W);            // 0-2MB (dead after prep)
  unsigned* ATbits = (unsigned*)(W + 2*MB);     // 2-4MB (dead after prep)
  char* M4 = W + 4*MB;                          // meta block 4.0-4.5MB
  int* cntD  = (int*)(M4);
  int* cur   = (int*)(M4 + 16*KB);
  int* bcnt  = (int*)(M4 + 32*KB);
  int* cntAT = (int*)(M4 + 48*KB);
  int* degA  = (int*)(M4 + 64*KB);
  int* rpAT  = (int*)(M4 + 80*KB);
  int* rpD   = (int*)(M4 + 100*KB);
  int* gptr  = (int*)(M4 + 120*KB);
  float* di  = (float*)(M4 + 124*KB);
  float* dis = (float*)(M4 + 140*KB);
  float* dc  = (float*)(M4 + 156*KB);
  int* colAT = (int*)(W + 4*MB + 512*KB);       // 256KB
  int* srcD  = (int*)(W + 4*MB + 768*KB);       // 256KB
  float* gv  = (float*)(W + 5*MB);              // [128,1024] stacked gv1|gv2, 512KB
  float* gh1 = (float*)(W + 5*MB + 512*KB);     // [128,512] 256KB
  float* gh2 = (float*)(W + 5*MB + 768*KB);     // [128,512] 256KB
  float* xf  = (float*)(W + 6*MB);              // [4096,128]
  float* Px  = (float*)(W + 8*MB);              // [4096,128] (dead after tower2 L1 GEMM)
  float* gsb = (float*)(W + 8*MB);              // [128,512] reuses Px region in MLP2
  float* XA  = (float*)(W + 10*MB);
  float* XB  = (float*)(W + 18*MB);
  float* Zb  = (float*)(W + 26*MB);
  float* Ub  = (float*)(W + 34*MB);
  float* z1s = (float*)(W + 42*MB);             // tower z1 (both towers, sequential)
  float* zs  = (float*)(W + 50*MB);             // stacked [8192,512]: z21|z22
  float* z21 = zs;
  float* z22 = (float*)(W + 58*MB);
  float* gpart = (float*)(W);                   // MLP2 split-K partials, <=4MB (bitmaps dead)
  float* sb  = (float*)(W + 10*MB);             // [8192,512] 16MB (over XA|XB, dead)
  float* h1  = (float*)(W + 26*MB);             // [8192,512] 16MB (over Zb|Ub, dead)
  float* h2  = zs;                              // [8192,512] overwrites zs after consumed

  hipMemsetAsync(W, 0, 4*MB, stream);           // bitmaps
  hipMemsetAsync(M4, 0, 64*KB, stream);         // cntD, cur, bcnt, cntAT

  k_embed<<<NN, CIN, 0, stream>>>(cb, xidx, xf);
  k_scatter<<<NE/256, 256, 0, stream>>>(ei, Abits, ATbits, cntD);
  k_hist_batch<<<NN/256, 256, 0, stream>>>(batch, bcnt);
  k_popc2<<<2048, 256, 0, stream>>>(Abits, ATbits, degA, cntAT);
  k_rsqrt2<<<16, 256, 0, stream>>>(degA, cntD, di, dis);
  k_prefix3<<<3, 1024, 0, stream>>>(cntAT, rpAT, NN, cntD, rpD, NN, bcnt, gptr, NG);
  k_fill_bits<<<1024, 256, 0, stream>>>(ATbits, rpAT, colAT);
  k_fill_edges<<<NE/256, 256, 0, stream>>>(ei, rpD, cur, srcD);

  // ---- tower 1 (sparse GCN) ----
  k_gemm<128,128,0,0,0,0,0,0><<<dim3(HIDC/128, NN/128), 256, 0, stream>>>(
      xf, g1W0, Ub, nullptr, nullptr, nullptr, nullptr, nullptr, nullptr, nullptr, NN, HIDC, CIN);
  k_gcn_sp<<<1024, 256, 0, stream>>>(Ub, z1s, rpD, srcD, dis, g1b0, g1a);
  k_gemm<128,128,0,0,0,0,0,0><<<dim3(HIDC/128, NN/128), 256, 0, stream>>>(
      z1s, g1W1, Ub, nullptr, nullptr, nullptr, nullptr, nullptr, nullptr, nullptr, NN, HIDC, HIDC);
  k_gcn_sp<<<1024, 256, 0, stream>>>(Ub, z21, rpD, srcD, dis, g1b1, g1a);
  k_segsum<<<NG, 256, 0, stream>>>(z1s, z21, gptr, gv);

  // ---- fused w-solve -> dc ----
  k_wsolve<<<1, 1024, 0, stream>>>(rpAT, colAT, di, dc);

  // ---- tower 2 layer 1: P@x (128 cols) ----
  k_prepZ128<<<2048, 256, 0, stream>>>(xf, dc, Zb, XA);
  {
    float* xc = XA; float* xn = XB;
    for (int k = 0; k < K_SOLVE; ++k){
      k_bapply<128><<<1024, 256, 0, stream>>>(xc, Zb, xn, rpAT, colAT, di);
      float* t = xc; xc = xn; xn = t;
    }
    k_fin1<<<2048, 256, 0, stream>>>(xc, xf, dc, Px);
  }
  k_gemm<128,128,1,0,1,0,0,0><<<dim3(HIDC/128, NN/128), 256, 0, stream>>>(
      Px, g2W0, z1s, g2b0, g2a, nullptr, nullptr, nullptr, nullptr, nullptr, NN, HIDC, CIN);

  // ---- tower 2 layer 2: U = z1*W1 (fused prepZ via ZOUT), then P@U (512 cols) ----
  k_gemm<128,128,0,0,0,0,0,1><<<dim3(HIDC/128, NN/128), 256, 0, stream>>>(
      z1s, g2W1, Ub, nullptr, nullptr, nullptr, nullptr, Zb, XA, dc, NN, HIDC, HIDC);
  {
    float* xc = XA; float* xn = XB;
    for (int k = 0; k < K_SOLVE; ++k){
      k_bapply<512><<<1024, 256, 0, stream>>>(xc, Zb, xn, rpAT, colAT, di);
      float* t = xc; xc = xn; xn = t;
    }
    k_fin2<<<8192, 256, 0, stream>>>(xc, Ub, dc, g2b1, g2a, z22);
  }
  k_segsum<<<NG, 256, 0, stream>>>(z1s, z22, gptr, gv + 64*1024);

  // ---- MLP1 on stacked zs = [z21|z22], M=8192 ----
  k_gemm<128,128,0,0,1,0,0,0><<<dim3(HIDC/128, 8192/128), 256, 0, stream>>>(
      zs, m1Ws, sb, m1bs, nullptr, nullptr, nullptr, nullptr, nullptr, nullptr, 8192, HIDC, HIDC);
  k_gemm<128,128,2,0,1,0,0,0><<<dim3(HIDC/128, 8192/128), 256, 0, stream>>>(
      zs, m1W1, h1, m1b1, m1a1, nullptr, nullptr, nullptr, nullptr, nullptr, 8192, HIDC, HIDC);
  k_gemm<128,128,2,0,1,0,0,0><<<dim3(HIDC/128, 8192/128), 256, 0, stream>>>(
      h1, m1W2, h2, m1b2, m1a2, nullptr, nullptr, nullptr, nullptr, nullptr, 8192, HIDC, HIDC);
  k_gemm<128,128,2,1,1,0,1,0><<<dim3(HIDC/128, 8192/128), 256, 0, stream>>>(
      h2, m1W3, out, m1b3, m1a3, sb, out + 2129920, nullptr, nullptr, nullptr, 8192, HIDC, HIDC);

  // ---- MLP2 on stacked gv [128,1024], split-K ----
  // gsb = gv@m2Ws + m2bs
  k_gemm<64,64,0,0,0,64,0,0><<<dim3(HIDC/64, 128/64, 16), 256, 0, stream>>>(
      gv, m2Ws, gpart, nullptr, nullptr, nullptr, nullptr, nullptr, nullptr, nullptr, 128, HIDC, 1024);
  k_red<0,0,0><<<256, 256, 0, stream>>>(gpart, 16, m2bs, nullptr, nullptr, gsb, nullptr, 128, HIDC);
  // gh1 = act(gv@m2W1 + b1)
  k_gemm<64,64,0,0,0,64,0,0><<<dim3(HIDC/64, 128/64, 16), 256, 0, stream>>>(
      gv, m2W1, gpart, nullptr, nullptr, nullptr, nullptr, nullptr, nullptr, nullptr, 128, HIDC, 1024);
  k_red<1,0,0><<<256, 256, 0, stream>>>(gpart, 16, m2b1, m2a1, nullptr, gh1, nullptr, 128, HIDC);
  // gh2 = act(gh1@m2W2 + b2)
  k_gemm<64,64,0,0,0,64,0,0><<<dim3(HIDC/64, 128/64, 8), 256, 0, stream>>>(
      gh1, m2W2, gpart, nullptr, nullptr, nullptr, nullptr, nullptr, nullptr, nullptr, 128, HIDC, HIDC);
  k_red<1,0,0><<<256, 256, 0, stream>>>(gpart, 8, m2b2, m2a2, nullptr, gh2, nullptr, 128, HIDC);
  // final = act(gh2@m2W3 + b3) + gsb -> out split (rows<64 -> gv1 out, else gv2 out)
  k_gemm<64,64,0,0,0,64,0,0><<<dim3(HIDC/64, 128/64, 8), 256, 0, stream>>>(
      gh2, m2W3, gpart, nullptr, nullptr, nullptr, nullptr, nullptr, nullptr, nullptr, 128, HIDC, HIDC);
  k_red<1,1,1><<<256, 256, 0, stream>>>(gpart, 8, m2b3, m2a3, gsb, out + 2097152, out + 4227072, 128, HIDC);
}

// Round 3
// 1222.634 us; speedup vs baseline: 1.3370x; 1.3154x over previous
//
#include <hip/hip_runtime.h>

// MVGRL encoder, MI355X gfx950. Round 3: parallel w-steps, fused solve epilogues.
#define NN 4096
#define NE 65536
#define NBAG 16
#define BFD 8192
#define CIN 128
#define HIDC 512
#define NG 64
#define ALPHA_C 0.2f
#define BETA_C 0.8f
#define K_SOLVE 24
#define K_W 24

typedef __attribute__((ext_vector_type(8))) short short8;
typedef __attribute__((ext_vector_type(4))) float f32x4;
typedef __attribute__((ext_vector_type(2))) float f32x2;

__device__ __forceinline__ short f2bf(float f){
  unsigned u = __float_as_uint(f);
  u += 0x7fffu + ((u >> 16) & 1u);
  return (short)(u >> 16);
}

// ---------- embedding bag (mean, padding idx = BFD) ----------
__global__ void k_embed(const float* __restrict__ cb, const int* __restrict__ xidx,
                        float* __restrict__ xf){
  int n = blockIdx.x, c = threadIdx.x;
  float acc = 0.f; int cnt = 0;
  #pragma unroll
  for (int b = 0; b < NBAG; ++b){
    int id = xidx[n*NBAG + b];
    if (id != BFD){ acc += cb[(size_t)id*CIN + c]; ++cnt; }
  }
  xf[(size_t)n*CIN + c] = acc / (float)(cnt > 0 ? cnt : 1);
}

// ---------- graph prep ----------
__global__ void k_scatter(const int* __restrict__ ei, unsigned* __restrict__ Ab,
                          unsigned* __restrict__ ATb, int* __restrict__ cntD){
  int e = blockIdx.x*256 + threadIdx.x;
  if (e >= NE) return;
  int s = ei[e], d = ei[NE + e];
  atomicOr(&Ab[s*128 + (d >> 5)], 1u << (d & 31));
  atomicOr(&ATb[d*128 + (s >> 5)], 1u << (s & 31));
  atomicAdd(&cntD[d], 1);
}

__global__ void k_hist_batch(const int* __restrict__ batch, int* __restrict__ bcnt){
  int n = blockIdx.x*256 + threadIdx.x;
  if (n >= NN) return;
  atomicAdd(&bcnt[batch[n]], 1);
}

__global__ void k_popc2(const unsigned* __restrict__ Ab, const unsigned* __restrict__ ATb,
                        int* __restrict__ degA, int* __restrict__ cntAT){
  int wid = (blockIdx.x*blockDim.x + threadIdx.x) >> 6;
  int lane = threadIdx.x & 63;
  if (wid >= 2*NN) return;
  const unsigned* bits; int* o; int r;
  if (wid < NN){ bits = Ab; r = wid; o = degA; }
  else { bits = ATb; r = wid - NN; o = cntAT; }
  int s = __popc(bits[r*128 + lane]) + __popc(bits[r*128 + 64 + lane]);
  #pragma unroll
  for (int off = 32; off > 0; off >>= 1) s += __shfl_down(s, off);
  if (lane == 0) o[r] = s;
}

__global__ void k_rsqrt2(const int* __restrict__ degA, const int* __restrict__ cntD,
                         float* __restrict__ di, float* __restrict__ dis){
  int i = blockIdx.x*256 + threadIdx.x;
  if (i >= NN) return;
  di[i]  = rsqrtf((float)degA[i] + 1.0f);
  dis[i] = rsqrtf((float)cntD[i] + 1.0f);
}

// three exclusive prefix sums in one launch
__global__ void k_prefix3(const int* __restrict__ c0, int* __restrict__ r0, int n0,
                          const int* __restrict__ c1, int* __restrict__ r1, int n1,
                          const int* __restrict__ c2, int* __restrict__ r2, int n2){
  const int* cnt; int* rp; int n;
  if (blockIdx.x == 0){ cnt = c0; rp = r0; n = n0; }
  else if (blockIdx.x == 1){ cnt = c1; rp = r1; n = n1; }
  else { cnt = c2; rp = r2; n = n2; }
  __shared__ int a[4096];
  __shared__ int ps[1024];
  int t = threadIdx.x;
  for (int i = t; i < 4096; i += 1024) a[i] = (i < n) ? cnt[i] : 0;
  __syncthreads();
  int b0 = a[t*4], b1 = a[t*4+1], b2 = a[t*4+2], b3 = a[t*4+3];
  int s0 = b0, s1 = s0+b1, s2 = s1+b2, s3 = s2+b3;
  ps[t] = s3;
  __syncthreads();
  for (int off = 1; off < 1024; off <<= 1){
    int v = ps[t];
    int u = (t >= off) ? ps[t-off] : 0;
    __syncthreads();
    ps[t] = v + u;
    __syncthreads();
  }
  int excl = (t > 0) ? ps[t-1] : 0;
  int base = t*4;
  if (base     < n) rp[base]   = excl;
  if (base + 1 < n) rp[base+1] = excl + s0;
  if (base + 2 < n) rp[base+2] = excl + s1;
  if (base + 3 < n) rp[base+3] = excl + s2;
  if (t == 1023) rp[n] = ps[1023];
}

__global__ void k_fill_bits(const unsigned* __restrict__ bits, const int* __restrict__ rp,
                            int* __restrict__ colidx){
  int wid = (blockIdx.x*blockDim.x + threadIdx.x) >> 6;
  int lane = threadIdx.x & 63;
  if (wid >= NN) return;
  unsigned w0 = bits[wid*128 + lane];
  unsigned w1 = bits[wid*128 + 64 + lane];
  int c = __popc(w0) + __popc(w1);
  int x = c;
  #pragma unroll
  for (int d = 1; d < 64; d <<= 1){
    int y = __shfl_up(x, d);
    if (lane >= d) x += y;
  }
  int pos = rp[wid] + (x - c);
  while (w0){ int b = __ffs(w0) - 1; w0 &= w0 - 1; colidx[pos++] = lane*32 + b; }
  while (w1){ int b = __ffs(w1) - 1; w1 &= w1 - 1; colidx[pos++] = (64 + lane)*32 + b; }
}

__global__ void k_fill_edges(const int* __restrict__ ei, const int* __restrict__ rp,
                             int* __restrict__ cur, int* __restrict__ srcs){
  int e = blockIdx.x*256 + threadIdx.x;
  if (e >= NE) return;
  int s = ei[e], d = ei[NE + e];
  int pos = atomicAdd(&cur[d], 1);
  srcs[rp[d] + pos] = s;
}

// ---------- sparse-tower GCN aggregation (wave per row) ----------
__global__ __launch_bounds__(256) void k_gcn_sp(const float* __restrict__ U, float* __restrict__ out,
    const int* __restrict__ rp, const int* __restrict__ srcs, const float* __restrict__ dis,
    const float* __restrict__ bias, const float* __restrict__ avec){
  int wid = (blockIdx.x*256 + threadIdx.x) >> 6;
  int lane = threadIdx.x & 63;
  if (wid >= NN) return;
  int j = wid;
  f32x4 a0 = {0,0,0,0}, a1 = {0,0,0,0};
  int b = rp[j], e = rp[j+1];
  for (int k = b; k < e; ++k){
    int s = srcs[k]; float w = dis[s];
    const f32x4* Us = (const f32x4*)(U + (size_t)s*HIDC);
    a0 += w*Us[lane]; a1 += w*Us[64+lane];
  }
  float dj = dis[j];
  const f32x4* Uj = (const f32x4*)(U + (size_t)j*HIDC);
  a0 += dj*Uj[lane]; a1 += dj*Uj[64+lane];
  float* op = out + (size_t)j*HIDC;
  #pragma unroll
  for (int v = 0; v < 4; ++v){
    int c0 = lane*4 + v, c1 = 256 + lane*4 + v;
    float x0 = dj*a0[v] + bias[c0]; float p0 = avec[c0];
    op[c0] = x0 >= 0.f ? x0 : p0*x0;
    float x1 = dj*a1[v] + bias[c1]; float p1 = avec[c1];
    op[c1] = x1 >= 0.f ? x1 : p1*x1;
  }
}

// ---------- w-step (column-sum solve), wave per row, lanes over edges ----------
// MODE 0: first step (w == ALPHA implicit). MODE 1: middle. MODE 2: final -> dc.
template<int MODE>
__global__ __launch_bounds__(256) void k_wstep(const float* __restrict__ w, float* __restrict__ wn,
    const int* __restrict__ rp, const int* __restrict__ cols, const float* __restrict__ di,
    float* __restrict__ dc){
  int wid = (blockIdx.x*256 + threadIdx.x) >> 6;
  int lane = threadIdx.x & 63;
  if (wid >= NN) return;
  int b = rp[wid], e = rp[wid+1];
  float acc = 0.f;
  for (int k = b + lane; k < e; k += 64){
    int i = cols[k];
    float wi = (MODE == 0) ? ALPHA_C : w[i];
    acc += di[i]*wi;
  }
  #pragma unroll
  for (int o = 32; o > 0; o >>= 1) acc += __shfl_down(acc, o);
  if (lane == 0){
    float dj = di[wid];
    float wj = (MODE == 0) ? ALPHA_C : w[wid];
    float v = ALPHA_C + BETA_C*dj*(acc + dj*wj);
    if (MODE == 2) dc[wid] = rsqrtf(fmaxf(v + 1.0f, 1e-12f));
    else wn[wid] = v;
  }
}

// ---------- Neumann step C=128, wave per row. FIN: Px = dc*(v + dc*xf) ----------
template<int FIN>
__global__ __launch_bounds__(256) void k_bapply128(const float* __restrict__ X, const float* __restrict__ Z,
    float* __restrict__ Xn, const int* __restrict__ rp, const int* __restrict__ cols,
    const float* __restrict__ di, const float* __restrict__ dc, const float* __restrict__ xf){
  int wid = (blockIdx.x*256 + threadIdx.x) >> 6;
  int lane = threadIdx.x & 63;
  if (wid >= NN) return;
  int j = wid;
  int b = rp[j], e = rp[j+1];
  float dj = di[j];
  f32x2 a0 = {0,0};
  for (int k = b; k < e; ++k){
    int i = cols[k]; float w = di[i];
    const f32x2* Xi = (const f32x2*)(X + (size_t)i*128);
    a0 += w*Xi[lane];
  }
  const f32x2* Xj = (const f32x2*)(X + (size_t)j*128);
  a0 += dj*Xj[lane];
  const f32x2* Zj = (const f32x2*)(Z + (size_t)j*128);
  f32x2 v = Zj[lane] + (BETA_C*dj)*a0;
  f32x2* Oj = (f32x2*)(Xn + (size_t)j*128);
  if constexpr (FIN){
    float d2 = dc[j];
    const f32x2* Fj = (const f32x2*)(xf + (size_t)j*128);
    f32x2 fv = Fj[lane];
    f32x2 r; r[0] = d2*(v[0] + d2*fv[0]); r[1] = d2*(v[1] + d2*fv[1]);
    Oj[lane] = r;
  } else {
    Oj[lane] = v;
  }
}

// ---------- Neumann step C=512, 2 waves per row (256 cols each) ----------
// FIN: out = prelu(dc*(v + dc*U) + bias, avec)
template<int FIN>
__global__ __launch_bounds__(256) void k_bapply512(const float* __restrict__ X, const float* __restrict__ Z,
    float* __restrict__ Xn, const int* __restrict__ rp, const int* __restrict__ cols,
    const float* __restrict__ di, const float* __restrict__ dc, const float* __restrict__ U,
    const float* __restrict__ bias, const float* __restrict__ avec){
  int wid = (blockIdx.x*256 + threadIdx.x) >> 6;
  int lane = threadIdx.x & 63;
  if (wid >= 2*NN) return;
  int j = wid >> 1, half = wid & 1;
  int co = half*256 + lane*4;                 // column offset of this lane's f32x4
  int b = rp[j], e = rp[j+1];
  float dj = di[j];
  f32x4 a0 = {0,0,0,0};
  for (int k = b; k < e; ++k){
    int i = cols[k]; float w = di[i];
    a0 += w * (*(const f32x4*)(X + (size_t)i*512 + co));
  }
  a0 += dj * (*(const f32x4*)(X + (size_t)j*512 + co));
  f32x4 v = *(const f32x4*)(Z + (size_t)j*512 + co) + (BETA_C*dj)*a0;
  if constexpr (FIN){
    float d2 = dc[j];
    f32x4 uv = *(const f32x4*)(U + (size_t)j*512 + co);
    #pragma unroll
    for (int q = 0; q < 4; ++q){
      float x = d2*(v[q] + d2*uv[q]) + bias[co + q];
      float a = avec[co + q];
      v[q] = x >= 0.f ? x : a*x;
    }
  }
  *(f32x4*)(Xn + (size_t)j*512 + co) = v;
}

// ---------- Z prep for 128-col solve ----------
__global__ void k_prepZ128(const float* __restrict__ in, const float* __restrict__ dc,
                           float* __restrict__ Z){
  int idx = blockIdx.x*256 + threadIdx.x;
  if (idx >= NN*CIN) return;
  Z[idx] = ALPHA_C * dc[idx >> 7] * in[idx];
}

// ---------- segment sum -> [NG, 1024] ----------
__global__ void k_segsum(const float* __restrict__ z1, const float* __restrict__ z2,
                         const int* __restrict__ gptr, float* __restrict__ gv){
  int g = blockIdx.x, t = threadIdx.x;
  float s0 = 0, s1 = 0, s2 = 0, s3 = 0;
  int rb = gptr[g], re = gptr[g+1];
  for (int r = rb; r < re; ++r){
    s0 += z1[(size_t)r*HIDC + t];       s1 += z1[(size_t)r*HIDC + 256 + t];
    s2 += z2[(size_t)r*HIDC + t];       s3 += z2[(size_t)r*HIDC + 256 + t];
  }
  gv[g*1024 + t] = s0; gv[g*1024 + 256 + t] = s1;
  gv[g*1024 + 512 + t] = s2; gv[g*1024 + 768 + t] = s3;
}

// ---------- bf16 MFMA GEMM ----------
template<int BM, int BN, int ACT, int ADDM, int BIAS, int KC, int SPLIT, int ZOUT>
__global__ __launch_bounds__(256) void k_gemm(
    const float* __restrict__ A, const float* __restrict__ B,
    float* __restrict__ C, const float* __restrict__ bias,
    const float* __restrict__ ap, const float* __restrict__ addm,
    float* __restrict__ C2, float* __restrict__ zb,
    const float* __restrict__ dcv,
    int M, int Nn, int K)
{
  __shared__ __align__(16) short As[BM][40];
  __shared__ __align__(16) short Bs[BN][40];
  const int tid = threadIdx.x;
  const int bm0 = blockIdx.y*BM, bn0 = blockIdx.x*BN;
  const int lane = tid & 63, wv = tid >> 6;
  const int wr = wv >> 1, wc = wv & 1;
  constexpr int MR = BM/32, NR = BN/32;
  f32x4 acc[MR][NR];
  #pragma unroll
  for (int i = 0; i < MR; ++i)
    #pragma unroll
    for (int j = 0; j < NR; ++j) acc[i][j] = (f32x4){0.f,0.f,0.f,0.f};
  const int r0 = wr*(BM/2), c0 = wc*(BN/2);
  constexpr int EA = BM*32/256;
  constexpr int EB = BN*32/256;
  const int arow = (tid*EA) >> 5, acol = (tid*EA) & 31;
  const int bkr = (tid*EB) / BN, bnc = (tid*EB) % BN;
  int k0 = 0, k1 = K;
  if constexpr (KC > 0){ k0 = blockIdx.z*KC; k1 = k0 + KC; }
  for (int kt = k0; kt < k1; kt += 32){
    __syncthreads();
    {
      const float* src = A + (size_t)(bm0 + arow)*K + kt + acol;
      short tmp[EA] __attribute__((aligned(16)));
      #pragma unroll
      for (int q = 0; q < EA; q += 4){
        f32x4 v = *(const f32x4*)(src + q);
        tmp[q+0] = f2bf(v[0]); tmp[q+1] = f2bf(v[1]);
        tmp[q+2] = f2bf(v[2]); tmp[q+3] = f2bf(v[3]);
      }
      #pragma unroll
      for (int q = 0; q < EA; q += 8)
        *(short8*)&As[arow][acol + q] = *(const short8*)&tmp[q];
    }
    {
      const float* src = B + (size_t)(kt + bkr)*Nn + bn0 + bnc;
      #pragma unroll
      for (int q = 0; q < EB; q += 4){
        f32x4 v = *(const f32x4*)(src + q);
        Bs[bnc+q+0][bkr] = f2bf(v[0]);
        Bs[bnc+q+1][bkr] = f2bf(v[1]);
        Bs[bnc+q+2][bkr] = f2bf(v[2]);
        Bs[bnc+q+3][bkr] = f2bf(v[3]);
      }
    }
    __syncthreads();
    short8 af[MR], bfv[NR];
    #pragma unroll
    for (int mi = 0; mi < MR; ++mi)
      af[mi] = *(const short8*)&As[r0 + mi*16 + (lane & 15)][(lane >> 4)*8];
    #pragma unroll
    for (int ni = 0; ni < NR; ++ni)
      bfv[ni] = *(const short8*)&Bs[c0 + ni*16 + (lane & 15)][(lane >> 4)*8];
    #pragma unroll
    for (int mi = 0; mi < MR; ++mi)
      #pragma unroll
      for (int ni = 0; ni < NR; ++ni)
        acc[mi][ni] = __builtin_amdgcn_mfma_f32_16x16x32_bf16(af[mi], bfv[ni], acc[mi][ni], 0, 0, 0);
  }
  #pragma unroll
  for (int mi = 0; mi < MR; ++mi){
    #pragma unroll
    for (int ni = 0; ni < NR; ++ni){
      int col = bn0 + c0 + ni*16 + (lane & 15);
      #pragma unroll
      for (int q = 0; q < 4; ++q){
        int row = bm0 + r0 + mi*16 + ((lane >> 4) << 2) + q;
        float v = acc[mi][ni][q];
        if constexpr (KC > 0){
          C[(size_t)blockIdx.z*M*Nn + (size_t)row*Nn + col] = v;
        } else {
          if constexpr (BIAS) v += bias[col];
          if constexpr (ACT == 1){ float a = ap[col]; v = v >= 0.f ? v : a*v; }
          if constexpr (ACT == 2){ float a = ap[0];   v = v >= 0.f ? v : a*v; }
          if constexpr (ADDM) v += addm[(size_t)row*Nn + col];
          if constexpr (SPLIT){
            float* dst = (row < NN) ? (C + (size_t)row*Nn) : (C2 + (size_t)(row - NN)*Nn);
            dst[col] = v;
          } else {
            C[(size_t)row*Nn + col] = v;
          }
          if constexpr (ZOUT){
            zb[(size_t)row*Nn + col] = ALPHA_C * dcv[row] * v;
          }
        }
      }
    }
  }
}

// split-K reduce + epilogue
template<int ACT, int ADDM, int SPLIT>
__global__ void k_red(const float* __restrict__ part, int KS,
                      const float* __restrict__ bias, const float* __restrict__ ap,
                      const float* __restrict__ addm,
                      float* __restrict__ C, float* __restrict__ C2,
                      int M, int Nn){
  int idx = blockIdx.x*256 + threadIdx.x;
  if (idx >= M*Nn) return;
  float v = 0.f;
  for (int z = 0; z < KS; ++z) v += part[(size_t)z*M*Nn + idx];
  int row = idx / Nn, col = idx - row*Nn;
  v += bias[col];
  if constexpr (ACT){ float a = ap[0]; v = v >= 0.f ? v : a*v; }
  if constexpr (ADDM) v += addm[idx];
  if constexpr (SPLIT){
    if (row < NG) C[(size_t)row*Nn + col] = v;
    else C2[(size_t)(row - NG)*Nn + col] = v;
  } else {
    C[idx] = v;
  }
}

extern "C" void kernel_launch(void* const* d_in, const int* in_sizes, int n_in,
                              void* d_out, int out_size, void* d_ws, size_t ws_size,
                              hipStream_t stream) {
  const float* cb   = (const float*)d_in[0];
  const float* g1W0 = (const float*)d_in[1];  const float* g1b0 = (const float*)d_in[2];
  const float* g1W1 = (const float*)d_in[3];  const float* g1b1 = (const float*)d_in[4];
  const float* g1a  = (const float*)d_in[5];
  const float* g2W0 = (const float*)d_in[6];  const float* g2b0 = (const float*)d_in[7];
  const float* g2W1 = (const float*)d_in[8];  const float* g2b1 = (const float*)d_in[9];
  const float* g2a  = (const float*)d_in[10];
  const float* m1W1 = (const float*)d_in[11]; const float* m1b1 = (const float*)d_in[12];
  const float* m1W2 = (const float*)d_in[13]; const float* m1b2 = (const float*)d_in[14];
  const float* m1W3 = (const float*)d_in[15]; const float* m1b3 = (const float*)d_in[16];
  const float* m1a1 = (const float*)d_in[17]; const float* m1a2 = (const float*)d_in[18];
  const float* m1a3 = (const float*)d_in[19];
  const float* m1Ws = (const float*)d_in[20]; const float* m1bs = (const float*)d_in[21];
  const float* m2W1 = (const float*)d_in[22]; const float* m2b1 = (const float*)d_in[23];
  const float* m2W2 = (const float*)d_in[24]; const float* m2b2 = (const float*)d_in[25];
  const float* m2W3 = (const float*)d_in[26]; const float* m2b3 = (const float*)d_in[27];
  const float* m2a1 = (const float*)d_in[28]; const float* m2a2 = (const float*)d_in[29];
  const float* m2a3 = (const float*)d_in[30];
  const float* m2Ws = (const float*)d_in[31]; const float* m2bs = (const float*)d_in[32];
  const int* xidx  = (const int*)d_in[33];
  const int* ei    = (const int*)d_in[34];
  const int* batch = (const int*)d_in[35];
  float* out = (float*)d_out;
  char* W = (char*)d_ws;
  constexpr size_t MB = 1024u*1024u;
  constexpr size_t KB = 1024u;

  // ---- workspace layout ----
  unsigned* Abits  = (unsigned*)(W);            // 0-2MB (dead after prep)
  unsigned* ATbits = (unsigned*)(W + 2*MB);     // 2-4MB (dead after prep)
  char* M4 = W + 4*MB;
  int* cntD  = (int*)(M4);
  int* cur   = (int*)(M4 + 16*KB);
  int* bcnt  = (int*)(M4 + 32*KB);
  int* cntAT = (int*)(M4 + 48*KB);
  int* degA  = (int*)(M4 + 64*KB);
  int* rpAT  = (int*)(M4 + 80*KB);
  int* rpD   = (int*)(M4 + 100*KB);
  int* gptr  = (int*)(M4 + 120*KB);
  float* di  = (float*)(M4 + 124*KB);
  float* dis = (float*)(M4 + 140*KB);
  float* dc  = (float*)(M4 + 156*KB);
  float* wv0 = (float*)(M4 + 172*KB);
  float* wv1 = (float*)(M4 + 188*KB);
  int* colAT = (int*)(W + 4*MB + 512*KB);       // 256KB
  int* srcD  = (int*)(W + 4*MB + 768*KB);       // 256KB
  float* gv  = (float*)(W + 5*MB);              // [128,1024] stacked gv1|gv2
  float* gh1 = (float*)(W + 5*MB + 512*KB);
  float* gh2 = (float*)(W + 5*MB + 768*KB);
  float* xf  = (float*)(W + 6*MB);              // [4096,128]
  float* Px  = (float*)(W + 8*MB);              // [4096,128]
  float* gsb = (float*)(W + 8*MB);              // reuses Px in MLP2 phase
  float* XA  = (float*)(W + 10*MB);
  float* XB  = (float*)(W + 18*MB);
  float* Zb  = (float*)(W + 26*MB);
  float* Ub  = (float*)(W + 34*MB);
  float* z1s = (float*)(W + 42*MB);
  float* zs  = (float*)(W + 50*MB);             // stacked [8192,512]: z21|z22
  float* z21 = zs;
  float* z22 = (float*)(W + 58*MB);
  float* gpart = (float*)(W);                   // MLP2 split-K partials (bitmaps dead)
  float* sb  = (float*)(W + 10*MB);             // [8192,512] over XA|XB (dead)
  float* h1  = (float*)(W + 26*MB);             // [8192,512] over Zb|Ub (dead)
  float* h2  = zs;

  hipMemsetAsync(W, 0, 4*MB, stream);
  hipMemsetAsync(M4, 0, 64*KB, stream);

  k_embed<<<NN, CIN, 0, stream>>>(cb, xidx, xf);
  k_scatter<<<NE/256, 256, 0, stream>>>(ei, Abits, ATbits, cntD);
  k_hist_batch<<<NN/256, 256, 0, stream>>>(batch, bcnt);
  k_popc2<<<2048, 256, 0, stream>>>(Abits, ATbits, degA, cntAT);
  k_rsqrt2<<<16, 256, 0, stream>>>(degA, cntD, di, dis);
  k_prefix3<<<3, 1024, 0, stream>>>(cntAT, rpAT, NN, cntD, rpD, NN, bcnt, gptr, NG);
  k_fill_bits<<<1024, 256, 0, stream>>>(ATbits, rpAT, colAT);
  k_fill_edges<<<NE/256, 256, 0, stream>>>(ei, rpD, cur, srcD);

  // ---- tower 1 (sparse GCN) ----
  k_gemm<128,128,0,0,0,0,0,0><<<dim3(HIDC/128, NN/128), 256, 0, stream>>>(
      xf, g1W0, Ub, nullptr, nullptr, nullptr, nullptr, nullptr, nullptr, NN, HIDC, CIN);
  k_gcn_sp<<<1024, 256, 0, stream>>>(Ub, z1s, rpD, srcD, dis, g1b0, g1a);
  k_gemm<128,128,0,0,0,0,0,0><<<dim3(HIDC/128, NN/128), 256, 0, stream>>>(
      z1s, g1W1, Ub, nullptr, nullptr, nullptr, nullptr, nullptr, nullptr, NN, HIDC, HIDC);
  k_gcn_sp<<<1024, 256, 0, stream>>>(Ub, z21, rpD, srcD, dis, g1b1, g1a);
  k_segsum<<<NG, 256, 0, stream>>>(z1s, z21, gptr, gv);

  // ---- w-solve -> dc (24 parallel wave-per-row steps) ----
  k_wstep<0><<<1024, 256, 0, stream>>>(wv0, wv0, rpAT, colAT, di, nullptr);
  {
    float* wc_ = wv0; float* wn_ = wv1;
    for (int k = 1; k < K_W - 1; ++k){
      k_wstep<1><<<1024, 256, 0, stream>>>(wc_, wn_, rpAT, colAT, di, nullptr);
      float* t = wc_; wc_ = wn_; wn_ = t;
    }
    k_wstep<2><<<1024, 256, 0, stream>>>(wc_, nullptr, rpAT, colAT, di, dc);
  }

  // ---- tower 2 layer 1: P@x (128 cols) ----
  k_prepZ128<<<2048, 256, 0, stream>>>(xf, dc, Zb);
  {
    const float* xc = Zb; float* bufs[2] = {XA, XB};
    for (int k = 0; k < K_SOLVE - 1; ++k){
      float* xn = bufs[k & 1];
      k_bapply128<0><<<1024, 256, 0, stream>>>(xc, Zb, xn, rpAT, colAT, di, nullptr, nullptr);
      xc = xn;
    }
    k_bapply128<1><<<1024, 256, 0, stream>>>(xc, Zb, Px, rpAT, colAT, di, dc, xf);
  }
  k_gemm<128,128,1,0,1,0,0,0><<<dim3(HIDC/128, NN/128), 256, 0, stream>>>(
      Px, g2W0, z1s, g2b0, g2a, nullptr, nullptr, nullptr, nullptr, NN, HIDC, CIN);

  // ---- tower 2 layer 2: U = z1*W1 (fused Z prep via ZOUT), then P@U (512 cols) ----
  k_gemm<128,128,0,0,0,0,0,1><<<dim3(HIDC/128, NN/128), 256, 0, stream>>>(
      z1s, g2W1, Ub, nullptr, nullptr, nullptr, nullptr, Zb, dc, NN, HIDC, HIDC);
  {
    const float* xc = Zb; float* bufs[2] = {XA, XB};
    for (int k = 0; k < K_SOLVE - 1; ++k){
      float* xn = bufs[k & 1];
      k_bapply512<0><<<2048, 256, 0, stream>>>(xc, Zb, xn, rpAT, colAT, di, nullptr, nullptr, nullptr, nullptr);
      xc = xn;
    }
    k_bapply512<1><<<2048, 256, 0, stream>>>(xc, Zb, z22, rpAT, colAT, di, dc, Ub, g2b1, g2a);
  }
  k_segsum<<<NG, 256, 0, stream>>>(z1s, z22, gptr, gv + 64*1024);

  // ---- MLP1 on stacked zs = [z21|z22], M=8192 ----
  k_gemm<128,128,0,0,1,0,0,0><<<dim3(HIDC/128, 8192/128), 256, 0, stream>>>(
      zs, m1Ws, sb, m1bs, nullptr, nullptr, nullptr, nullptr, nullptr, 8192, HIDC, HIDC);
  k_gemm<128,128,2,0,1,0,0,0><<<dim3(HIDC/128, 8192/128), 256, 0, stream>>>(
      zs, m1W1, h1, m1b1, m1a1, nullptr, nullptr, nullptr, nullptr, 8192, HIDC, HIDC);
  k_gemm<128,128,2,0,1,0,0,0><<<dim3(HIDC/128, 8192/128), 256, 0, stream>>>(
      h1, m1W2, h2, m1b2, m1a2, nullptr, nullptr, nullptr, nullptr, 8192, HIDC, HIDC);
  k_gemm<128,128,2,1,1,0,1,0><<<dim3(HIDC/128, 8192/128), 256, 0, stream>>>(
      h2, m1W3, out, m1b3, m1a3, sb, out + 2129920, nullptr, nullptr, 8192, HIDC, HIDC);

  // ---- MLP2 on stacked gv [128,1024], split-K ----
  k_gemm<64,64,0,0,0,64,0,0><<<dim3(HIDC/64, 128/64, 16), 256, 0, stream>>>(
      gv, m2Ws, gpart, nullptr, nullptr, nullptr, nullptr, nullptr, nullptr, 128, HIDC, 1024);
  k_red<0,0,0><<<256, 256, 0, stream>>>(gpart, 16, m2bs, nullptr, nullptr, gsb, nullptr, 128, HIDC);
  k_gemm<64,64,0,0,0,64,0,0><<<dim3(HIDC/64, 128/64, 16), 256, 0, stream>>>(
      gv, m2W1, gpart, nullptr, nullptr, nullptr, nullptr, nullptr, nullptr, 128, HIDC, 1024);
  k_red<1,0,0><<<256, 256, 0, stream>>>(gpart, 16, m2b1, m2a1, nullptr, gh1, nullptr, 128, HIDC);
  k_gemm<64,64,0,0,0,64,0,0><<<dim3(HIDC/64, 128/64, 8), 256, 0, stream>>>(
      gh1, m2W2, gpart, nullptr, nullptr, nullptr, nullptr, nullptr, nullptr, 128, HIDC, HIDC);
  k_red<1,0,0><<<256, 256, 0, stream>>>(gpart, 8, m2b2, m2a2, nullptr, gh2, nullptr, 128, HIDC);
  k_gemm<64,64,0,0,0,64,0,0><<<dim3(HIDC/64, 128/64, 8), 256, 0, stream>>>(
      gh2, m2W3, gpart, nullptr, nullptr, nullptr, nullptr, nullptr, nullptr, 128, HIDC, HIDC);
  k_red<1,1,1><<<256, 256, 0, stream>>>(gpart, 8, m2b3, m2a3, gsb, out + 2097152, out + 4227072, 128, HIDC);
}

// Round 4
// 952.080 us; speedup vs baseline: 1.7170x; 1.2842x over previous
//
#include <hip/hip_runtime.h>

// MVGRL encoder, MI355X gfx950. Round 4: bf16 global_load_lds GEMM, Chebyshev solves.
#define NN 4096
#define NE 65536
#define NBAG 16
#define BFD 8192
#define CIN 128
#define HIDC 512
#define NG 64
#define ALPHA_C 0.2f
#define BETA_C 0.8f
#define K_CH 18   // Chebyshev steps for all solves

typedef unsigned short u16;
typedef __attribute__((ext_vector_type(8))) short short8;
typedef __attribute__((ext_vector_type(4))) short short4v;
typedef __attribute__((ext_vector_type(4))) float f32x4;
typedef __attribute__((ext_vector_type(2))) float f32x2;

__device__ __forceinline__ short f2bf(float f){
  unsigned u = __float_as_uint(f);
  u += 0x7fffu + ((u >> 16) & 1u);
  return (short)(u >> 16);
}
__device__ __forceinline__ float bf2f(u16 h){
  return __uint_as_float(((unsigned)h) << 16);
}
__device__ __forceinline__ void gload16(const void* g, const void* l){
  __builtin_amdgcn_global_load_lds(
    (const __attribute__((address_space(1))) unsigned int*)g,
    (__attribute__((address_space(3))) unsigned int*)l, 16, 0, 0);
}

// ---------- embedding bag (mean, padding idx = BFD), dual write f32 + bf16 ----------
__global__ void k_embed(const float* __restrict__ cb, const int* __restrict__ xidx,
                        float* __restrict__ xf, u16* __restrict__ xfbf){
  int n = blockIdx.x, c = threadIdx.x;
  float acc = 0.f; int cnt = 0;
  #pragma unroll
  for (int b = 0; b < NBAG; ++b){
    int id = xidx[n*NBAG + b];
    if (id != BFD){ acc += cb[(size_t)id*CIN + c]; ++cnt; }
  }
  float v = acc / (float)(cnt > 0 ? cnt : 1);
  xf[(size_t)n*CIN + c] = v;
  xfbf[(size_t)n*CIN + c] = (u16)f2bf(v);
}

// ---------- graph prep ----------
__global__ void k_scatter(const int* __restrict__ ei, unsigned* __restrict__ Ab,
                          unsigned* __restrict__ ATb, int* __restrict__ cntD){
  int e = blockIdx.x*256 + threadIdx.x;
  if (e >= NE) return;
  int s = ei[e], d = ei[NE + e];
  atomicOr(&Ab[s*128 + (d >> 5)], 1u << (d & 31));
  atomicOr(&ATb[d*128 + (s >> 5)], 1u << (s & 31));
  atomicAdd(&cntD[d], 1);
}

__global__ void k_hist_batch(const int* __restrict__ batch, int* __restrict__ bcnt){
  int n = blockIdx.x*256 + threadIdx.x;
  if (n >= NN) return;
  atomicAdd(&bcnt[batch[n]], 1);
}

__global__ void k_popc2(const unsigned* __restrict__ Ab, const unsigned* __restrict__ ATb,
                        int* __restrict__ degA, int* __restrict__ cntAT){
  int wid = (blockIdx.x*blockDim.x + threadIdx.x) >> 6;
  int lane = threadIdx.x & 63;
  if (wid >= 2*NN) return;
  const unsigned* bits; int* o; int r;
  if (wid < NN){ bits = Ab; r = wid; o = degA; }
  else { bits = ATb; r = wid - NN; o = cntAT; }
  int s = __popc(bits[r*128 + lane]) + __popc(bits[r*128 + 64 + lane]);
  #pragma unroll
  for (int off = 32; off > 0; off >>= 1) s += __shfl_down(s, off);
  if (lane == 0) o[r] = s;
}

__global__ void k_rsqrt2(const int* __restrict__ degA, const int* __restrict__ cntD,
                         float* __restrict__ di, float* __restrict__ dis){
  int i = blockIdx.x*256 + threadIdx.x;
  if (i >= NN) return;
  di[i]  = rsqrtf((float)degA[i] + 1.0f);
  dis[i] = rsqrtf((float)cntD[i] + 1.0f);
}

__global__ void k_prefix3(const int* __restrict__ c0, int* __restrict__ r0, int n0,
                          const int* __restrict__ c1, int* __restrict__ r1, int n1,
                          const int* __restrict__ c2, int* __restrict__ r2, int n2){
  const int* cnt; int* rp; int n;
  if (blockIdx.x == 0){ cnt = c0; rp = r0; n = n0; }
  else if (blockIdx.x == 1){ cnt = c1; rp = r1; n = n1; }
  else { cnt = c2; rp = r2; n = n2; }
  __shared__ int a[4096];
  __shared__ int ps[1024];
  int t = threadIdx.x;
  for (int i = t; i < 4096; i += 1024) a[i] = (i < n) ? cnt[i] : 0;
  __syncthreads();
  int b0 = a[t*4], b1 = a[t*4+1], b2 = a[t*4+2], b3 = a[t*4+3];
  int s0 = b0, s1 = s0+b1, s2 = s1+b2, s3 = s2+b3;
  ps[t] = s3;
  __syncthreads();
  for (int off = 1; off < 1024; off <<= 1){
    int v = ps[t];
    int u = (t >= off) ? ps[t-off] : 0;
    __syncthreads();
    ps[t] = v + u;
    __syncthreads();
  }
  int excl = (t > 0) ? ps[t-1] : 0;
  int base = t*4;
  if (base     < n) rp[base]   = excl;
  if (base + 1 < n) rp[base+1] = excl + s0;
  if (base + 2 < n) rp[base+2] = excl + s1;
  if (base + 3 < n) rp[base+3] = excl + s2;
  if (t == 1023) rp[n] = ps[1023];
}

__global__ void k_fill_bits(const unsigned* __restrict__ bits, const int* __restrict__ rp,
                            int* __restrict__ colidx){
  int wid = (blockIdx.x*blockDim.x + threadIdx.x) >> 6;
  int lane = threadIdx.x & 63;
  if (wid >= NN) return;
  unsigned w0 = bits[wid*128 + lane];
  unsigned w1 = bits[wid*128 + 64 + lane];
  int c = __popc(w0) + __popc(w1);
  int x = c;
  #pragma unroll
  for (int d = 1; d < 64; d <<= 1){
    int y = __shfl_up(x, d);
    if (lane >= d) x += y;
  }
  int pos = rp[wid] + (x - c);
  while (w0){ int b = __ffs(w0) - 1; w0 &= w0 - 1; colidx[pos++] = lane*32 + b; }
  while (w1){ int b = __ffs(w1) - 1; w1 &= w1 - 1; colidx[pos++] = (64 + lane)*32 + b; }
}

__global__ void k_fill_edges(const int* __restrict__ ei, const int* __restrict__ rp,
                             int* __restrict__ cur, int* __restrict__ srcs){
  int e = blockIdx.x*256 + threadIdx.x;
  if (e >= NE) return;
  int s = ei[e], d = ei[NE + e];
  int pos = atomicAdd(&cur[d], 1);
  srcs[rp[d] + pos] = s;
}

// ---------- weight transpose+convert: dst[N,K] bf16 = src[K,N] f32 ----------
struct WDesc { const float* src; u16* dst; int K; int N; };
struct WPack { WDesc w[12]; };
__global__ void k_wconv(WPack p){
  WDesc d = p.w[blockIdx.z];
  int k0 = blockIdx.y*32, n0 = blockIdx.x*32;
  if (k0 >= d.K || n0 >= d.N) return;
  __shared__ float t[32][33];
  int tx = threadIdx.x & 31, ty = threadIdx.x >> 5;
  #pragma unroll
  for (int r = 0; r < 4; ++r){
    int row = ty + r*8;
    t[row][tx] = d.src[(size_t)(k0 + row)*d.N + n0 + tx];
  }
  __syncthreads();
  #pragma unroll
  for (int r = 0; r < 4; ++r){
    int row = ty + r*8;
    d.dst[(size_t)(n0 + row)*d.K + k0 + tx] = (u16)f2bf(t[tx][row]);
  }
}

// ---------- sparse-tower GCN aggregation (wave per row), dual write ----------
__global__ __launch_bounds__(256) void k_gcn_sp(const float* __restrict__ U, float* __restrict__ out,
    u16* __restrict__ outbf,
    const int* __restrict__ rp, const int* __restrict__ srcs, const float* __restrict__ dis,
    const float* __restrict__ bias, const float* __restrict__ avec){
  int wid = (blockIdx.x*256 + threadIdx.x) >> 6;
  int lane = threadIdx.x & 63;
  if (wid >= NN) return;
  int j = wid;
  f32x4 a0 = {0,0,0,0}, a1 = {0,0,0,0};
  int b = rp[j], e = rp[j+1];
  for (int k = b; k < e; ++k){
    int s = srcs[k]; float w = dis[s];
    const f32x4* Us = (const f32x4*)(U + (size_t)s*HIDC);
    a0 += w*Us[lane]; a1 += w*Us[64+lane];
  }
  float dj = dis[j];
  const f32x4* Uj = (const f32x4*)(U + (size_t)j*HIDC);
  a0 += dj*Uj[lane]; a1 += dj*Uj[64+lane];
  float* op = out + (size_t)j*HIDC;
  u16* ob = outbf + (size_t)j*HIDC;
  #pragma unroll
  for (int v = 0; v < 4; ++v){
    int c0 = lane*4 + v, c1 = 256 + lane*4 + v;
    float x0 = dj*a0[v] + bias[c0]; float p0 = avec[c0];
    float r0 = x0 >= 0.f ? x0 : p0*x0;
    op[c0] = r0; ob[c0] = (u16)f2bf(r0);
    float x1 = dj*a1[v] + bias[c1]; float p1 = avec[c1];
    float r1 = x1 >= 0.f ? x1 : p1*x1;
    op[c1] = r1; ob[c1] = (u16)f2bf(r1);
  }
}

// ---------- Chebyshev w-step. MODE 0: first (w==alpha); 1: mid; 2: final -> dc ----------
template<int MODE>
__global__ __launch_bounds__(256) void k_wstep(const float* __restrict__ w, const float* wp,
    float* __restrict__ wn, const int* __restrict__ rp, const int* __restrict__ cols,
    const float* __restrict__ di, float* __restrict__ dcv, float om){
  int wid = (blockIdx.x*256 + threadIdx.x) >> 6;
  int lane = threadIdx.x & 63;
  if (wid >= NN) return;
  int b = rp[wid], e = rp[wid+1];
  float acc = 0.f;
  for (int k = b + lane; k < e; k += 64){
    int i = cols[k];
    float wi = (MODE == 0) ? ALPHA_C : w[i];
    acc += di[i]*wi;
  }
  #pragma unroll
  for (int o = 32; o > 0; o >>= 1) acc += __shfl_down(acc, o);
  if (lane == 0){
    float dj = di[wid];
    float wj = (MODE == 0) ? ALPHA_C : w[wid];
    float basic = ALPHA_C + BETA_C*dj*(acc + dj*wj);
    float v;
    if (MODE == 0) v = basic;
    else {
      float pv = wp ? wp[wid] : ALPHA_C;
      v = om*basic + (1.f - om)*pv;
    }
    if (MODE == 2) dcv[wid] = rsqrtf(fmaxf(v + 1.0f, 1e-12f));
    else wn[wid] = v;
  }
}

// ---------- Chebyshev Neumann step C=128, wave per row ----------
template<int FIN>
__global__ __launch_bounds__(256) void k_b128(const float* __restrict__ X, const float* __restrict__ Z,
    const float* Xp, float* Xn, u16* __restrict__ Pxbf,
    const int* __restrict__ rp, const int* __restrict__ cols,
    const float* __restrict__ di, float om,
    const float* __restrict__ dcv, const float* __restrict__ xf){
  int wid = (blockIdx.x*256 + threadIdx.x) >> 6;
  int lane = threadIdx.x & 63;
  if (wid >= NN) return;
  int j = wid;
  int b = rp[j], e = rp[j+1];
  float dj = di[j];
  f32x2 a0 = {0,0};
  for (int k = b; k < e; ++k){
    int i = cols[k]; float w = di[i];
    a0 += w * (*(const f32x2*)(X + (size_t)i*128 + lane*2));
  }
  a0 += dj * (*(const f32x2*)(X + (size_t)j*128 + lane*2));
  f32x2 basic = *(const f32x2*)(Z + (size_t)j*128 + lane*2) + (BETA_C*dj)*a0;
  f32x2 xp = *(const f32x2*)(Xp + (size_t)j*128 + lane*2);
  f32x2 v; v[0] = om*basic[0] + (1.f-om)*xp[0]; v[1] = om*basic[1] + (1.f-om)*xp[1];
  if constexpr (FIN){
    float d2 = dcv[j];
    f32x2 fv = *(const f32x2*)(xf + (size_t)j*128 + lane*2);
    unsigned pk = (unsigned)(unsigned short)f2bf(d2*(v[0] + d2*fv[0]))
                | ((unsigned)(unsigned short)f2bf(d2*(v[1] + d2*fv[1])) << 16);
    *(unsigned*)(Pxbf + (size_t)j*128 + lane*2) = pk;
  } else {
    *(f32x2*)(Xn + (size_t)j*128 + lane*2) = v;
  }
}

// ---------- Chebyshev Neumann step C=512, 2 waves per row ----------
template<int FIN>
__global__ __launch_bounds__(256) void k_b512(const float* __restrict__ X, const float* __restrict__ Z,
    const float* Xp, float* Xn, u16* __restrict__ Xnbf,
    const int* __restrict__ rp, const int* __restrict__ cols,
    const float* __restrict__ di, float om,
    const float* __restrict__ dcv, const u16* __restrict__ Ubf,
    const float* __restrict__ bias, const float* __restrict__ avec){
  int wid = (blockIdx.x*256 + threadIdx.x) >> 6;
  int lane = threadIdx.x & 63;
  if (wid >= 2*NN) return;
  int j = wid >> 1, half = wid & 1;
  int co = half*256 + lane*4;
  int b = rp[j], e = rp[j+1];
  float dj = di[j];
  f32x4 a0 = {0,0,0,0};
  for (int k = b; k < e; ++k){
    int i = cols[k]; float w = di[i];
    a0 += w * (*(const f32x4*)(X + (size_t)i*512 + co));
  }
  a0 += dj * (*(const f32x4*)(X + (size_t)j*512 + co));
  f32x4 basic = *(const f32x4*)(Z + (size_t)j*512 + co) + (BETA_C*dj)*a0;
  f32x4 xp = *(const f32x4*)(Xp + (size_t)j*512 + co);
  f32x4 v;
  #pragma unroll
  for (int q = 0; q < 4; ++q) v[q] = om*basic[q] + (1.f-om)*xp[q];
  if constexpr (FIN){
    float d2 = dcv[j];
    short4v pk;
    #pragma unroll
    for (int q = 0; q < 4; ++q){
      float uq = bf2f(Ubf[(size_t)j*512 + co + q]);
      float x = d2*(v[q] + d2*uq) + bias[co + q];
      float a = avec[co + q];
      float r = x >= 0.f ? x : a*x;
      v[q] = r;
      pk[q] = f2bf(r);
    }
    *(f32x4*)(Xn + (size_t)j*512 + co) = v;              // z22 f32 (for segsum)
    *(short4v*)(Xnbf + (size_t)j*512 + co) = pk;         // z22 bf16 (for MLP1)
  } else {
    *(f32x4*)(Xn + (size_t)j*512 + co) = v;
  }
}

// ---------- Z prep for 128-col solve ----------
__global__ void k_prepZ128(const float* __restrict__ in, const float* __restrict__ dcv,
                           float* __restrict__ Z){
  int idx = blockIdx.x*256 + threadIdx.x;
  if (idx >= NN*CIN) return;
  Z[idx] = ALPHA_C * dcv[idx >> 7] * in[idx];
}

// ---------- segment sum -> [NG, 1024] bf16 ----------
__global__ void k_segsum(const float* __restrict__ z1, const float* __restrict__ z2,
                         const int* __restrict__ gptr, u16* __restrict__ gv){
  int g = blockIdx.x, t = threadIdx.x;
  float s0 = 0, s1 = 0, s2 = 0, s3 = 0;
  int rb = gptr[g], re = gptr[g+1];
  for (int r = rb; r < re; ++r){
    s0 += z1[(size_t)r*HIDC + t];       s1 += z1[(size_t)r*HIDC + 256 + t];
    s2 += z2[(size_t)r*HIDC + t];       s3 += z2[(size_t)r*HIDC + 256 + t];
  }
  gv[g*1024 + t] = (u16)f2bf(s0); gv[g*1024 + 256 + t] = (u16)f2bf(s1);
  gv[g*1024 + 512 + t] = (u16)f2bf(s2); gv[g*1024 + 768 + t] = (u16)f2bf(s3);
}

// ---------- bf16 MFMA GEMM, global_load_lds staging ----------
// A[M,K] bf16 row-major, Bt[N,K] bf16 row-major (pre-transposed weights).
// KC>0: split-K partials. Else epilogue: bias/act/addm, WF32->C (SPLIT), WBF->Cb, ZOUT->zb.
template<int BM, int BN, int ACT, int ADDM, int BIAS, int KC, int SPLIT, int ZOUT, int WF32, int WBF>
__global__ __launch_bounds__(256) void k_gemm(
    const u16* __restrict__ A, const u16* __restrict__ Bt,
    float* __restrict__ C, u16* __restrict__ Cb,
    const float* __restrict__ bias, const float* __restrict__ ap,
    const float* __restrict__ addm, float* __restrict__ C2,
    float* __restrict__ zb, const float* __restrict__ dcv,
    int M, int Nn, int K)
{
  __shared__ __align__(16) u16 As[BM*32];
  __shared__ __align__(16) u16 Bs[BN*32];
  const int tid = threadIdx.x;
  const int bm0 = blockIdx.y*BM, bn0 = blockIdx.x*BN;
  const int lane = tid & 63, wv = tid >> 6;
  const int wr = wv >> 1, wc = wv & 1;
  constexpr int MR = BM/32, NR = BN/32;
  f32x4 acc[MR][NR];
  #pragma unroll
  for (int i = 0; i < MR; ++i)
    #pragma unroll
    for (int j = 0; j < NR; ++j) acc[i][j] = (f32x4){0.f,0.f,0.f,0.f};
  const int r0 = wr*(BM/2), c0 = wc*(BN/2);
  const int glr = lane >> 2, glc = (lane & 3)*8;
  int k0 = 0, k1 = K;
  if constexpr (KC > 0){ k0 = blockIdx.z*KC; k1 = k0 + KC; }
  for (int kt = k0; kt < k1; kt += 32){
    #pragma unroll
    for (int q = 0; q < BM/64; ++q)
      gload16(A + (size_t)(bm0 + q*64 + wv*16 + glr)*K + kt + glc, &As[(q*4+wv)*512]);
    #pragma unroll
    for (int q = 0; q < BN/64; ++q)
      gload16(Bt + (size_t)(bn0 + q*64 + wv*16 + glr)*K + kt + glc, &Bs[(q*4+wv)*512]);
    __syncthreads();
    short8 af[MR], bfv[NR];
    #pragma unroll
    for (int mi = 0; mi < MR; ++mi)
      af[mi] = *(const short8*)&As[(r0 + mi*16 + (lane & 15))*32 + (lane >> 4)*8];
    #pragma unroll
    for (int ni = 0; ni < NR; ++ni)
      bfv[ni] = *(const short8*)&Bs[(c0 + ni*16 + (lane & 15))*32 + (lane >> 4)*8];
    #pragma unroll
    for (int mi = 0; mi < MR; ++mi)
      #pragma unroll
      for (int ni = 0; ni < NR; ++ni)
        acc[mi][ni] = __builtin_amdgcn_mfma_f32_16x16x32_bf16(af[mi], bfv[ni], acc[mi][ni], 0, 0, 0);
    __syncthreads();
  }
  #pragma unroll
  for (int mi = 0; mi < MR; ++mi){
    #pragma unroll
    for (int ni = 0; ni < NR; ++ni){
      int col = bn0 + c0 + ni*16 + (lane & 15);
      #pragma unroll
      for (int q = 0; q < 4; ++q){
        int row = bm0 + r0 + mi*16 + ((lane >> 4) << 2) + q;
        float v = acc[mi][ni][q];
        if constexpr (KC > 0){
          C[(size_t)blockIdx.z*M*Nn + (size_t)row*Nn + col] = v;
        } else {
          if constexpr (BIAS) v += bias[col];
          if constexpr (ACT == 1){ float a = ap[col]; v = v >= 0.f ? v : a*v; }
          if constexpr (ACT == 2){ float a = ap[0];   v = v >= 0.f ? v : a*v; }
          if constexpr (ADDM) v += addm[(size_t)row*Nn + col];
          if constexpr (WF32){
            if constexpr (SPLIT){
              float* dst = (row < NN) ? (C + (size_t)row*Nn) : (C2 + (size_t)(row - NN)*Nn);
              dst[col] = v;
            } else {
              C[(size_t)row*Nn + col] = v;
            }
          }
          if constexpr (WBF) Cb[(size_t)row*Nn + col] = (u16)f2bf(v);
          if constexpr (ZOUT) zb[(size_t)row*Nn + col] = ALPHA_C * dcv[row] * v;
        }
      }
    }
  }
}

// split-K reduce + epilogue. OBF: bf16 out.
template<int ACT, int ADDM, int SPLIT, int OBF>
__global__ void k_red(const float* __restrict__ part, int KS,
                      const float* __restrict__ bias, const float* __restrict__ ap,
                      const float* __restrict__ addm,
                      float* __restrict__ C, float* __restrict__ C2, u16* __restrict__ Cb,
                      int M, int Nn){
  int idx = blockIdx.x*256 + threadIdx.x;
  if (idx >= M*Nn) return;
  float v = 0.f;
  for (int z = 0; z < KS; ++z) v += part[(size_t)z*M*Nn + idx];
  int row = idx / Nn, col = idx - row*Nn;
  v += bias[col];
  if constexpr (ACT){ float a = ap[0]; v = v >= 0.f ? v : a*v; }
  if constexpr (ADDM) v += addm[idx];
  if constexpr (OBF){
    Cb[idx] = (u16)f2bf(v);
  } else if constexpr (SPLIT){
    if (row < NG) C[(size_t)row*Nn + col] = v;
    else C2[(size_t)(row - NG)*Nn + col] = v;
  } else {
    C[idx] = v;
  }
}

extern "C" void kernel_launch(void* const* d_in, const int* in_sizes, int n_in,
                              void* d_out, int out_size, void* d_ws, size_t ws_size,
                              hipStream_t stream) {
  const float* cb   = (const float*)d_in[0];
  const float* g1W0 = (const float*)d_in[1];  const float* g1b0 = (const float*)d_in[2];
  const float* g1W1 = (const float*)d_in[3];  const float* g1b1 = (const float*)d_in[4];
  const float* g1a  = (const float*)d_in[5];
  const float* g2W0 = (const float*)d_in[6];  const float* g2b0 = (const float*)d_in[7];
  const float* g2W1 = (const float*)d_in[8];  const float* g2b1 = (const float*)d_in[9];
  const float* g2a  = (const float*)d_in[10];
  const float* m1W1 = (const float*)d_in[11]; const float* m1b1 = (const float*)d_in[12];
  const float* m1W2 = (const float*)d_in[13]; const float* m1b2 = (const float*)d_in[14];
  const float* m1W3 = (const float*)d_in[15]; const float* m1b3 = (const float*)d_in[16];
  const float* m1a1 = (const float*)d_in[17]; const float* m1a2 = (const float*)d_in[18];
  const float* m1a3 = (const float*)d_in[19];
  const float* m1Ws = (const float*)d_in[20]; const float* m1bs = (const float*)d_in[21];
  const float* m2W1 = (const float*)d_in[22]; const float* m2b1 = (const float*)d_in[23];
  const float* m2W2 = (const float*)d_in[24]; const float* m2b2 = (const float*)d_in[25];
  const float* m2W3 = (const float*)d_in[26]; const float* m2b3 = (const float*)d_in[27];
  const float* m2a1 = (const float*)d_in[28]; const float* m2a2 = (const float*)d_in[29];
  const float* m2a3 = (const float*)d_in[30];
  const float* m2Ws = (const float*)d_in[31]; const float* m2bs = (const float*)d_in[32];
  const int* xidx  = (const int*)d_in[33];
  const int* ei    = (const int*)d_in[34];
  const int* batch = (const int*)d_in[35];
  float* out = (float*)d_out;
  char* W = (char*)d_ws;
  constexpr size_t MB = 1024u*1024u;
  constexpr size_t KB = 1024u;

  // ---- workspace layout (max 67MB, proven) ----
  unsigned* Abits  = (unsigned*)(W);            // 0-2MB, dead after prep
  unsigned* ATbits = (unsigned*)(W + 2*MB);     // 2-4MB, dead after prep
  // post-prep: 8 weights bf16 at 0-3.25MB; MLP2 phase: gpart 0-4MB
  u16* w_g1W0t = (u16*)(W);
  u16* w_g2W0t = (u16*)(W + 128*KB);
  u16* w_g1W1t = (u16*)(W + 256*KB);
  u16* w_g2W1t = (u16*)(W + 768*KB);
  u16* w_m1W1t = (u16*)(W + 1280*KB);
  u16* w_m1W2t = (u16*)(W + 1792*KB);
  u16* w_m1W3t = (u16*)(W + 2304*KB);
  u16* w_m1Wst = (u16*)(W + 2816*KB);
  float* gpart = (float*)(W);
  char* M4 = W + 4*MB;
  int* cntD  = (int*)(M4);
  int* cur   = (int*)(M4 + 16*KB);
  int* bcnt  = (int*)(M4 + 32*KB);
  int* cntAT = (int*)(M4 + 48*KB);
  int* degA  = (int*)(M4 + 64*KB);
  int* rpAT  = (int*)(M4 + 80*KB);
  int* rpD   = (int*)(M4 + 100*KB);
  int* gptr  = (int*)(M4 + 120*KB);
  float* di  = (float*)(M4 + 124*KB);
  float* dis = (float*)(M4 + 140*KB);
  float* dc  = (float*)(M4 + 156*KB);
  float* wv0 = (float*)(M4 + 172*KB);
  float* wv1 = (float*)(M4 + 188*KB);
  int* colAT = (int*)(W + 4*MB + 256*KB);
  int* srcD  = (int*)(W + 4*MB + 512*KB);
  u16* gvbf  = (u16*)(W + 4*MB + 768*KB);       // [128,1024] 256KB
  u16* gh1bf = (u16*)(W + 5*MB);                // 128KB
  u16* gh2bf = (u16*)(W + 5*MB + 128*KB);       // 128KB
  float* gsb = (float*)(W + 5*MB + 256*KB);     // [128,512] 256KB
  float* xf  = (float*)(W + 6*MB);              // [4096,128] 2MB
  u16* xfbf  = (u16*)(W + 8*MB);                // 1MB
  u16* PxBf  = (u16*)(W + 9*MB);                // 1MB
  u16* w_m2W1t = (u16*)(W + 10*MB);             // 1MB
  u16* w_m2Wst = (u16*)(W + 11*MB);             // 1MB
  u16* w_m2W2t = (u16*)(W + 12*MB);             // 512KB
  u16* w_m2W3t = (u16*)(W + 12*MB + 512*KB);    // 512KB
  float* Zb128 = (float*)(W + 13*MB);           // 2MB
  float* Zb  = (float*)(W + 15*MB);             // 8MB
  float* XA  = (float*)(W + 23*MB);             // 8MB (XA128 subrange; Ub_t1; MLP1 sb part)
  float* XB  = (float*)(W + 31*MB);             // 8MB (XB128 subrange; MLP1 h1)
  u16* z1sbf = (u16*)(W + 35*MB);               // 4MB (temporally disjoint from XB128/h1 use)
  u16* Ubf   = (u16*)(W + 39*MB);               // 4MB
  float* z1s = (float*)(W + 43*MB);             // 8MB
  u16* zsbf  = (u16*)(W + 51*MB);               // [8192,512] 8MB: z21bf|z22bf
  u16* z21bf = zsbf;
  u16* z22bf = (u16*)(W + 55*MB);
  float* ztmp = (float*)(W + 59*MB);            // 8MB: z21 f32, then z22 f32
  float* Ub_t1 = XA;                            // tower1 GCN input staging
  float* sb  = Zb;                              // 16MB @15-31 (Zb+XA dead in MLP1)
  u16* h1    = (u16*)(W + 31*MB);               // 8MB over XB
  u16* h2    = (u16*)(W + 59*MB);               // 8MB over ztmp
  float* XA128 = XA;                            // [4096,128] 2MB
  float* XB128 = XB;

  // Chebyshev omegas (sigma = 0.8)
  float omg[K_CH + 1];
  {
    double o = 1.0; omg[1] = 1.0f;
    for (int k = 2; k <= K_CH; ++k){ o = 1.0/(1.0 - 0.16*o); omg[k] = (float)o; }
  }

  hipMemsetAsync(W, 0, 4*MB, stream);
  hipMemsetAsync(M4, 0, 64*KB, stream);

  k_embed<<<NN, CIN, 0, stream>>>(cb, xidx, xf, xfbf);
  k_scatter<<<NE/256, 256, 0, stream>>>(ei, Abits, ATbits, cntD);
  k_hist_batch<<<NN/256, 256, 0, stream>>>(batch, bcnt);
  k_popc2<<<2048, 256, 0, stream>>>(Abits, ATbits, degA, cntAT);
  k_rsqrt2<<<16, 256, 0, stream>>>(degA, cntD, di, dis);
  k_prefix3<<<3, 1024, 0, stream>>>(cntAT, rpAT, NN, cntD, rpD, NN, bcnt, gptr, NG);
  k_fill_bits<<<1024, 256, 0, stream>>>(ATbits, rpAT, colAT);
  k_fill_edges<<<NE/256, 256, 0, stream>>>(ei, rpD, cur, srcD);

  // weight convert (bitmaps now dead)
  {
    WPack p = {{ {g1W0, w_g1W0t, 128, 512}, {g2W0, w_g2W0t, 128, 512},
                 {g1W1, w_g1W1t, 512, 512}, {g2W1, w_g2W1t, 512, 512},
                 {m1W1, w_m1W1t, 512, 512}, {m1W2, w_m1W2t, 512, 512},
                 {m1W3, w_m1W3t, 512, 512}, {m1Ws, w_m1Wst, 512, 512},
                 {m2W1, w_m2W1t, 1024, 512}, {m2Ws, w_m2Wst, 1024, 512},
                 {m2W2, w_m2W2t, 512, 512}, {m2W3, w_m2W3t, 512, 512} }};
    k_wconv<<<dim3(16, 32, 12), 256, 0, stream>>>(p);
  }

  // ---- tower 1 (sparse GCN) ----
  k_gemm<128,128,0,0,0,0,0,0,1,0><<<dim3(4, 32), 256, 0, stream>>>(
      xfbf, w_g1W0t, Ub_t1, nullptr, nullptr, nullptr, nullptr, nullptr, nullptr, nullptr, NN, HIDC, CIN);
  k_gcn_sp<<<1024, 256, 0, stream>>>(Ub_t1, z1s, z1sbf, rpD, srcD, dis, g1b0, g1a);
  k_gemm<128,128,0,0,0,0,0,0,1,0><<<dim3(4, 32), 256, 0, stream>>>(
      z1sbf, w_g1W1t, Ub_t1, nullptr, nullptr, nullptr, nullptr, nullptr, nullptr, nullptr, NN, HIDC, HIDC);
  k_gcn_sp<<<1024, 256, 0, stream>>>(Ub_t1, ztmp, z21bf, rpD, srcD, dis, g1b1, g1a);
  k_segsum<<<NG, 256, 0, stream>>>(z1s, ztmp, gptr, gvbf);

  // ---- w-solve -> dc (Chebyshev) ----
  k_wstep<0><<<1024, 256, 0, stream>>>(nullptr, nullptr, wv0, rpAT, colAT, di, nullptr, 1.0f);
  {
    float *curp = wv0, *prv = nullptr;
    for (int k = 2; k < K_CH; ++k){
      float* nxt = (k == 2) ? wv1 : prv;
      k_wstep<1><<<1024, 256, 0, stream>>>(curp, prv, nxt, rpAT, colAT, di, nullptr, omg[k]);
      prv = curp; curp = nxt;
    }
    k_wstep<2><<<1024, 256, 0, stream>>>(curp, prv, nullptr, rpAT, colAT, di, dc, omg[K_CH]);
  }

  // ---- tower 2 layer 1: P@x (128 cols), Chebyshev ----
  k_prepZ128<<<2048, 256, 0, stream>>>(xf, dc, Zb128);
  k_b128<0><<<1024, 256, 0, stream>>>(Zb128, Zb128, Zb128, XA128, nullptr, rpAT, colAT, di, 1.0f, nullptr, nullptr);
  {
    float *curp = XA128, *prv = Zb128;
    for (int k = 2; k < K_CH; ++k){
      float* nxt = (k == 2) ? XB128 : prv;
      k_b128<0><<<1024, 256, 0, stream>>>(curp, Zb128, prv, nxt, nullptr, rpAT, colAT, di, omg[k], nullptr, nullptr);
      prv = curp; curp = nxt;
    }
    k_b128<1><<<1024, 256, 0, stream>>>(curp, Zb128, prv, nullptr, PxBf, rpAT, colAT, di, omg[K_CH], dc, xf);
  }
  k_gemm<128,128,1,0,1,0,0,0,1,1><<<dim3(4, 32), 256, 0, stream>>>(
      PxBf, w_g2W0t, z1s, z1sbf, g2b0, g2a, nullptr, nullptr, nullptr, nullptr, NN, HIDC, CIN);

  // ---- tower 2 layer 2: U = z1*W1 (bf16 out + fused Z prep), then P@U (512 cols) ----
  k_gemm<128,128,0,0,0,0,0,1,0,1><<<dim3(4, 32), 256, 0, stream>>>(
      z1sbf, w_g2W1t, nullptr, Ubf, nullptr, nullptr, nullptr, nullptr, Zb, dc, NN, HIDC, HIDC);
  k_b512<0><<<2048, 256, 0, stream>>>(Zb, Zb, Zb, XA, nullptr, rpAT, colAT, di, 1.0f, nullptr, nullptr, nullptr, nullptr);
  {
    float *curp = XA, *prv = Zb;
    for (int k = 2; k < K_CH; ++k){
      float* nxt = (k == 2) ? XB : prv;
      k_b512<0><<<2048, 256, 0, stream>>>(curp, Zb, prv, nxt, nullptr, rpAT, colAT, di, omg[k], nullptr, nullptr, nullptr, nullptr);
      prv = curp; curp = nxt;
    }
    k_b512<1><<<2048, 256, 0, stream>>>(curp, Zb, prv, ztmp, z22bf, rpAT, colAT, di, omg[K_CH], dc, Ubf, g2b1, g2a);
  }
  k_segsum<<<NG, 256, 0, stream>>>(z1s, ztmp, gptr, gvbf + 64*1024);

  // ---- MLP1 on stacked zsbf = [z21bf|z22bf], M=8192 ----
  k_gemm<128,128,0,0,1,0,0,0,1,0><<<dim3(4, 64), 256, 0, stream>>>(
      zsbf, w_m1Wst, sb, nullptr, m1bs, nullptr, nullptr, nullptr, nullptr, nullptr, 8192, HIDC, HIDC);
  k_gemm<128,128,2,0,1,0,0,0,0,1><<<dim3(4, 64), 256, 0, stream>>>(
      zsbf, w_m1W1t, nullptr, h1, m1b1, m1a1, nullptr, nullptr, nullptr, nullptr, 8192, HIDC, HIDC);
  k_gemm<128,128,2,0,1,0,0,0,0,1><<<dim3(4, 64), 256, 0, stream>>>(
      h1, w_m1W2t, nullptr, h2, m1b2, m1a2, nullptr, nullptr, nullptr, nullptr, 8192, HIDC, HIDC);
  k_gemm<128,128,2,1,1,0,1,0,1,0><<<dim3(4, 64), 256, 0, stream>>>(
      h2, w_m1W3t, out, nullptr, m1b3, m1a3, sb, out + 2129920, nullptr, nullptr, 8192, HIDC, HIDC);

  // ---- MLP2 on stacked gvbf [128,1024], split-K (gpart over dead weights8) ----
  k_gemm<64,64,0,0,0,64,0,0,1,0><<<dim3(8, 2, 16), 256, 0, stream>>>(
      gvbf, w_m2Wst, gpart, nullptr, nullptr, nullptr, nullptr, nullptr, nullptr, nullptr, 128, HIDC, 1024);
  k_red<0,0,0,0><<<256, 256, 0, stream>>>(gpart, 16, m2bs, nullptr, nullptr, gsb, nullptr, nullptr, 128, HIDC);
  k_gemm<64,64,0,0,0,64,0,0,1,0><<<dim3(8, 2, 16), 256, 0, stream>>>(
      gvbf, w_m2W1t, gpart, nullptr, nullptr, nullptr, nullptr, nullptr, nullptr, nullptr, 128, HIDC, 1024);
  k_red<1,0,0,1><<<256, 256, 0, stream>>>(gpart, 16, m2b1, m2a1, nullptr, nullptr, nullptr, gh1bf, 128, HIDC);
  k_gemm<64,64,0,0,0,64,0,0,1,0><<<dim3(8, 2, 8), 256, 0, stream>>>(
      gh1bf, w_m2W2t, gpart, nullptr, nullptr, nullptr, nullptr, nullptr, nullptr, nullptr, 128, HIDC, HIDC);
  k_red<1,0,0,1><<<256, 256, 0, stream>>>(gpart, 8, m2b2, m2a2, nullptr, nullptr, nullptr, gh2bf, 128, HIDC);
  k_gemm<64,64,0,0,0,64,0,0,1,0><<<dim3(8, 2, 8), 256, 0, stream>>>(
      gh2bf, w_m2W3t, gpart, nullptr, nullptr, nullptr, nullptr, nullptr, nullptr, nullptr, 128, HIDC, HIDC);
  k_red<1,1,1,0><<<256, 256, 0, stream>>>(gpart, 8, m2b3, m2a3, gsb, out + 2097152, out + 4227072, nullptr, 128, HIDC);
}

// Round 5
// 651.887 us; speedup vs baseline: 2.5076x; 1.4605x over previous
//
#include <hip/hip_runtime.h>

// MVGRL encoder, MI355X gfx950. Round 5: K_CH=12, shuffle-broadcast gathers, launch fusion.
#define NN 4096
#define NE 65536
#define NBAG 16
#define BFD 8192
#define CIN 128
#define HIDC 512
#define NG 64
#define ALPHA_C 0.2f
#define BETA_C 0.8f
#define K_CH 12

typedef unsigned short u16;
typedef __attribute__((ext_vector_type(8))) short short8;
typedef __attribute__((ext_vector_type(4))) short short4v;
typedef __attribute__((ext_vector_type(4))) float f32x4;
typedef __attribute__((ext_vector_type(2))) float f32x2;

__device__ __forceinline__ short f2bf(float f){
  unsigned u = __float_as_uint(f);
  u += 0x7fffu + ((u >> 16) & 1u);
  return (short)(u >> 16);
}
__device__ __forceinline__ float bf2f(u16 h){
  return __uint_as_float(((unsigned)h) << 16);
}
__device__ __forceinline__ void gload16(const void* g, const void* l){
  __builtin_amdgcn_global_load_lds(
    (const __attribute__((address_space(1))) unsigned int*)g,
    (__attribute__((address_space(3))) unsigned int*)l, 16, 0, 0);
}

// ---------- embedding bag (mean, padding idx = BFD), dual write f32 + bf16 ----------
__global__ void k_embed(const float* __restrict__ cb, const int* __restrict__ xidx,
                        float* __restrict__ xf, u16* __restrict__ xfbf){
  int n = blockIdx.x, c = threadIdx.x;
  float acc = 0.f; int cnt = 0;
  #pragma unroll
  for (int b = 0; b < NBAG; ++b){
    int id = xidx[n*NBAG + b];
    if (id != BFD){ acc += cb[(size_t)id*CIN + c]; ++cnt; }
  }
  float v = acc / (float)(cnt > 0 ? cnt : 1);
  xf[(size_t)n*CIN + c] = v;
  xfbf[(size_t)n*CIN + c] = (u16)f2bf(v);
}

// ---------- edge scatter + batch histogram (merged) ----------
__global__ void k_scatter_hist(const int* __restrict__ ei, unsigned* __restrict__ Ab,
                               unsigned* __restrict__ ATb, int* __restrict__ cntD,
                               const int* __restrict__ batch, int* __restrict__ bcnt){
  if (blockIdx.x < 256){
    int e = blockIdx.x*256 + threadIdx.x;
    int s = ei[e], d = ei[NE + e];
    atomicOr(&Ab[s*128 + (d >> 5)], 1u << (d & 31));
    atomicOr(&ATb[d*128 + (s >> 5)], 1u << (s & 31));
    atomicAdd(&cntD[d], 1);
  } else {
    int n = (blockIdx.x - 256)*256 + threadIdx.x;
    if (n < NN) atomicAdd(&bcnt[batch[n]], 1);
  }
}

// popcount rows; A-side writes di directly, AT-side writes cntAT
__global__ void k_popc2(const unsigned* __restrict__ Ab, const unsigned* __restrict__ ATb,
                        float* __restrict__ di, int* __restrict__ cntAT){
  int wid = (blockIdx.x*blockDim.x + threadIdx.x) >> 6;
  int lane = threadIdx.x & 63;
  if (wid >= 2*NN) return;
  const unsigned* bits; int r;
  if (wid < NN){ bits = Ab; r = wid; }
  else { bits = ATb; r = wid - NN; }
  int s = __popc(bits[r*128 + lane]) + __popc(bits[r*128 + 64 + lane]);
  #pragma unroll
  for (int off = 32; off > 0; off >>= 1) s += __shfl_down(s, off);
  if (lane == 0){
    if (wid < NN) di[r] = rsqrtf((float)s + 1.0f);
    else cntAT[r] = s;
  }
}

// three exclusive prefix sums; block 1 also emits dis = rsqrt(cntD+1)
__global__ void k_prefix3(const int* __restrict__ c0, int* __restrict__ r0, int n0,
                          const int* __restrict__ c1, int* __restrict__ r1, int n1,
                          const int* __restrict__ c2, int* __restrict__ r2, int n2,
                          float* __restrict__ dis){
  const int* cnt; int* rp; int n;
  if (blockIdx.x == 0){ cnt = c0; rp = r0; n = n0; }
  else if (blockIdx.x == 1){ cnt = c1; rp = r1; n = n1; }
  else { cnt = c2; rp = r2; n = n2; }
  __shared__ int a[4096];
  __shared__ int ps[1024];
  int t = threadIdx.x;
  for (int i = t; i < 4096; i += 1024) a[i] = (i < n) ? cnt[i] : 0;
  __syncthreads();
  if (blockIdx.x == 1){
    for (int i = t; i < NN; i += 1024) dis[i] = rsqrtf((float)a[i] + 1.0f);
  }
  int b0 = a[t*4], b1 = a[t*4+1], b2 = a[t*4+2], b3 = a[t*4+3];
  int s0 = b0, s1 = s0+b1, s2 = s1+b2, s3 = s2+b3;
  ps[t] = s3;
  __syncthreads();
  for (int off = 1; off < 1024; off <<= 1){
    int v = ps[t];
    int u = (t >= off) ? ps[t-off] : 0;
    __syncthreads();
    ps[t] = v + u;
    __syncthreads();
  }
  int excl = (t > 0) ? ps[t-1] : 0;
  int base = t*4;
  if (base     < n) rp[base]   = excl;
  if (base + 1 < n) rp[base+1] = excl + s0;
  if (base + 2 < n) rp[base+2] = excl + s1;
  if (base + 3 < n) rp[base+3] = excl + s2;
  if (t == 1023) rp[n] = ps[1023];
}

// CSR fill: blocks 0..1023 -> colAT from bitmap; 1024..1279 -> srcD from edges
__global__ void k_fillboth(const unsigned* __restrict__ bits, const int* __restrict__ rpA,
                           int* __restrict__ colidx,
                           const int* __restrict__ ei, const int* __restrict__ rpD,
                           int* __restrict__ cur, int* __restrict__ srcs){
  if (blockIdx.x < 1024){
    int wid = (blockIdx.x*blockDim.x + threadIdx.x) >> 6;
    int lane = threadIdx.x & 63;
    unsigned w0 = bits[wid*128 + lane];
    unsigned w1 = bits[wid*128 + 64 + lane];
    int c = __popc(w0) + __popc(w1);
    int x = c;
    #pragma unroll
    for (int d = 1; d < 64; d <<= 1){
      int y = __shfl_up(x, d);
      if (lane >= d) x += y;
    }
    int pos = rpA[wid] + (x - c);
    while (w0){ int b = __ffs(w0) - 1; w0 &= w0 - 1; colidx[pos++] = lane*32 + b; }
    while (w1){ int b = __ffs(w1) - 1; w1 &= w1 - 1; colidx[pos++] = (64 + lane)*32 + b; }
  } else {
    int e = (blockIdx.x - 1024)*256 + threadIdx.x;
    int s = ei[e], d = ei[NE + e];
    int pos = atomicAdd(&cur[d], 1);
    srcs[rpD[d] + pos] = s;
  }
}

// ---------- weight transpose+convert: dst[N,K] bf16 = src[K,N] f32 ----------
struct WDesc { const float* src; u16* dst; int K; int N; };
struct WPack { WDesc w[12]; };
__global__ void k_wconv(WPack p){
  WDesc d = p.w[blockIdx.z];
  int k0 = blockIdx.y*32, n0 = blockIdx.x*32;
  if (k0 >= d.K || n0 >= d.N) return;
  __shared__ float t[32][33];
  int tx = threadIdx.x & 31, ty = threadIdx.x >> 5;
  #pragma unroll
  for (int r = 0; r < 4; ++r){
    int row = ty + r*8;
    t[row][tx] = d.src[(size_t)(k0 + row)*d.N + n0 + tx];
  }
  __syncthreads();
  #pragma unroll
  for (int r = 0; r < 4; ++r){
    int row = ty + r*8;
    d.dst[(size_t)(n0 + row)*d.K + k0 + tx] = (u16)f2bf(t[tx][row]);
  }
}

// ---------- sparse-tower GCN aggregation (wave per row, shuffle-broadcast) ----------
__global__ __launch_bounds__(256) void k_gcn_sp(const float* __restrict__ U, float* __restrict__ out,
    u16* __restrict__ outbf,
    const int* __restrict__ rp, const int* __restrict__ srcs, const float* __restrict__ dis,
    const float* __restrict__ bias, const float* __restrict__ avec){
  int wid = (blockIdx.x*256 + threadIdx.x) >> 6;
  int lane = threadIdx.x & 63;
  if (wid >= NN) return;
  int j = wid;
  f32x4 a0 = {0,0,0,0}, a1 = {0,0,0,0};
  int b = rp[j], e = rp[j+1];
  for (int base = b; base < e; base += 64){
    int idx = base + lane;
    int myc = 0; float myd = 0.f;
    if (idx < e){ myc = srcs[idx]; myd = dis[myc]; }
    int m = min(64, e - base);
    for (int k = 0; k < m; ++k){
      int s = __shfl(myc, k); float w = __shfl(myd, k);
      const f32x4* Us = (const f32x4*)(U + (size_t)s*HIDC);
      a0 += w*Us[lane]; a1 += w*Us[64+lane];
    }
  }
  float dj = dis[j];
  const f32x4* Uj = (const f32x4*)(U + (size_t)j*HIDC);
  a0 += dj*Uj[lane]; a1 += dj*Uj[64+lane];
  float* op = out + (size_t)j*HIDC;
  u16* ob = outbf + (size_t)j*HIDC;
  #pragma unroll
  for (int v = 0; v < 4; ++v){
    int c0 = lane*4 + v, c1 = 256 + lane*4 + v;
    float x0 = dj*a0[v] + bias[c0]; float p0 = avec[c0];
    float r0 = x0 >= 0.f ? x0 : p0*x0;
    op[c0] = r0; ob[c0] = (u16)f2bf(r0);
    float x1 = dj*a1[v] + bias[c1]; float p1 = avec[c1];
    float r1 = x1 >= 0.f ? x1 : p1*x1;
    op[c1] = r1; ob[c1] = (u16)f2bf(r1);
  }
}

// ---------- Chebyshev w-step. MODE 0: first (w==alpha); 1: mid; 2: final -> dc ----------
template<int MODE>
__global__ __launch_bounds__(256) void k_wstep(const float* __restrict__ w, const float* wp,
    float* __restrict__ wn, const int* __restrict__ rp, const int* __restrict__ cols,
    const float* __restrict__ di, float* __restrict__ dcv, float om){
  int wid = (blockIdx.x*256 + threadIdx.x) >> 6;
  int lane = threadIdx.x & 63;
  if (wid >= NN) return;
  int b = rp[wid], e = rp[wid+1];
  float acc = 0.f;
  for (int k = b + lane; k < e; k += 64){
    int i = cols[k];
    float wi = (MODE == 0) ? ALPHA_C : w[i];
    acc += di[i]*wi;
  }
  #pragma unroll
  for (int o = 32; o > 0; o >>= 1) acc += __shfl_down(acc, o);
  if (lane == 0){
    float dj = di[wid];
    float wj = (MODE == 0) ? ALPHA_C : w[wid];
    float basic = ALPHA_C + BETA_C*dj*(acc + dj*wj);
    float v;
    if (MODE == 0) v = basic;
    else {
      float pv = wp[wid];
      v = om*basic + (1.f - om)*pv;
    }
    if (MODE == 2) dcv[wid] = rsqrtf(fmaxf(v + 1.0f, 1e-12f));
    else wn[wid] = v;
  }
}

// ---------- Chebyshev step C=128, wave per row, shuffle-broadcast ----------
template<int FIN>
__global__ __launch_bounds__(256) void k_b128(const float* __restrict__ X, const float* __restrict__ Z,
    const float* Xp, float* Xn, u16* __restrict__ Pxbf,
    const int* __restrict__ rp, const int* __restrict__ cols,
    const float* __restrict__ di, float om,
    const float* __restrict__ dcv, const float* __restrict__ xf){
  int wid = (blockIdx.x*256 + threadIdx.x) >> 6;
  int lane = threadIdx.x & 63;
  if (wid >= NN) return;
  int j = wid;
  int b = rp[j], e = rp[j+1];
  float dj = di[j];
  f32x2 a0 = {0,0};
  for (int base = b; base < e; base += 64){
    int idx = base + lane;
    int myc = 0; float myd = 0.f;
    if (idx < e){ myc = cols[idx]; myd = di[myc]; }
    int m = min(64, e - base);
    for (int k = 0; k < m; ++k){
      int i = __shfl(myc, k); float w = __shfl(myd, k);
      a0 += w * (*(const f32x2*)(X + (size_t)i*128 + lane*2));
    }
  }
  a0 += dj * (*(const f32x2*)(X + (size_t)j*128 + lane*2));
  f32x2 basic = *(const f32x2*)(Z + (size_t)j*128 + lane*2) + (BETA_C*dj)*a0;
  f32x2 xp = *(const f32x2*)(Xp + (size_t)j*128 + lane*2);
  f32x2 v; v[0] = om*basic[0] + (1.f-om)*xp[0]; v[1] = om*basic[1] + (1.f-om)*xp[1];
  if constexpr (FIN){
    float d2 = dcv[j];
    f32x2 fv = *(const f32x2*)(xf + (size_t)j*128 + lane*2);
    unsigned pk = (unsigned)(unsigned short)f2bf(d2*(v[0] + d2*fv[0]))
                | ((unsigned)(unsigned short)f2bf(d2*(v[1] + d2*fv[1])) << 16);
    *(unsigned*)(Pxbf + (size_t)j*128 + lane*2) = pk;
  } else {
    *(f32x2*)(Xn + (size_t)j*128 + lane*2) = v;
  }
}

// ---------- Chebyshev step C=512, 2 waves per row, shuffle-broadcast ----------
template<int FIN>
__global__ __launch_bounds__(256) void k_b512(const float* __restrict__ X, const float* __restrict__ Z,
    const float* Xp, float* Xn, u16* __restrict__ Xnbf,
    const int* __restrict__ rp, const int* __restrict__ cols,
    const float* __restrict__ di, float om,
    const float* __restrict__ dcv, const u16* __restrict__ Ubf,
    const float* __restrict__ bias, const float* __restrict__ avec){
  int wid = (blockIdx.x*256 + threadIdx.x) >> 6;
  int lane = threadIdx.x & 63;
  if (wid >= 2*NN) return;
  int j = wid >> 1, half = wid & 1;
  int co = half*256 + lane*4;
  int b = rp[j], e = rp[j+1];
  float dj = di[j];
  f32x4 a0 = {0,0,0,0};
  for (int base = b; base < e; base += 64){
    int idx = base + lane;
    int myc = 0; float myd = 0.f;
    if (idx < e){ myc = cols[idx]; myd = di[myc]; }
    int m = min(64, e - base);
    for (int k = 0; k < m; ++k){
      int i = __shfl(myc, k); float w = __shfl(myd, k);
      a0 += w * (*(const f32x4*)(X + (size_t)i*512 + co));
    }
  }
  a0 += dj * (*(const f32x4*)(X + (size_t)j*512 + co));
  f32x4 basic = *(const f32x4*)(Z + (size_t)j*512 + co) + (BETA_C*dj)*a0;
  f32x4 xp = *(const f32x4*)(Xp + (size_t)j*512 + co);
  f32x4 v;
  #pragma unroll
  for (int q = 0; q < 4; ++q) v[q] = om*basic[q] + (1.f-om)*xp[q];
  if constexpr (FIN){
    float d2 = dcv[j];
    short4v pk;
    #pragma unroll
    for (int q = 0; q < 4; ++q){
      float uq = bf2f(Ubf[(size_t)j*512 + co + q]);
      float x = d2*(v[q] + d2*uq) + bias[co + q];
      float a = avec[co + q];
      float r = x >= 0.f ? x : a*x;
      v[q] = r;
      pk[q] = f2bf(r);
    }
    *(f32x4*)(Xn + (size_t)j*512 + co) = v;
    *(short4v*)(Xnbf + (size_t)j*512 + co) = pk;
  } else {
    *(f32x4*)(Xn + (size_t)j*512 + co) = v;
  }
}

// ---------- Z prep for 128-col solve ----------
__global__ void k_prepZ128(const float* __restrict__ in, const float* __restrict__ dcv,
                           float* __restrict__ Z){
  int idx = blockIdx.x*256 + threadIdx.x;
  if (idx >= NN*CIN) return;
  Z[idx] = ALPHA_C * dcv[idx >> 7] * in[idx];
}

// ---------- segment sum -> [NG, 1024] bf16 ----------
__global__ void k_segsum(const float* __restrict__ z1, const float* __restrict__ z2,
                         const int* __restrict__ gptr, u16* __restrict__ gv){
  int g = blockIdx.x, t = threadIdx.x;
  float s0 = 0, s1 = 0, s2 = 0, s3 = 0;
  int rb = gptr[g], re = gptr[g+1];
  for (int r = rb; r < re; ++r){
    s0 += z1[(size_t)r*HIDC + t];       s1 += z1[(size_t)r*HIDC + 256 + t];
    s2 += z2[(size_t)r*HIDC + t];       s3 += z2[(size_t)r*HIDC + 256 + t];
  }
  gv[g*1024 + t] = (u16)f2bf(s0); gv[g*1024 + 256 + t] = (u16)f2bf(s1);
  gv[g*1024 + 512 + t] = (u16)f2bf(s2); gv[g*1024 + 768 + t] = (u16)f2bf(s3);
}

// ---------- bf16 MFMA GEMM, global_load_lds staging ----------
// A[M,K] bf16 row-major, Bt[N,K] bf16 row-major.
// KC>0: split-K partials to C. DUAL: cols<512 -> C f32 (+bias), cols>=512 -> Cb bf16 (+bias2, act ap2).
template<int BM, int BN, int ACT, int ADDM, int BIAS, int KC, int SPLIT, int ZOUT, int WF32, int WBF, int DUAL>
__global__ __launch_bounds__(256) void k_gemm(
    const u16* __restrict__ A, const u16* __restrict__ Bt,
    float* __restrict__ C, u16* __restrict__ Cb,
    const float* __restrict__ bias, const float* __restrict__ ap,
    const float* __restrict__ addm, float* __restrict__ C2,
    float* __restrict__ zb, const float* __restrict__ dcv,
    const float* __restrict__ bias2, const float* __restrict__ ap2,
    int M, int Nn, int K)
{
  __shared__ __align__(16) u16 As[BM*32];
  __shared__ __align__(16) u16 Bs[BN*32];
  const int tid = threadIdx.x;
  const int bm0 = blockIdx.y*BM, bn0 = blockIdx.x*BN;
  const int lane = tid & 63, wv = tid >> 6;
  const int wr = wv >> 1, wc = wv & 1;
  constexpr int MR = BM/32, NR = BN/32;
  f32x4 acc[MR][NR];
  #pragma unroll
  for (int i = 0; i < MR; ++i)
    #pragma unroll
    for (int j = 0; j < NR; ++j) acc[i][j] = (f32x4){0.f,0.f,0.f,0.f};
  const int r0 = wr*(BM/2), c0 = wc*(BN/2);
  const int glr = lane >> 2, glc = (lane & 3)*8;
  int k0 = 0, k1 = K;
  if constexpr (KC > 0){ k0 = blockIdx.z*KC; k1 = k0 + KC; }
  for (int kt = k0; kt < k1; kt += 32){
    #pragma unroll
    for (int q = 0; q < BM/64; ++q)
      gload16(A + (size_t)(bm0 + q*64 + wv*16 + glr)*K + kt + glc, &As[(q*4+wv)*512]);
    #pragma unroll
    for (int q = 0; q < BN/64; ++q)
      gload16(Bt + (size_t)(bn0 + q*64 + wv*16 + glr)*K + kt + glc, &Bs[(q*4+wv)*512]);
    __syncthreads();
    short8 af[MR], bfv[NR];
    #pragma unroll
    for (int mi = 0; mi < MR; ++mi)
      af[mi] = *(const short8*)&As[(r0 + mi*16 + (lane & 15))*32 + (lane >> 4)*8];
    #pragma unroll
    for (int ni = 0; ni < NR; ++ni)
      bfv[ni] = *(const short8*)&Bs[(c0 + ni*16 + (lane & 15))*32 + (lane >> 4)*8];
    #pragma unroll
    for (int mi = 0; mi < MR; ++mi)
      #pragma unroll
      for (int ni = 0; ni < NR; ++ni)
        acc[mi][ni] = __builtin_amdgcn_mfma_f32_16x16x32_bf16(af[mi], bfv[ni], acc[mi][ni], 0, 0, 0);
    __syncthreads();
  }
  #pragma unroll
  for (int mi = 0; mi < MR; ++mi){
    #pragma unroll
    for (int ni = 0; ni < NR; ++ni){
      int col = bn0 + c0 + ni*16 + (lane & 15);
      #pragma unroll
      for (int q = 0; q < 4; ++q){
        int row = bm0 + r0 + mi*16 + ((lane >> 4) << 2) + q;
        float v = acc[mi][ni][q];
        if constexpr (KC > 0){
          C[(size_t)blockIdx.z*M*Nn + (size_t)row*Nn + col] = v;
        } else if constexpr (DUAL){
          if (col < 512){
            v += bias[col];
            C[(size_t)row*512 + col] = v;
          } else {
            int c2 = col - 512;
            v += bias2[c2];
            float a = ap2[0];
            v = v >= 0.f ? v : a*v;
            Cb[(size_t)row*512 + c2] = (u16)f2bf(v);
          }
        } else {
          if constexpr (BIAS) v += bias[col];
          if constexpr (ACT == 1){ float a = ap[col]; v = v >= 0.f ? v : a*v; }
          if constexpr (ACT == 2){ float a = ap[0];   v = v >= 0.f ? v : a*v; }
          if constexpr (ADDM) v += addm[(size_t)row*Nn + col];
          if constexpr (WF32){
            if constexpr (SPLIT){
              float* dst = (row < NN) ? (C + (size_t)row*Nn) : (C2 + (size_t)(row - NN)*Nn);
              dst[col] = v;
            } else {
              C[(size_t)row*Nn + col] = v;
            }
          }
          if constexpr (WBF) Cb[(size_t)row*Nn + col] = (u16)f2bf(v);
          if constexpr (ZOUT) zb[(size_t)row*Nn + col] = ALPHA_C * dcv[row] * v;
        }
      }
    }
  }
}

// split-K reduce + epilogue. MODE 0: dual (gsb f32 | gh1 bf16+act); 1: bf16+act; 2: final split.
template<int MODE>
__global__ void k_red(const float* __restrict__ part, int KS, int Nn,
                      const float* __restrict__ b1, const float* __restrict__ a1s,
                      const float* __restrict__ b2, const float* __restrict__ a2s,
                      float* __restrict__ Cf, u16* __restrict__ Cb,
                      const float* __restrict__ addm,
                      float* __restrict__ o1, float* __restrict__ o2){
  int idx = blockIdx.x*256 + threadIdx.x;
  if (idx >= 128*Nn) return;
  float v = 0.f;
  for (int z = 0; z < KS; ++z) v += part[(size_t)z*128*Nn + idx];
  int row = idx / Nn, col = idx - row*Nn;
  if constexpr (MODE == 0){
    if (col < 512){
      v += b1[col];
      Cf[(size_t)row*512 + col] = v;
    } else {
      int c2 = col - 512;
      v += b2[c2];
      float a = a2s[0]; v = v >= 0.f ? v : a*v;
      Cb[(size_t)row*512 + c2] = (u16)f2bf(v);
    }
  } else if constexpr (MODE == 1){
    v += b1[col];
    float a = a1s[0]; v = v >= 0.f ? v : a*v;
    Cb[idx] = (u16)f2bf(v);
  } else {
    v += b1[col];
    float a = a1s[0]; v = v >= 0.f ? v : a*v;
    v += addm[idx];
    if (row < NG) o1[(size_t)row*Nn + col] = v;
    else o2[(size_t)(row - NG)*Nn + col] = v;
  }
}

extern "C" void kernel_launch(void* const* d_in, const int* in_sizes, int n_in,
                              void* d_out, int out_size, void* d_ws, size_t ws_size,
                              hipStream_t stream) {
  const float* cb   = (const float*)d_in[0];
  const float* g1W0 = (const float*)d_in[1];  const float* g1b0 = (const float*)d_in[2];
  const float* g1W1 = (const float*)d_in[3];  const float* g1b1 = (const float*)d_in[4];
  const float* g1a  = (const float*)d_in[5];
  const float* g2W0 = (const float*)d_in[6];  const float* g2b0 = (const float*)d_in[7];
  const float* g2W1 = (const float*)d_in[8];  const float* g2b1 = (const float*)d_in[9];
  const float* g2a  = (const float*)d_in[10];
  const float* m1W1 = (const float*)d_in[11]; const float* m1b1 = (const float*)d_in[12];
  const float* m1W2 = (const float*)d_in[13]; const float* m1b2 = (const float*)d_in[14];
  const float* m1W3 = (const float*)d_in[15]; const float* m1b3 = (const float*)d_in[16];
  const float* m1a1 = (const float*)d_in[17]; const float* m1a2 = (const float*)d_in[18];
  const float* m1a3 = (const float*)d_in[19];
  const float* m1Ws = (const float*)d_in[20]; const float* m1bs = (const float*)d_in[21];
  const float* m2W1 = (const float*)d_in[22]; const float* m2b1 = (const float*)d_in[23];
  const float* m2W2 = (const float*)d_in[24]; const float* m2b2 = (const float*)d_in[25];
  const float* m2W3 = (const float*)d_in[26]; const float* m2b3 = (const float*)d_in[27];
  const float* m2a1 = (const float*)d_in[28]; const float* m2a2 = (const float*)d_in[29];
  const float* m2a3 = (const float*)d_in[30];
  const float* m2Ws = (const float*)d_in[31]; const float* m2bs = (const float*)d_in[32];
  const int* xidx  = (const int*)d_in[33];
  const int* ei    = (const int*)d_in[34];
  const int* batch = (const int*)d_in[35];
  float* out = (float*)d_out;
  char* W = (char*)d_ws;
  constexpr size_t MB = 1024u*1024u;
  constexpr size_t KB = 1024u;

  // ---- workspace layout ----
  unsigned* Abits  = (unsigned*)(W);            // 0-2MB, dead after fill
  unsigned* ATbits = (unsigned*)(W + 2*MB);     // 2-4MB, dead after fill
  // post-fill: weights bf16 in 0-3.25MB
  u16* w_g1W0t   = (u16*)(W);
  u16* w_g2W0t   = (u16*)(W + 128*KB);
  u16* w_g1W1t   = (u16*)(W + 256*KB);
  u16* w_g2W1t   = (u16*)(W + 768*KB);
  u16* w_m1WsW1t = (u16*)(W + 1280*KB);         // [1024,512] 1MB: rows0-511 Ws^T, 512-1023 W1^T
  u16* w_m1W2t   = (u16*)(W + 2304*KB);
  u16* w_m1W3t   = (u16*)(W + 2816*KB);
  char* M4 = W + 4*MB;
  int* cntD  = (int*)(M4);
  int* cur   = (int*)(M4 + 16*KB);
  int* bcnt  = (int*)(M4 + 32*KB);
  int* cntAT = (int*)(M4 + 48*KB);
  int* rpAT  = (int*)(M4 + 80*KB);
  int* rpD   = (int*)(M4 + 100*KB);
  int* gptr  = (int*)(M4 + 120*KB);
  float* di  = (float*)(M4 + 124*KB);
  float* dis = (float*)(M4 + 140*KB);
  float* dc  = (float*)(M4 + 156*KB);
  float* wv0 = (float*)(M4 + 172*KB);
  float* wv1 = (float*)(M4 + 188*KB);
  int* colAT = (int*)(W + 4*MB + 256*KB);       // 256KB
  int* srcD  = (int*)(W + 4*MB + 512*KB);       // 256KB
  u16* gvbf  = (u16*)(W + 4*MB + 768*KB);       // [128,1024] 256KB
  u16* gh1bf = (u16*)(W + 5*MB);                // 128KB
  u16* gh2bf = (u16*)(W + 5*MB + 128*KB);       // 128KB
  float* gsb = (float*)(W + 5*MB + 256*KB);     // [128,512] 256KB
  float* xf  = (float*)(W + 6*MB);              // [4096,128] 2MB
  u16* xfbf  = (u16*)(W + 8*MB);                // 1MB
  u16* PxBf  = (u16*)(W + 9*MB);                // 1MB
  u16* w_m2WsW1t = (u16*)(W + 10*MB);           // [1024,1024] 2MB
  u16* w_m2W2t   = (u16*)(W + 12*MB);           // 512KB
  u16* w_m2W3t   = (u16*)(W + 12*MB + 512*KB);  // 512KB
  float* Zb128 = (float*)(W + 13*MB);           // 2MB
  float* Zb  = (float*)(W + 15*MB);             // 8MB
  float* XA  = (float*)(W + 23*MB);             // 8MB
  float* XB  = (float*)(W + 31*MB);             // 8MB
  u16* z1sbf = (u16*)(W + 35*MB);               // 4MB (dead before h1 use)
  u16* Ubf   = (u16*)(W + 39*MB);               // 4MB
  float* z1s = (float*)(W + 43*MB);             // 8MB
  u16* zsbf  = (u16*)(W + 51*MB);               // [8192,512] 8MB
  u16* z21bf = zsbf;
  u16* z22bf = (u16*)(W + 55*MB);
  float* ztmp = (float*)(W + 59*MB);            // 8MB
  float* Ub_t1 = XA;
  float* sb  = Zb;                              // [8192,512] f32 16MB @15-31MB
  u16* h1    = (u16*)(W + 31*MB);               // 8MB over XB
  u16* h2    = (u16*)(W + 59*MB);               // 8MB over ztmp
  float* gpart = (float*)(W + 59*MB);           // MLP2 partials (h2 dead by then), <=4MB
  float* XA128 = XA;
  float* XB128 = XB;

  // Chebyshev omegas (sigma = 0.8 -> sigma^2/4 = 0.16)
  float omg[K_CH + 1];
  {
    double o = 1.0; omg[1] = 1.0f;
    for (int k = 2; k <= K_CH; ++k){ o = 1.0/(1.0 - 0.16*o); omg[k] = (float)o; }
  }

  hipMemsetAsync(W, 0, 4*MB, stream);
  hipMemsetAsync(M4, 0, 64*KB, stream);

  k_embed<<<NN, CIN, 0, stream>>>(cb, xidx, xf, xfbf);
  k_scatter_hist<<<272, 256, 0, stream>>>(ei, Abits, ATbits, cntD, batch, bcnt);
  k_popc2<<<2048, 256, 0, stream>>>(Abits, ATbits, di, cntAT);
  k_prefix3<<<3, 1024, 0, stream>>>(cntAT, rpAT, NN, cntD, rpD, NN, bcnt, gptr, NG, dis);
  k_fillboth<<<1280, 256, 0, stream>>>(ATbits, rpAT, colAT, ei, rpD, cur, srcD);

  // weight convert (bitmaps now dead)
  {
    WPack p = {{ {g1W0, w_g1W0t, 128, 512}, {g2W0, w_g2W0t, 128, 512},
                 {g1W1, w_g1W1t, 512, 512}, {g2W1, w_g2W1t, 512, 512},
                 {m1Ws, w_m1WsW1t, 512, 512}, {m1W1, w_m1WsW1t + 512*512, 512, 512},
                 {m1W2, w_m1W2t, 512, 512}, {m1W3, w_m1W3t, 512, 512},
                 {m2Ws, w_m2WsW1t, 1024, 512}, {m2W1, w_m2WsW1t + 512*1024, 1024, 512},
                 {m2W2, w_m2W2t, 512, 512}, {m2W3, w_m2W3t, 512, 512} }};
    k_wconv<<<dim3(16, 32, 12), 256, 0, stream>>>(p);
  }

  // ---- tower 1 (sparse GCN) ----
  k_gemm<128,128,0,0,0,0,0,0,1,0,0><<<dim3(4, 32), 256, 0, stream>>>(
      xfbf, w_g1W0t, Ub_t1, nullptr, nullptr, nullptr, nullptr, nullptr, nullptr, nullptr, nullptr, nullptr, NN, HIDC, CIN);
  k_gcn_sp<<<1024, 256, 0, stream>>>(Ub_t1, z1s, z1sbf, rpD, srcD, dis, g1b0, g1a);
  k_gemm<128,128,0,0,0,0,0,0,1,0,0><<<dim3(4, 32), 256, 0, stream>>>(
      z1sbf, w_g1W1t, Ub_t1, nullptr, nullptr, nullptr, nullptr, nullptr, nullptr, nullptr, nullptr, nullptr, NN, HIDC, HIDC);
  k_gcn_sp<<<1024, 256, 0, stream>>>(Ub_t1, ztmp, z21bf, rpD, srcD, dis, g1b1, g1a);
  k_segsum<<<NG, 256, 0, stream>>>(z1s, ztmp, gptr, gvbf);

  // ---- w-solve -> dc (Chebyshev) ----
  k_wstep<0><<<1024, 256, 0, stream>>>(nullptr, nullptr, wv0, rpAT, colAT, di, nullptr, 1.0f);
  {
    float *curp = wv0, *prv = wv0;
    for (int k = 2; k < K_CH; ++k){
      float* nxt = (k == 2) ? wv1 : (float*)prv;
      if (k == 2) prv = wv0;
      k_wstep<1><<<1024, 256, 0, stream>>>(curp, prv, nxt, rpAT, colAT, di, nullptr, omg[k]);
      float* t = curp; curp = nxt; prv = t;
    }
    k_wstep<2><<<1024, 256, 0, stream>>>(curp, prv, nullptr, rpAT, colAT, di, dc, omg[K_CH]);
  }

  // ---- tower 2 layer 1: P@x (128 cols), Chebyshev ----
  k_prepZ128<<<2048, 256, 0, stream>>>(xf, dc, Zb128);
  k_b128<0><<<1024, 256, 0, stream>>>(Zb128, Zb128, Zb128, XA128, nullptr, rpAT, colAT, di, 1.0f, nullptr, nullptr);
  {
    float *curp = XA128, *prv = Zb128;
    for (int k = 2; k < K_CH; ++k){
      float* nxt = (k == 2) ? XB128 : prv;
      k_b128<0><<<1024, 256, 0, stream>>>(curp, Zb128, prv, nxt, nullptr, rpAT, colAT, di, omg[k], nullptr, nullptr);
      prv = curp; curp = nxt;
    }
    k_b128<1><<<1024, 256, 0, stream>>>(curp, Zb128, prv, nullptr, PxBf, rpAT, colAT, di, omg[K_CH], dc, xf);
  }
  k_gemm<128,128,1,0,1,0,0,0,1,1,0><<<dim3(4, 32), 256, 0, stream>>>(
      PxBf, w_g2W0t, z1s, z1sbf, g2b0, g2a, nullptr, nullptr, nullptr, nullptr, nullptr, nullptr, NN, HIDC, CIN);

  // ---- tower 2 layer 2: U = z1*W1 (bf16 + fused Z prep), then P@U (512 cols) ----
  k_gemm<128,128,0,0,0,0,0,1,0,1,0><<<dim3(4, 32), 256, 0, stream>>>(
      z1sbf, w_g2W1t, nullptr, Ubf, nullptr, nullptr, nullptr, nullptr, Zb, dc, nullptr, nullptr, NN, HIDC, HIDC);
  k_b512<0><<<2048, 256, 0, stream>>>(Zb, Zb, Zb, XA, nullptr, rpAT, colAT, di, 1.0f, nullptr, nullptr, nullptr, nullptr);
  {
    float *curp = XA, *prv = Zb;
    for (int k = 2; k < K_CH; ++k){
      float* nxt = (k == 2) ? XB : prv;
      k_b512<0><<<2048, 256, 0, stream>>>(curp, Zb, prv, nxt, nullptr, rpAT, colAT, di, omg[k], nullptr, nullptr, nullptr, nullptr);
      prv = curp; curp = nxt;
    }
    k_b512<1><<<2048, 256, 0, stream>>>(curp, Zb, prv, ztmp, z22bf, rpAT, colAT, di, omg[K_CH], dc, Ubf, g2b1, g2a);
  }
  k_segsum<<<NG, 256, 0, stream>>>(z1s, ztmp, gptr, gvbf + 64*1024);

  // ---- MLP1 on stacked zsbf = [z21bf|z22bf], M=8192 ----
  // dual GEMM: sb = zs@Ws + bs (f32), h1 = prelu(zs@W1 + b1) (bf16)
  k_gemm<128,128,0,0,0,0,0,0,0,0,1><<<dim3(8, 64), 256, 0, stream>>>(
      zsbf, w_m1WsW1t, sb, h1, m1bs, nullptr, nullptr, nullptr, nullptr, nullptr, m1b1, m1a1, 8192, 1024, HIDC);
  k_gemm<128,128,2,0,1,0,0,0,0,1,0><<<dim3(4, 64), 256, 0, stream>>>(
      h1, w_m1W2t, nullptr, h2, m1b2, m1a2, nullptr, nullptr, nullptr, nullptr, nullptr, nullptr, 8192, HIDC, HIDC);
  k_gemm<128,128,2,1,1,0,1,0,1,0,0><<<dim3(4, 64), 256, 0, stream>>>(
      h2, w_m1W3t, out, nullptr, m1b3, m1a3, sb, out + 2129920, nullptr, nullptr, nullptr, nullptr, 8192, HIDC, HIDC);

  // ---- MLP2 on stacked gvbf [128,1024] ----
  // layer 1 (Ws|W1 stacked, N=1024), split-K KC=128 -> 8 slices
  k_gemm<64,64,0,0,0,128,0,0,1,0,0><<<dim3(16, 2, 8), 256, 0, stream>>>(
      gvbf, w_m2WsW1t, gpart, nullptr, nullptr, nullptr, nullptr, nullptr, nullptr, nullptr, nullptr, nullptr, 128, 1024, 1024);
  k_red<0><<<512, 256, 0, stream>>>(gpart, 8, 1024, m2bs, nullptr, m2b1, m2a1, gsb, gh1bf, nullptr, nullptr, nullptr);
  // layer 2
  k_gemm<64,64,0,0,0,64,0,0,1,0,0><<<dim3(8, 2, 8), 256, 0, stream>>>(
      gh1bf, w_m2W2t, gpart, nullptr, nullptr, nullptr, nullptr, nullptr, nullptr, nullptr, nullptr, nullptr, 128, HIDC, HIDC);
  k_red<1><<<256, 256, 0, stream>>>(gpart, 8, 512, m2b2, m2a2, nullptr, nullptr, nullptr, gh2bf, nullptr, nullptr, nullptr);
  // layer 3 + skip + split out
  k_gemm<64,64,0,0,0,64,0,0,1,0,0><<<dim3(8, 2, 8), 256, 0, stream>>>(
      gh2bf, w_m2W3t, gpart, nullptr, nullptr, nullptr, nullptr, nullptr, nullptr, nullptr, nullptr, nullptr, 128, HIDC, HIDC);
  k_red<2><<<256, 256, 0, stream>>>(gpart, 8, 512, m2b3, m2a3, nullptr, nullptr, nullptr, nullptr, gsb, out + 2097152, out + 4227072);
}

// Round 6
// 542.094 us; speedup vs baseline: 3.0155x; 1.2025x over previous
//
#include <hip/hip_runtime.h>

// MVGRL encoder, MI355X gfx950. Round 6: XCD-swizzled dbuf GEMM (BN=64), bf16 GCN gathers, K=10.
#define NN 4096
#define NE 65536
#define NBAG 16
#define BFD 8192
#define CIN 128
#define HIDC 512
#define NG 64
#define ALPHA_C 0.2f
#define BETA_C 0.8f
#define K_CH 10
#define K_W 10

typedef unsigned short u16;
typedef __attribute__((ext_vector_type(8))) short short8;
typedef __attribute__((ext_vector_type(4))) short short4v;
typedef __attribute__((ext_vector_type(4))) float f32x4;
typedef __attribute__((ext_vector_type(2))) float f32x2;

__device__ __forceinline__ short f2bf(float f){
  unsigned u = __float_as_uint(f);
  u += 0x7fffu + ((u >> 16) & 1u);
  return (short)(u >> 16);
}
__device__ __forceinline__ float bf2f(u16 h){
  return __uint_as_float(((unsigned)h) << 16);
}
__device__ __forceinline__ void gload16(const void* g, const void* l){
  __builtin_amdgcn_global_load_lds(
    (const __attribute__((address_space(1))) unsigned int*)g,
    (__attribute__((address_space(3))) unsigned int*)l, 16, 0, 0);
}

// ---------- embedding bag (mean, padding idx = BFD), dual write f32 + bf16 ----------
__global__ void k_embed(const float* __restrict__ cb, const int* __restrict__ xidx,
                        float* __restrict__ xf, u16* __restrict__ xfbf){
  int n = blockIdx.x, c = threadIdx.x;
  float acc = 0.f; int cnt = 0;
  #pragma unroll
  for (int b = 0; b < NBAG; ++b){
    int id = xidx[n*NBAG + b];
    if (id != BFD){ acc += cb[(size_t)id*CIN + c]; ++cnt; }
  }
  float v = acc / (float)(cnt > 0 ? cnt : 1);
  xf[(size_t)n*CIN + c] = v;
  xfbf[(size_t)n*CIN + c] = (u16)f2bf(v);
}

// ---------- edge scatter + batch histogram (merged) ----------
__global__ void k_scatter_hist(const int* __restrict__ ei, unsigned* __restrict__ Ab,
                               unsigned* __restrict__ ATb, int* __restrict__ cntD,
                               const int* __restrict__ batch, int* __restrict__ bcnt){
  if (blockIdx.x < 256){
    int e = blockIdx.x*256 + threadIdx.x;
    int s = ei[e], d = ei[NE + e];
    atomicOr(&Ab[s*128 + (d >> 5)], 1u << (d & 31));
    atomicOr(&ATb[d*128 + (s >> 5)], 1u << (s & 31));
    atomicAdd(&cntD[d], 1);
  } else {
    int n = (blockIdx.x - 256)*256 + threadIdx.x;
    if (n < NN) atomicAdd(&bcnt[batch[n]], 1);
  }
}

// popcount rows; A-side writes di directly, AT-side writes cntAT
__global__ void k_popc2(const unsigned* __restrict__ Ab, const unsigned* __restrict__ ATb,
                        float* __restrict__ di, int* __restrict__ cntAT){
  int wid = (blockIdx.x*blockDim.x + threadIdx.x) >> 6;
  int lane = threadIdx.x & 63;
  if (wid >= 2*NN) return;
  const unsigned* bits; int r;
  if (wid < NN){ bits = Ab; r = wid; }
  else { bits = ATb; r = wid - NN; }
  int s = __popc(bits[r*128 + lane]) + __popc(bits[r*128 + 64 + lane]);
  #pragma unroll
  for (int off = 32; off > 0; off >>= 1) s += __shfl_down(s, off);
  if (lane == 0){
    if (wid < NN) di[r] = rsqrtf((float)s + 1.0f);
    else cntAT[r] = s;
  }
}

// three exclusive prefix sums; block 1 also emits dis = rsqrt(cntD+1)
__global__ void k_prefix3(const int* __restrict__ c0, int* __restrict__ r0, int n0,
                          const int* __restrict__ c1, int* __restrict__ r1, int n1,
                          const int* __restrict__ c2, int* __restrict__ r2, int n2,
                          float* __restrict__ dis){
  const int* cnt; int* rp; int n;
  if (blockIdx.x == 0){ cnt = c0; rp = r0; n = n0; }
  else if (blockIdx.x == 1){ cnt = c1; rp = r1; n = n1; }
  else { cnt = c2; rp = r2; n = n2; }
  __shared__ int a[4096];
  __shared__ int ps[1024];
  int t = threadIdx.x;
  for (int i = t; i < 4096; i += 1024) a[i] = (i < n) ? cnt[i] : 0;
  __syncthreads();
  if (blockIdx.x == 1){
    for (int i = t; i < NN; i += 1024) dis[i] = rsqrtf((float)a[i] + 1.0f);
  }
  int b0 = a[t*4], b1 = a[t*4+1], b2 = a[t*4+2], b3 = a[t*4+3];
  int s0 = b0, s1 = s0+b1, s2 = s1+b2, s3 = s2+b3;
  ps[t] = s3;
  __syncthreads();
  for (int off = 1; off < 1024; off <<= 1){
    int v = ps[t];
    int u = (t >= off) ? ps[t-off] : 0;
    __syncthreads();
    ps[t] = v + u;
    __syncthreads();
  }
  int excl = (t > 0) ? ps[t-1] : 0;
  int base = t*4;
  if (base     < n) rp[base]   = excl;
  if (base + 1 < n) rp[base+1] = excl + s0;
  if (base + 2 < n) rp[base+2] = excl + s1;
  if (base + 3 < n) rp[base+3] = excl + s2;
  if (t == 1023) rp[n] = ps[1023];
}

// CSR fill: blocks 0..1023 -> colAT from bitmap; 1024..1279 -> srcD from edges
__global__ void k_fillboth(const unsigned* __restrict__ bits, const int* __restrict__ rpA,
                           int* __restrict__ colidx,
                           const int* __restrict__ ei, const int* __restrict__ rpD,
                           int* __restrict__ cur, int* __restrict__ srcs){
  if (blockIdx.x < 1024){
    int wid = (blockIdx.x*blockDim.x + threadIdx.x) >> 6;
    int lane = threadIdx.x & 63;
    unsigned w0 = bits[wid*128 + lane];
    unsigned w1 = bits[wid*128 + 64 + lane];
    int c = __popc(w0) + __popc(w1);
    int x = c;
    #pragma unroll
    for (int d = 1; d < 64; d <<= 1){
      int y = __shfl_up(x, d);
      if (lane >= d) x += y;
    }
    int pos = rpA[wid] + (x - c);
    while (w0){ int b = __ffs(w0) - 1; w0 &= w0 - 1; colidx[pos++] = lane*32 + b; }
    while (w1){ int b = __ffs(w1) - 1; w1 &= w1 - 1; colidx[pos++] = (64 + lane)*32 + b; }
  } else {
    int e = (blockIdx.x - 1024)*256 + threadIdx.x;
    int s = ei[e], d = ei[NE + e];
    int pos = atomicAdd(&cur[d], 1);
    srcs[rpD[d] + pos] = s;
  }
}

// ---------- weight transpose+convert: dst[N,K] bf16 = src[K,N] f32 ----------
struct WDesc { const float* src; u16* dst; int K; int N; };
struct WPack { WDesc w[12]; };
__global__ void k_wconv(WPack p){
  WDesc d = p.w[blockIdx.z];
  int k0 = blockIdx.y*32, n0 = blockIdx.x*32;
  if (k0 >= d.K || n0 >= d.N) return;
  __shared__ float t[32][33];
  int tx = threadIdx.x & 31, ty = threadIdx.x >> 5;
  #pragma unroll
  for (int r = 0; r < 4; ++r){
    int row = ty + r*8;
    t[row][tx] = d.src[(size_t)(k0 + row)*d.N + n0 + tx];
  }
  __syncthreads();
  #pragma unroll
  for (int r = 0; r < 4; ++r){
    int row = ty + r*8;
    d.dst[(size_t)(n0 + row)*d.K + k0 + tx] = (u16)f2bf(t[tx][row]);
  }
}

// ---------- sparse-tower GCN aggregation (wave per row, shuffle-broadcast, bf16 U) ----------
__global__ __launch_bounds__(256) void k_gcn_sp(const u16* __restrict__ U, float* __restrict__ out,
    u16* __restrict__ outbf,
    const int* __restrict__ rp, const int* __restrict__ srcs, const float* __restrict__ dis,
    const float* __restrict__ bias, const float* __restrict__ avec){
  int wid = (blockIdx.x*256 + threadIdx.x) >> 6;
  int lane = threadIdx.x & 63;
  if (wid >= NN) return;
  int j = wid;
  f32x4 a0 = {0,0,0,0}, a1 = {0,0,0,0};
  int b = rp[j], e = rp[j+1];
  for (int base = b; base < e; base += 64){
    int idx = base + lane;
    int myc = 0; float myd = 0.f;
    if (idx < e){ myc = srcs[idx]; myd = dis[myc]; }
    int m = min(64, e - base);
    for (int k = 0; k < m; ++k){
      int s = __shfl(myc, k); float w = __shfl(myd, k);
      const u16* Us = U + (size_t)s*HIDC;
      short4v q0 = *(const short4v*)(Us + lane*4);
      short4v q1 = *(const short4v*)(Us + 256 + lane*4);
      #pragma unroll
      for (int r = 0; r < 4; ++r){
        a0[r] += w*bf2f((u16)q0[r]);
        a1[r] += w*bf2f((u16)q1[r]);
      }
    }
  }
  float dj = dis[j];
  const u16* Uj = U + (size_t)j*HIDC;
  short4v s0 = *(const short4v*)(Uj + lane*4);
  short4v s1 = *(const short4v*)(Uj + 256 + lane*4);
  #pragma unroll
  for (int r = 0; r < 4; ++r){
    a0[r] += dj*bf2f((u16)s0[r]);
    a1[r] += dj*bf2f((u16)s1[r]);
  }
  float* op = out + (size_t)j*HIDC;
  u16* ob = outbf + (size_t)j*HIDC;
  #pragma unroll
  for (int v = 0; v < 4; ++v){
    int c0 = lane*4 + v, c1 = 256 + lane*4 + v;
    float x0 = dj*a0[v] + bias[c0]; float p0 = avec[c0];
    float r0 = x0 >= 0.f ? x0 : p0*x0;
    op[c0] = r0; ob[c0] = (u16)f2bf(r0);
    float x1 = dj*a1[v] + bias[c1]; float p1 = avec[c1];
    float r1 = x1 >= 0.f ? x1 : p1*x1;
    op[c1] = r1; ob[c1] = (u16)f2bf(r1);
  }
}

// ---------- Chebyshev w-step. MODE 0: first (w==alpha); 1: mid; 2: final -> dc ----------
template<int MODE>
__global__ __launch_bounds__(256) void k_wstep(const float* __restrict__ w, const float* wp,
    float* __restrict__ wn, const int* __restrict__ rp, const int* __restrict__ cols,
    const float* __restrict__ di, float* __restrict__ dcv, float om){
  int wid = (blockIdx.x*256 + threadIdx.x) >> 6;
  int lane = threadIdx.x & 63;
  if (wid >= NN) return;
  int b = rp[wid], e = rp[wid+1];
  float acc = 0.f;
  for (int k = b + lane; k < e; k += 64){
    int i = cols[k];
    float wi = (MODE == 0) ? ALPHA_C : w[i];
    acc += di[i]*wi;
  }
  #pragma unroll
  for (int o = 32; o > 0; o >>= 1) acc += __shfl_down(acc, o);
  if (lane == 0){
    float dj = di[wid];
    float wj = (MODE == 0) ? ALPHA_C : w[wid];
    float basic = ALPHA_C + BETA_C*dj*(acc + dj*wj);
    float v;
    if (MODE == 0) v = basic;
    else {
      float pv = wp[wid];
      v = om*basic + (1.f - om)*pv;
    }
    if (MODE == 2) dcv[wid] = rsqrtf(fmaxf(v + 1.0f, 1e-12f));
    else wn[wid] = v;
  }
}

// ---------- Chebyshev step C=128, wave per row, shuffle-broadcast ----------
template<int FIN>
__global__ __launch_bounds__(256) void k_b128(const float* __restrict__ X, const float* __restrict__ Z,
    const float* Xp, float* Xn, u16* __restrict__ Pxbf,
    const int* __restrict__ rp, const int* __restrict__ cols,
    const float* __restrict__ di, float om,
    const float* __restrict__ dcv, const float* __restrict__ xf){
  int wid = (blockIdx.x*256 + threadIdx.x) >> 6;
  int lane = threadIdx.x & 63;
  if (wid >= NN) return;
  int j = wid;
  int b = rp[j], e = rp[j+1];
  float dj = di[j];
  f32x2 a0 = {0,0};
  for (int base = b; base < e; base += 64){
    int idx = base + lane;
    int myc = 0; float myd = 0.f;
    if (idx < e){ myc = cols[idx]; myd = di[myc]; }
    int m = min(64, e - base);
    for (int k = 0; k < m; ++k){
      int i = __shfl(myc, k); float w = __shfl(myd, k);
      a0 += w * (*(const f32x2*)(X + (size_t)i*128 + lane*2));
    }
  }
  a0 += dj * (*(const f32x2*)(X + (size_t)j*128 + lane*2));
  f32x2 basic = *(const f32x2*)(Z + (size_t)j*128 + lane*2) + (BETA_C*dj)*a0;
  f32x2 xp = *(const f32x2*)(Xp + (size_t)j*128 + lane*2);
  f32x2 v; v[0] = om*basic[0] + (1.f-om)*xp[0]; v[1] = om*basic[1] + (1.f-om)*xp[1];
  if constexpr (FIN){
    float d2 = dcv[j];
    f32x2 fv = *(const f32x2*)(xf + (size_t)j*128 + lane*2);
    unsigned pk = (unsigned)(unsigned short)f2bf(d2*(v[0] + d2*fv[0]))
                | ((unsigned)(unsigned short)f2bf(d2*(v[1] + d2*fv[1])) << 16);
    *(unsigned*)(Pxbf + (size_t)j*128 + lane*2) = pk;
  } else {
    *(f32x2*)(Xn + (size_t)j*128 + lane*2) = v;
  }
}

// ---------- Chebyshev step C=512, 2 waves per row, shuffle-broadcast ----------
template<int FIN>
__global__ __launch_bounds__(256) void k_b512(const float* __restrict__ X, const float* __restrict__ Z,
    const float* Xp, float* Xn, u16* __restrict__ Xnbf,
    const int* __restrict__ rp, const int* __restrict__ cols,
    const float* __restrict__ di, float om,
    const float* __restrict__ dcv, const u16* __restrict__ Ubf,
    const float* __restrict__ bias, const float* __restrict__ avec){
  int wid = (blockIdx.x*256 + threadIdx.x) >> 6;
  int lane = threadIdx.x & 63;
  if (wid >= 2*NN) return;
  int j = wid >> 1, half = wid & 1;
  int co = half*256 + lane*4;
  int b = rp[j], e = rp[j+1];
  float dj = di[j];
  f32x4 a0 = {0,0,0,0};
  for (int base = b; base < e; base += 64){
    int idx = base + lane;
    int myc = 0; float myd = 0.f;
    if (idx < e){ myc = cols[idx]; myd = di[myc]; }
    int m = min(64, e - base);
    for (int k = 0; k < m; ++k){
      int i = __shfl(myc, k); float w = __shfl(myd, k);
      a0 += w * (*(const f32x4*)(X + (size_t)i*512 + co));
    }
  }
  a0 += dj * (*(const f32x4*)(X + (size_t)j*512 + co));
  f32x4 basic = *(const f32x4*)(Z + (size_t)j*512 + co) + (BETA_C*dj)*a0;
  f32x4 xp = *(const f32x4*)(Xp + (size_t)j*512 + co);
  f32x4 v;
  #pragma unroll
  for (int q = 0; q < 4; ++q) v[q] = om*basic[q] + (1.f-om)*xp[q];
  if constexpr (FIN){
    float d2 = dcv[j];
    short4v pk;
    #pragma unroll
    for (int q = 0; q < 4; ++q){
      float uq = bf2f(Ubf[(size_t)j*512 + co + q]);
      float x = d2*(v[q] + d2*uq) + bias[co + q];
      float a = avec[co + q];
      float r = x >= 0.f ? x : a*x;
      v[q] = r;
      pk[q] = f2bf(r);
    }
    *(f32x4*)(Xn + (size_t)j*512 + co) = v;
    *(short4v*)(Xnbf + (size_t)j*512 + co) = pk;
  } else {
    *(f32x4*)(Xn + (size_t)j*512 + co) = v;
  }
}

// ---------- Z prep for 128-col solve ----------
__global__ void k_prepZ128(const float* __restrict__ in, const float* __restrict__ dcv,
                           float* __restrict__ Z){
  int idx = blockIdx.x*256 + threadIdx.x;
  if (idx >= NN*CIN) return;
  Z[idx] = ALPHA_C * dcv[idx >> 7] * in[idx];
}

// ---------- segment sum -> [NG, 1024] bf16 ----------
__global__ void k_segsum(const float* __restrict__ z1, const float* __restrict__ z2,
                         const int* __restrict__ gptr, u16* __restrict__ gv){
  int g = blockIdx.x, t = threadIdx.x;
  float s0 = 0, s1 = 0, s2 = 0, s3 = 0;
  int rb = gptr[g], re = gptr[g+1];
  for (int r = rb; r < re; ++r){
    s0 += z1[(size_t)r*HIDC + t];       s1 += z1[(size_t)r*HIDC + 256 + t];
    s2 += z2[(size_t)r*HIDC + t];       s3 += z2[(size_t)r*HIDC + 256 + t];
  }
  gv[g*1024 + t] = (u16)f2bf(s0); gv[g*1024 + 256 + t] = (u16)f2bf(s1);
  gv[g*1024 + 512 + t] = (u16)f2bf(s2); gv[g*1024 + 768 + t] = (u16)f2bf(s3);
}

// ---------- bf16 MFMA GEMM: XCD-swizzled, double-buffered 2-phase, global_load_lds ----------
// A[M,K] bf16 row-major, Bt[N,K] bf16 row-major.
// KC>0: split-K partials to C. DUAL: cols<512 -> C f32 (+bias), cols>=512 -> Cb bf16 (+bias2, ap2).
template<int BM, int BN, int ACT, int ADDM, int BIAS, int KC, int SPLIT, int ZOUT, int WF32, int WBF, int DUAL>
__global__ __launch_bounds__(256, 2) void k_gemm(
    const u16* __restrict__ A, const u16* __restrict__ Bt,
    float* __restrict__ C, u16* __restrict__ Cb,
    const float* __restrict__ bias, const float* __restrict__ ap,
    const float* __restrict__ addm, float* __restrict__ C2,
    float* __restrict__ zb, const float* __restrict__ dcv,
    const float* __restrict__ bias2, const float* __restrict__ ap2,
    int M, int Nn, int K)
{
  __shared__ __align__(16) u16 As[2][BM*32];
  __shared__ __align__(16) u16 Bs[2][BN*32];
  const int tid = threadIdx.x;
  // XCD-aware swizzle: col-blocks of one row-panel land on one XCD (nwg % 8 == 0 for all grids)
  int nwg = gridDim.x * gridDim.y;
  int flat = blockIdx.y * gridDim.x + blockIdx.x;
  int swz = (flat & 7) * (nwg >> 3) + (flat >> 3);
  int bxx = swz % gridDim.x, byy = swz / gridDim.x;
  const int bm0 = byy*BM, bn0 = bxx*BN;
  const int lane = tid & 63, wv = tid >> 6;
  const int wr = wv >> 1, wc = wv & 1;
  constexpr int MR = BM/32, NR = BN/32;
  f32x4 acc[MR][NR];
  #pragma unroll
  for (int i = 0; i < MR; ++i)
    #pragma unroll
    for (int j = 0; j < NR; ++j) acc[i][j] = (f32x4){0.f,0.f,0.f,0.f};
  const int r0 = wr*(BM/2), c0 = wc*(BN/2);
  const int glr = lane >> 2, glc = (lane & 3)*8;
  int k0 = 0, k1 = K;
  if constexpr (KC > 0){ k0 = blockIdx.z*KC; k1 = k0 + KC; }
  const int nt = (k1 - k0) >> 5;
  auto STAGE = [&](int buf, int kt){
    #pragma unroll
    for (int q = 0; q < BM/64; ++q)
      gload16(A + (size_t)(bm0 + q*64 + wv*16 + glr)*K + kt + glc, &As[buf][(q*4+wv)*512]);
    #pragma unroll
    for (int q = 0; q < BN/64; ++q)
      gload16(Bt + (size_t)(bn0 + q*64 + wv*16 + glr)*K + kt + glc, &Bs[buf][(q*4+wv)*512]);
  };
  STAGE(0, k0);
  __syncthreads();
  for (int t = 0; t < nt; ++t){
    if (t + 1 < nt) STAGE((t+1)&1, k0 + ((t+1) << 5));
    short8 af[MR], bfv[NR];
    #pragma unroll
    for (int mi = 0; mi < MR; ++mi)
      af[mi] = *(const short8*)&As[t&1][(r0 + mi*16 + (lane & 15))*32 + (lane >> 4)*8];
    #pragma unroll
    for (int ni = 0; ni < NR; ++ni)
      bfv[ni] = *(const short8*)&Bs[t&1][(c0 + ni*16 + (lane & 15))*32 + (lane >> 4)*8];
    #pragma unroll
    for (int mi = 0; mi < MR; ++mi)
      #pragma unroll
      for (int ni = 0; ni < NR; ++ni)
        acc[mi][ni] = __builtin_amdgcn_mfma_f32_16x16x32_bf16(af[mi], bfv[ni], acc[mi][ni], 0, 0, 0);
    __syncthreads();
  }
  #pragma unroll
  for (int mi = 0; mi < MR; ++mi){
    #pragma unroll
    for (int ni = 0; ni < NR; ++ni){
      int col = bn0 + c0 + ni*16 + (lane & 15);
      #pragma unroll
      for (int q = 0; q < 4; ++q){
        int row = bm0 + r0 + mi*16 + ((lane >> 4) << 2) + q;
        float v = acc[mi][ni][q];
        if constexpr (KC > 0){
          C[(size_t)blockIdx.z*M*Nn + (size_t)row*Nn + col] = v;
        } else if constexpr (DUAL){
          if (col < 512){
            v += bias[col];
            C[(size_t)row*512 + col] = v;
          } else {
            int c2 = col - 512;
            v += bias2[c2];
            float a = ap2[0];
            v = v >= 0.f ? v : a*v;
            Cb[(size_t)row*512 + c2] = (u16)f2bf(v);
          }
        } else {
          if constexpr (BIAS) v += bias[col];
          if constexpr (ACT == 1){ float a = ap[col]; v = v >= 0.f ? v : a*v; }
          if constexpr (ACT == 2){ float a = ap[0];   v = v >= 0.f ? v : a*v; }
          if constexpr (ADDM) v += addm[(size_t)row*Nn + col];
          if constexpr (WF32){
            if constexpr (SPLIT){
              float* dst = (row < NN) ? (C + (size_t)row*Nn) : (C2 + (size_t)(row - NN)*Nn);
              dst[col] = v;
            } else {
              C[(size_t)row*Nn + col] = v;
            }
          }
          if constexpr (WBF) Cb[(size_t)row*Nn + col] = (u16)f2bf(v);
          if constexpr (ZOUT) zb[(size_t)row*Nn + col] = ALPHA_C * dcv[row] * v;
        }
      }
    }
  }
}

// split-K reduce + epilogue. MODE 0: dual (gsb f32 | gh1 bf16+act); 1: bf16+act; 2: final split.
template<int MODE>
__global__ void k_red(const float* __restrict__ part, int KS, int Nn,
                      const float* __restrict__ b1, const float* __restrict__ a1s,
                      const float* __restrict__ b2, const float* __restrict__ a2s,
                      float* __restrict__ Cf, u16* __restrict__ Cb,
                      const float* __restrict__ addm,
                      float* __restrict__ o1, float* __restrict__ o2){
  int idx = blockIdx.x*256 + threadIdx.x;
  if (idx >= 128*Nn) return;
  float v = 0.f;
  for (int z = 0; z < KS; ++z) v += part[(size_t)z*128*Nn + idx];
  int row = idx / Nn, col = idx - row*Nn;
  if constexpr (MODE == 0){
    if (col < 512){
      v += b1[col];
      Cf[(size_t)row*512 + col] = v;
    } else {
      int c2 = col - 512;
      v += b2[c2];
      float a = a2s[0]; v = v >= 0.f ? v : a*v;
      Cb[(size_t)row*512 + c2] = (u16)f2bf(v);
    }
  } else if constexpr (MODE == 1){
    v += b1[col];
    float a = a1s[0]; v = v >= 0.f ? v : a*v;
    Cb[idx] = (u16)f2bf(v);
  } else {
    v += b1[col];
    float a = a1s[0]; v = v >= 0.f ? v : a*v;
    v += addm[idx];
    if (row < NG) o1[(size_t)row*Nn + col] = v;
    else o2[(size_t)(row - NG)*Nn + col] = v;
  }
}

extern "C" void kernel_launch(void* const* d_in, const int* in_sizes, int n_in,
                              void* d_out, int out_size, void* d_ws, size_t ws_size,
                              hipStream_t stream) {
  const float* cb   = (const float*)d_in[0];
  const float* g1W0 = (const float*)d_in[1];  const float* g1b0 = (const float*)d_in[2];
  const float* g1W1 = (const float*)d_in[3];  const float* g1b1 = (const float*)d_in[4];
  const float* g1a  = (const float*)d_in[5];
  const float* g2W0 = (const float*)d_in[6];  const float* g2b0 = (const float*)d_in[7];
  const float* g2W1 = (const float*)d_in[8];  const float* g2b1 = (const float*)d_in[9];
  const float* g2a  = (const float*)d_in[10];
  const float* m1W1 = (const float*)d_in[11]; const float* m1b1 = (const float*)d_in[12];
  const float* m1W2 = (const float*)d_in[13]; const float* m1b2 = (const float*)d_in[14];
  const float* m1W3 = (const float*)d_in[15]; const float* m1b3 = (const float*)d_in[16];
  const float* m1a1 = (const float*)d_in[17]; const float* m1a2 = (const float*)d_in[18];
  const float* m1a3 = (const float*)d_in[19];
  const float* m1Ws = (const float*)d_in[20]; const float* m1bs = (const float*)d_in[21];
  const float* m2W1 = (const float*)d_in[22]; const float* m2b1 = (const float*)d_in[23];
  const float* m2W2 = (const float*)d_in[24]; const float* m2b2 = (const float*)d_in[25];
  const float* m2W3 = (const float*)d_in[26]; const float* m2b3 = (const float*)d_in[27];
  const float* m2a1 = (const float*)d_in[28]; const float* m2a2 = (const float*)d_in[29];
  const float* m2a3 = (const float*)d_in[30];
  const float* m2Ws = (const float*)d_in[31]; const float* m2bs = (const float*)d_in[32];
  const int* xidx  = (const int*)d_in[33];
  const int* ei    = (const int*)d_in[34];
  const int* batch = (const int*)d_in[35];
  float* out = (float*)d_out;
  char* W = (char*)d_ws;
  constexpr size_t MB = 1024u*1024u;
  constexpr size_t KB = 1024u;

  // ---- workspace layout ----
  unsigned* Abits  = (unsigned*)(W);            // 0-2MB, dead after fill
  unsigned* ATbits = (unsigned*)(W + 2*MB);     // 2-4MB, dead after fill
  u16* w_g1W0t   = (u16*)(W);
  u16* w_g2W0t   = (u16*)(W + 128*KB);
  u16* w_g1W1t   = (u16*)(W + 256*KB);
  u16* w_g2W1t   = (u16*)(W + 768*KB);
  u16* w_m1WsW1t = (u16*)(W + 1280*KB);         // [1024,512] 1MB: rows0-511 Ws^T, 512-1023 W1^T
  u16* w_m1W2t   = (u16*)(W + 2304*KB);
  u16* w_m1W3t   = (u16*)(W + 2816*KB);
  char* M4 = W + 4*MB;
  int* cntD  = (int*)(M4);
  int* cur   = (int*)(M4 + 16*KB);
  int* bcnt  = (int*)(M4 + 32*KB);
  int* cntAT = (int*)(M4 + 48*KB);
  int* rpAT  = (int*)(M4 + 80*KB);
  int* rpD   = (int*)(M4 + 100*KB);
  int* gptr  = (int*)(M4 + 120*KB);
  float* di  = (float*)(M4 + 124*KB);
  float* dis = (float*)(M4 + 140*KB);
  float* dc  = (float*)(M4 + 156*KB);
  float* wv0 = (float*)(M4 + 172*KB);
  float* wv1 = (float*)(M4 + 188*KB);
  int* colAT = (int*)(W + 4*MB + 256*KB);       // 256KB
  int* srcD  = (int*)(W + 4*MB + 512*KB);       // 256KB
  u16* gvbf  = (u16*)(W + 4*MB + 768*KB);       // [128,1024] 256KB
  u16* gh1bf = (u16*)(W + 5*MB);                // 128KB
  u16* gh2bf = (u16*)(W + 5*MB + 128*KB);       // 128KB
  float* gsb = (float*)(W + 5*MB + 256*KB);     // [128,512] 256KB
  float* xf  = (float*)(W + 6*MB);              // [4096,128] 2MB
  u16* xfbf  = (u16*)(W + 8*MB);                // 1MB
  u16* PxBf  = (u16*)(W + 9*MB);                // 1MB
  u16* w_m2WsW1t = (u16*)(W + 10*MB);           // [1024,1024] 2MB
  u16* w_m2W2t   = (u16*)(W + 12*MB);           // 512KB
  u16* w_m2W3t   = (u16*)(W + 12*MB + 512*KB);  // 512KB
  float* Zb128 = (float*)(W + 13*MB);           // 2MB
  float* Zb  = (float*)(W + 15*MB);             // 8MB
  float* XA  = (float*)(W + 23*MB);             // 8MB
  float* XB  = (float*)(W + 31*MB);             // 8MB
  u16* z1sbf = (u16*)(W + 35*MB);               // 4MB
  u16* Ubf   = (u16*)(W + 39*MB);               // 4MB (tower1 staging, then tower2 U)
  float* z1s = (float*)(W + 43*MB);             // 8MB
  u16* zsbf  = (u16*)(W + 51*MB);               // [8192,512] 8MB
  u16* z21bf = zsbf;
  u16* z22bf = (u16*)(W + 55*MB);
  float* ztmp = (float*)(W + 59*MB);            // 8MB
  float* sb  = Zb;                              // [8192,512] f32 16MB @15-31MB (Zb+XA dead)
  u16* h1    = (u16*)(W + 31*MB);               // 8MB over XB
  u16* h2    = (u16*)(W + 59*MB);               // 8MB over ztmp
  float* gpart = (float*)(W + 59*MB);           // MLP2 partials (h2 dead by then), <=4MB
  float* XA128 = XA;
  float* XB128 = XB;

  // Chebyshev omegas (sigma = 0.8 -> sigma^2/4 = 0.16)
  float omg[13];
  {
    double o = 1.0; omg[1] = 1.0f;
    for (int k = 2; k <= 12; ++k){ o = 1.0/(1.0 - 0.16*o); omg[k] = (float)o; }
  }

  hipMemsetAsync(W, 0, 4*MB, stream);
  hipMemsetAsync(M4, 0, 64*KB, stream);

  k_embed<<<NN, CIN, 0, stream>>>(cb, xidx, xf, xfbf);
  k_scatter_hist<<<272, 256, 0, stream>>>(ei, Abits, ATbits, cntD, batch, bcnt);
  k_popc2<<<2048, 256, 0, stream>>>(Abits, ATbits, di, cntAT);
  k_prefix3<<<3, 1024, 0, stream>>>(cntAT, rpAT, NN, cntD, rpD, NN, bcnt, gptr, NG, dis);
  k_fillboth<<<1280, 256, 0, stream>>>(ATbits, rpAT, colAT, ei, rpD, cur, srcD);

  // weight convert (bitmaps now dead)
  {
    WPack p = {{ {g1W0, w_g1W0t, 128, 512}, {g2W0, w_g2W0t, 128, 512},
                 {g1W1, w_g1W1t, 512, 512}, {g2W1, w_g2W1t, 512, 512},
                 {m1Ws, w_m1WsW1t, 512, 512}, {m1W1, w_m1WsW1t + 512*512, 512, 512},
                 {m1W2, w_m1W2t, 512, 512}, {m1W3, w_m1W3t, 512, 512},
                 {m2Ws, w_m2WsW1t, 1024, 512}, {m2W1, w_m2WsW1t + 512*1024, 1024, 512},
                 {m2W2, w_m2W2t, 512, 512}, {m2W3, w_m2W3t, 512, 512} }};
    k_wconv<<<dim3(16, 32, 12), 256, 0, stream>>>(p);
  }

  // ---- tower 1 (sparse GCN), U staged as bf16 ----
  k_gemm<128,64,0,0,0,0,0,0,0,1,0><<<dim3(8, 32), 256, 0, stream>>>(
      xfbf, w_g1W0t, nullptr, Ubf, nullptr, nullptr, nullptr, nullptr, nullptr, nullptr, nullptr, nullptr, NN, HIDC, CIN);
  k_gcn_sp<<<1024, 256, 0, stream>>>(Ubf, z1s, z1sbf, rpD, srcD, dis, g1b0, g1a);
  k_gemm<128,64,0,0,0,0,0,0,0,1,0><<<dim3(8, 32), 256, 0, stream>>>(
      z1sbf, w_g1W1t, nullptr, Ubf, nullptr, nullptr, nullptr, nullptr, nullptr, nullptr, nullptr, nullptr, NN, HIDC, HIDC);
  k_gcn_sp<<<1024, 256, 0, stream>>>(Ubf, ztmp, z21bf, rpD, srcD, dis, g1b1, g1a);
  k_segsum<<<NG, 256, 0, stream>>>(z1s, ztmp, gptr, gvbf);

  // ---- w-solve -> dc (Chebyshev, K_W steps) ----
  k_wstep<0><<<1024, 256, 0, stream>>>(nullptr, nullptr, wv0, rpAT, colAT, di, nullptr, 1.0f);
  {
    float *curp = wv0, *prv = wv0;
    for (int k = 2; k < K_W; ++k){
      float* nxt = (k == 2) ? wv1 : (float*)prv;
      if (k == 2) prv = wv0;
      k_wstep<1><<<1024, 256, 0, stream>>>(curp, prv, nxt, rpAT, colAT, di, nullptr, omg[k]);
      float* t = curp; curp = nxt; prv = t;
    }
    k_wstep<2><<<1024, 256, 0, stream>>>(curp, prv, nullptr, rpAT, colAT, di, dc, omg[K_W]);
  }

  // ---- tower 2 layer 1: P@x (128 cols), Chebyshev ----
  k_prepZ128<<<2048, 256, 0, stream>>>(xf, dc, Zb128);
  k_b128<0><<<1024, 256, 0, stream>>>(Zb128, Zb128, Zb128, XA128, nullptr, rpAT, colAT, di, 1.0f, nullptr, nullptr);
  {
    float *curp = XA128, *prv = Zb128;
    for (int k = 2; k < K_CH; ++k){
      float* nxt = (k == 2) ? XB128 : prv;
      k_b128<0><<<1024, 256, 0, stream>>>(curp, Zb128, prv, nxt, nullptr, rpAT, colAT, di, omg[k], nullptr, nullptr);
      prv = curp; curp = nxt;
    }
    k_b128<1><<<1024, 256, 0, stream>>>(curp, Zb128, prv, nullptr, PxBf, rpAT, colAT, di, omg[K_CH], dc, xf);
  }
  k_gemm<128,64,1,0,1,0,0,0,1,1,0><<<dim3(8, 32), 256, 0, stream>>>(
      PxBf, w_g2W0t, z1s, z1sbf, g2b0, g2a, nullptr, nullptr, nullptr, nullptr, nullptr, nullptr, NN, HIDC, CIN);

  // ---- tower 2 layer 2: U = z1*W1 (bf16 + fused Z prep), then P@U (512 cols) ----
  k_gemm<128,64,0,0,0,0,0,1,0,1,0><<<dim3(8, 32), 256, 0, stream>>>(
      z1sbf, w_g2W1t, nullptr, Ubf, nullptr, nullptr, nullptr, nullptr, Zb, dc, nullptr, nullptr, NN, HIDC, HIDC);
  k_b512<0><<<2048, 256, 0, stream>>>(Zb, Zb, Zb, XA, nullptr, rpAT, colAT, di, 1.0f, nullptr, nullptr, nullptr, nullptr);
  {
    float *curp = XA, *prv = Zb;
    for (int k = 2; k < K_CH; ++k){
      float* nxt = (k == 2) ? XB : prv;
      k_b512<0><<<2048, 256, 0, stream>>>(curp, Zb, prv, nxt, nullptr, rpAT, colAT, di, omg[k], nullptr, nullptr, nullptr, nullptr);
      prv = curp; curp = nxt;
    }
    k_b512<1><<<2048, 256, 0, stream>>>(curp, Zb, prv, ztmp, z22bf, rpAT, colAT, di, omg[K_CH], dc, Ubf, g2b1, g2a);
  }
  k_segsum<<<NG, 256, 0, stream>>>(z1s, ztmp, gptr, gvbf + 64*1024);

  // ---- MLP1 on stacked zsbf = [z21bf|z22bf], M=8192 ----
  k_gemm<128,64,0,0,0,0,0,0,0,0,1><<<dim3(16, 64), 256, 0, stream>>>(
      zsbf, w_m1WsW1t, sb, h1, m1bs, nullptr, nullptr, nullptr, nullptr, nullptr, m1b1, m1a1, 8192, 1024, HIDC);
  k_gemm<128,64,2,0,1,0,0,0,0,1,0><<<dim3(8, 64), 256, 0, stream>>>(
      h1, w_m1W2t, nullptr, h2, m1b2, m1a2, nullptr, nullptr, nullptr, nullptr, nullptr, nullptr, 8192, HIDC, HIDC);
  k_gemm<128,64,2,1,1,0,1,0,1,0,0><<<dim3(8, 64), 256, 0, stream>>>(
      h2, w_m1W3t, out, nullptr, m1b3, m1a3, sb, out + 2129920, nullptr, nullptr, nullptr, nullptr, 8192, HIDC, HIDC);

  // ---- MLP2 on stacked gvbf [128,1024] ----
  k_gemm<64,64,0,0,0,128,0,0,1,0,0><<<dim3(16, 2, 8), 256, 0, stream>>>(
      gvbf, w_m2WsW1t, gpart, nullptr, nullptr, nullptr, nullptr, nullptr, nullptr, nullptr, nullptr, nullptr, 128, 1024, 1024);
  k_red<0><<<512, 256, 0, stream>>>(gpart, 8, 1024, m2bs, nullptr, m2b1, m2a1, gsb, gh1bf, nullptr, nullptr, nullptr);
  k_gemm<64,64,0,0,0,64,0,0,1,0,0><<<dim3(8, 2, 8), 256, 0, stream>>>(
      gh1bf, w_m2W2t, gpart, nullptr, nullptr, nullptr, nullptr, nullptr, nullptr, nullptr, nullptr, nullptr, 128, HIDC, HIDC);
  k_red<1><<<256, 256, 0, stream>>>(gpart, 8, 512, m2b2, m2a2, nullptr, nullptr, nullptr, gh2bf, nullptr, nullptr, nullptr);
  k_gemm<64,64,0,0,0,64,0,0,1,0,0><<<dim3(8, 2, 8), 256, 0, stream>>>(
      gh2bf, w_m2W3t, gpart, nullptr, nullptr, nullptr, nullptr, nullptr, nullptr, nullptr, nullptr, nullptr, 128, HIDC, HIDC);
  k_red<2><<<256, 256, 0, stream>>>(gpart, 8, 512, m2b3, m2a3, nullptr, nullptr, nullptr, nullptr, gsb, out + 2097152, out + 4227072);
}